// Round 1
// baseline (8775.201 us; speedup 1.0000x reference)
//
#include <hip/hip_runtime.h>
#include <hip/hip_bf16.h>
#include <math.h>

// DockPointNet fused: edge PPF+MLP(47->64->128, ReLU+LN each) -> atomicMax
// segment reduce (ordered-uint float encoding) -> node MLP(128->256, ReLU+LN).
// Round 1: fp32 everywhere, per-thread-column LDS staging, direct atomics.

#define LN_EPS 1e-5f

// monotone float->uint mapping so unsigned atomicMax == float max
__device__ __forceinline__ unsigned ord(float f) {
    int i = __float_as_int(f);
    return (i >= 0) ? ((unsigned)i | 0x80000000u) : ~((unsigned)i);
}
__device__ __forceinline__ float unord(unsigned u) {
    int i = (u & 0x80000000u) ? (int)(u & 0x7fffffffu) : ~(int)u;
    return __int_as_float(i);
}

__global__ __launch_bounds__(256, 2)
void edge_kernel(const float* __restrict__ x,
                 const float* __restrict__ pos,
                 const float* __restrict__ nrm,
                 const float* __restrict__ ea,
                 const int* __restrict__ ei,
                 const float* __restrict__ W1, const float* __restrict__ b1,
                 const float* __restrict__ g1, const float* __restrict__ be1,
                 const float* __restrict__ W2, const float* __restrict__ b2,
                 const float* __restrict__ g2, const float* __restrict__ be2,
                 unsigned* __restrict__ agg, int E)
{
    // per-thread feature column; layout [k][tid] -> lane i hits bank i%32 (2-way, free)
    __shared__ float buf[64 * 256];
    const int tid = threadIdx.x;
    const int e = blockIdx.x * 256 + tid;
    if (e >= E) return;
    const int src = ei[e];        // j
    const int dst = ei[E + e];    // i

    // ---- x[src] -> cols 0..31
    {
        const float4* xp = (const float4*)(x + (size_t)src * 32);
        #pragma unroll
        for (int q = 0; q < 8; ++q) {
            float4 v = xp[q];
            buf[(4*q+0)*256 + tid] = v.x;
            buf[(4*q+1)*256 + tid] = v.y;
            buf[(4*q+2)*256 + tid] = v.z;
            buf[(4*q+3)*256 + tid] = v.w;
        }
    }
    // ---- geometry -> ppf cols 32..38
    {
        float pix = pos[3*dst+0], piy = pos[3*dst+1], piz = pos[3*dst+2];
        float pjx = pos[3*src+0], pjy = pos[3*src+1], pjz = pos[3*src+2];
        float dx = pjx - pix, dy = pjy - piy, dz = pjz - piz;
        float nix = nrm[3*dst+0], niy = nrm[3*dst+1], niz = nrm[3*dst+2];
        float njx = nrm[3*src+0], njy = nrm[3*src+1], njz = nrm[3*src+2];
        float pn2 = dx*dx + dy*dy + dz*dz;
        buf[32*256+tid] = sqrtf(pn2) * 0.125f;  // |pseudo| / RADIUS
        float cx, cy, cz, c2, d, den, inv, sn, cs;
        // a1 = angle(n_i, pseudo): sin = |cross|/r, cos = dot/r, r = sqrt(|c|^2+dot^2)
        cx = niy*dz - niz*dy; cy = niz*dx - nix*dz; cz = nix*dy - niy*dx;
        c2 = cx*cx + cy*cy + cz*cz;
        d  = nix*dx + niy*dy + niz*dz;
        den = c2 + d*d;
        if (den > 0.f) { inv = rsqrtf(den); sn = sqrtf(c2)*inv; cs = d*inv; }
        else           { sn = 0.f; cs = 1.f; }   // atan2(0,0) = 0
        buf[33*256+tid] = sn; buf[34*256+tid] = cs;
        // a2 = angle(n_j, pseudo)
        cx = njy*dz - njz*dy; cy = njz*dx - njx*dz; cz = njx*dy - njy*dx;
        c2 = cx*cx + cy*cy + cz*cz;
        d  = njx*dx + njy*dy + njz*dz;
        den = c2 + d*d;
        if (den > 0.f) { inv = rsqrtf(den); sn = sqrtf(c2)*inv; cs = d*inv; }
        else           { sn = 0.f; cs = 1.f; }
        buf[35*256+tid] = sn; buf[36*256+tid] = cs;
        // a3 = angle(n_i, n_j)
        cx = niy*njz - niz*njy; cy = niz*njx - nix*njz; cz = nix*njy - niy*njx;
        c2 = cx*cx + cy*cy + cz*cz;
        d  = nix*njx + niy*njy + niz*njz;
        den = c2 + d*d;
        if (den > 0.f) { inv = rsqrtf(den); sn = sqrtf(c2)*inv; cs = d*inv; }
        else           { sn = 0.f; cs = 1.f; }
        buf[37*256+tid] = sn; buf[38*256+tid] = cs;
    }
    // ---- edge_attr -> cols 39..46
    {
        const float4* ep = (const float4*)(ea + (size_t)e * 8);
        float4 a0 = ep[0], a1 = ep[1];
        buf[39*256+tid] = a0.x; buf[40*256+tid] = a0.y;
        buf[41*256+tid] = a0.z; buf[42*256+tid] = a0.w;
        buf[43*256+tid] = a1.x; buf[44*256+tid] = a1.y;
        buf[45*256+tid] = a1.z; buf[46*256+tid] = a1.w;
    }

    // ---- GEMM1: 47 -> 64 (W uniform -> scalar loads)
    float h1v[64];
    {
        const float4* bp = (const float4*)b1;
        #pragma unroll
        for (int j4 = 0; j4 < 16; ++j4) {
            float4 b = bp[j4];
            h1v[4*j4+0]=b.x; h1v[4*j4+1]=b.y; h1v[4*j4+2]=b.z; h1v[4*j4+3]=b.w;
        }
        for (int k = 0; k < 47; ++k) {
            float m = buf[k*256 + tid];
            const float4* wr = (const float4*)(W1 + k*64);
            #pragma unroll
            for (int j4 = 0; j4 < 16; ++j4) {
                float4 w = wr[j4];
                h1v[4*j4+0] = fmaf(m, w.x, h1v[4*j4+0]);
                h1v[4*j4+1] = fmaf(m, w.y, h1v[4*j4+1]);
                h1v[4*j4+2] = fmaf(m, w.z, h1v[4*j4+2]);
                h1v[4*j4+3] = fmaf(m, w.w, h1v[4*j4+3]);
            }
        }
    }
    // ---- ReLU + LN(64); normalized values back to LDS cols 0..63
    {
        float s = 0.f, s2 = 0.f;
        #pragma unroll
        for (int j = 0; j < 64; ++j) {
            float v = fmaxf(h1v[j], 0.f);
            h1v[j] = v; s += v; s2 += v*v;
        }
        float mu = s * (1.f/64.f);
        float var = fmaxf(s2 * (1.f/64.f) - mu*mu, 0.f);
        float rstd = rsqrtf(var + LN_EPS);
        #pragma unroll
        for (int j = 0; j < 64; ++j) {
            buf[j*256 + tid] = fmaf((h1v[j] - mu) * rstd, g1[j], be1[j]);
        }
    }
    // ---- GEMM2: 64 -> 128
    float h2v[128];
    {
        const float4* bp = (const float4*)b2;
        #pragma unroll
        for (int j4 = 0; j4 < 32; ++j4) {
            float4 b = bp[j4];
            h2v[4*j4+0]=b.x; h2v[4*j4+1]=b.y; h2v[4*j4+2]=b.z; h2v[4*j4+3]=b.w;
        }
        for (int k = 0; k < 64; ++k) {
            float m = buf[k*256 + tid];
            const float4* wr = (const float4*)(W2 + k*128);
            #pragma unroll
            for (int j4 = 0; j4 < 32; ++j4) {
                float4 w = wr[j4];
                h2v[4*j4+0] = fmaf(m, w.x, h2v[4*j4+0]);
                h2v[4*j4+1] = fmaf(m, w.y, h2v[4*j4+1]);
                h2v[4*j4+2] = fmaf(m, w.z, h2v[4*j4+2]);
                h2v[4*j4+3] = fmaf(m, w.w, h2v[4*j4+3]);
            }
        }
    }
    // ---- ReLU + LN(128) + ordered-uint atomic scatter-max
    {
        float s = 0.f, s2 = 0.f;
        #pragma unroll
        for (int j = 0; j < 128; ++j) {
            float v = fmaxf(h2v[j], 0.f);
            h2v[j] = v; s += v; s2 += v*v;
        }
        float mu = s * (1.f/128.f);
        float var = fmaxf(s2 * (1.f/128.f) - mu*mu, 0.f);
        float rstd = rsqrtf(var + LN_EPS);
        unsigned* ap = agg + (size_t)dst * 128;
        #pragma unroll
        for (int j = 0; j < 128; ++j) {
            float v = fmaf((h2v[j] - mu) * rstd, g2[j], be2[j]);
            atomicMax(ap + j, ord(v));
        }
    }
}

// node MLP: agg[128] @ Wg[128,256] + bg -> ReLU -> LN -> out
// 16 nodes/block, 16 threads/node, 16 outputs/thread
__global__ __launch_bounds__(256, 4)
void node_kernel(const unsigned* __restrict__ agg,
                 const float* __restrict__ Wg, const float* __restrict__ bg,
                 const float* __restrict__ gg, const float* __restrict__ beg,
                 float* __restrict__ out, int N)
{
    __shared__ float a_lds[16 * 130];  // +2 pad breaks 4-way broadcast-bank aliasing
    const int nb = blockIdx.x * 16;
    const size_t total = (size_t)N * 128;
    for (int t = threadIdx.x; t < 16 * 128; t += 256) {
        size_t g = (size_t)nb * 128 + t;
        unsigned u = (g < total) ? agg[g] : 0u;
        // sentinel 0 == segment never written (empty) -> 0.0 (matches isfinite fixup)
        a_lds[(t >> 7) * 130 + (t & 127)] = (u == 0u) ? 0.f : unord(u);
    }
    __syncthreads();
    const int n_local = threadIdx.x >> 4;
    const int og = threadIdx.x & 15;
    const int node = nb + n_local;
    if (node >= N) return;

    float acc[16];
    {
        const float4* bp = (const float4*)(bg + og * 16);
        #pragma unroll
        for (int r4 = 0; r4 < 4; ++r4) {
            float4 b = bp[r4];
            acc[4*r4+0]=b.x; acc[4*r4+1]=b.y; acc[4*r4+2]=b.z; acc[4*r4+3]=b.w;
        }
    }
    for (int k = 0; k < 128; ++k) {
        float a = a_lds[n_local * 130 + k];
        const float4* wr = (const float4*)(Wg + (size_t)k * 256 + og * 16);
        #pragma unroll
        for (int r4 = 0; r4 < 4; ++r4) {
            float4 w = wr[r4];
            acc[4*r4+0] = fmaf(a, w.x, acc[4*r4+0]);
            acc[4*r4+1] = fmaf(a, w.y, acc[4*r4+1]);
            acc[4*r4+2] = fmaf(a, w.z, acc[4*r4+2]);
            acc[4*r4+3] = fmaf(a, w.w, acc[4*r4+3]);
        }
    }
    // ReLU + LN(256) across the 16 threads of this node (same wave, 16-lane groups)
    float s = 0.f, s2 = 0.f;
    #pragma unroll
    for (int r = 0; r < 16; ++r) {
        float v = fmaxf(acc[r], 0.f);
        acc[r] = v; s += v; s2 += v*v;
    }
    #pragma unroll
    for (int m = 1; m < 16; m <<= 1) {
        s  += __shfl_xor(s,  m, 16);
        s2 += __shfl_xor(s2, m, 16);
    }
    float mu = s * (1.f/256.f);
    float var = fmaxf(s2 * (1.f/256.f) - mu*mu, 0.f);
    float rstd = rsqrtf(var + LN_EPS);
    float4* op = (float4*)(out + (size_t)node * 256 + og * 16);
    #pragma unroll
    for (int r4 = 0; r4 < 4; ++r4) {
        float4 o;
        o.x = fmaf((acc[4*r4+0] - mu) * rstd, gg[og*16 + 4*r4+0], beg[og*16 + 4*r4+0]);
        o.y = fmaf((acc[4*r4+1] - mu) * rstd, gg[og*16 + 4*r4+1], beg[og*16 + 4*r4+1]);
        o.z = fmaf((acc[4*r4+2] - mu) * rstd, gg[og*16 + 4*r4+2], beg[og*16 + 4*r4+2]);
        o.w = fmaf((acc[4*r4+3] - mu) * rstd, gg[og*16 + 4*r4+3], beg[og*16 + 4*r4+3]);
        op[r4] = o;
    }
}

extern "C" void kernel_launch(void* const* d_in, const int* in_sizes, int n_in,
                              void* d_out, int out_size, void* d_ws, size_t ws_size,
                              hipStream_t stream) {
    const float* x         = (const float*)d_in[0];
    const float* pos       = (const float*)d_in[1];
    const float* nrm       = (const float*)d_in[2];
    const float* edge_attr = (const float*)d_in[3];
    const int*   edge_idx  = (const int*)d_in[4];
    const float* W1  = (const float*)d_in[5];
    const float* b1  = (const float*)d_in[6];
    const float* g1  = (const float*)d_in[7];
    const float* be1 = (const float*)d_in[8];
    const float* W2  = (const float*)d_in[9];
    const float* b2  = (const float*)d_in[10];
    const float* g2  = (const float*)d_in[11];
    const float* be2 = (const float*)d_in[12];
    const float* Wg  = (const float*)d_in[13];
    const float* bg  = (const float*)d_in[14];
    const float* gg  = (const float*)d_in[15];
    const float* beg = (const float*)d_in[16];

    const int E = in_sizes[3] / 8;    // edge_attr is [E,8]
    const int N = in_sizes[0] / 32;   // x is [N,32]

    unsigned* agg = (unsigned*)d_ws;  // N*128 uints = 25.6 MB
    hipMemsetAsync(agg, 0, (size_t)N * 128 * sizeof(unsigned), stream);

    hipLaunchKernelGGL(edge_kernel, dim3((E + 255) / 256), dim3(256), 0, stream,
                       x, pos, nrm, edge_attr, edge_idx,
                       W1, b1, g1, be1, W2, b2, g2, be2, agg, E);

    hipLaunchKernelGGL(node_kernel, dim3((N + 15) / 16), dim3(256), 0, stream,
                       agg, Wg, bg, gg, beg, (float*)d_out, N);
}

// Round 3
// 2021.228 us; speedup vs baseline: 4.3415x; 4.3415x over previous
//
#include <hip/hip_runtime.h>
#include <hip/hip_bf16.h>
#include <math.h>

// DockPointNet fused, round 3: CSR-group edges by dst, per-block segmented max
// in LDS -> plain stores for interior runs, atomicMax only at block boundaries.
// R2 bug fixed: a run CONTINUING from the previous block (dst==dprev at tid 0)
// never started a run and was dropped. tid 0 now always starts a run; dprev
// only decides contPrev (atomic vs plain store).

#define LN_EPS 1e-5f
#define EBLK 192              // 3 waves; LDS = 64*192*4 + small = ~51 KB (<64 KB)
#define BIDX(k, t) ((k)*EBLK + ((t) ^ ((k) & 31)))   // XOR swizzle: both access
                                                      // patterns <=2-way banked

// monotone float->uint mapping so unsigned max == float max; 0 never produced
// for finite floats (would require -NaN input)
__device__ __forceinline__ unsigned ord(float f) {
    int i = __float_as_int(f);
    return (i >= 0) ? ((unsigned)i | 0x80000000u) : ~((unsigned)i);
}
__device__ __forceinline__ float unord(unsigned u) {
    int i = (u & 0x80000000u) ? (int)(u & 0x7fffffffu) : ~(int)u;
    return __int_as_float(i);
}

// ---------------- CSR build ----------------
__global__ void hist_kernel(const int* __restrict__ ei, unsigned* __restrict__ deg, int E) {
    int e = blockIdx.x * 256 + threadIdx.x;
    if (e < E) atomicAdd(&deg[ei[E + e]], 1u);
}

__global__ void scan1(const unsigned* __restrict__ deg, unsigned* __restrict__ part, int N) {
    __shared__ unsigned s[256];
    int i = blockIdx.x * 256 + threadIdx.x;
    s[threadIdx.x] = (i < N) ? deg[i] : 0u;
    __syncthreads();
    for (int st = 128; st > 0; st >>= 1) {
        if (threadIdx.x < st) s[threadIdx.x] += s[threadIdx.x + st];
        __syncthreads();
    }
    if (threadIdx.x == 0) part[blockIdx.x] = s[0];
}

__global__ void scan2(unsigned* __restrict__ part, int nb) {
    __shared__ unsigned s[256];
    int t = threadIdx.x;
    unsigned v = (t < nb) ? part[t] : 0u;
    s[t] = v;
    __syncthreads();
    for (int st = 1; st < 256; st <<= 1) {
        unsigned add = (t >= st) ? s[t - st] : 0u;
        __syncthreads();
        s[t] += add;
        __syncthreads();
    }
    if (t < nb) part[t] = s[t] - v;   // exclusive
}

__global__ void scan3(const unsigned* __restrict__ deg, const unsigned* __restrict__ part,
                      unsigned* __restrict__ off, int N) {
    __shared__ unsigned s[256];
    int i = blockIdx.x * 256 + threadIdx.x, t = threadIdx.x;
    unsigned v = (i < N) ? deg[i] : 0u;
    s[t] = v;
    __syncthreads();
    for (int st = 1; st < 256; st <<= 1) {
        unsigned add = (t >= st) ? s[t - st] : 0u;
        __syncthreads();
        s[t] += add;
        __syncthreads();
    }
    if (i < N) off[i] = part[blockIdx.x] + s[t] - v;   // exclusive
}

__global__ void scatter_kernel(const int* __restrict__ ei, unsigned* __restrict__ cursor,
                               unsigned* __restrict__ perm, int* __restrict__ dsts, int E) {
    int e = blockIdx.x * 256 + threadIdx.x;
    if (e >= E) return;
    int d = ei[E + e];
    unsigned pos = atomicAdd(&cursor[d], 1u);
    perm[pos] = (unsigned)e;
    dsts[pos] = d;   // deterministic per-slot (all slots of a node share d)
}

// ---------------- fused edge MLP + segmented max ----------------
__global__ __launch_bounds__(EBLK, 2)
void edge_kernel(const float* __restrict__ x,
                 const float* __restrict__ pos,
                 const float* __restrict__ nrm,
                 const float* __restrict__ ea,
                 const int* __restrict__ ei,
                 const unsigned* __restrict__ perm,
                 const int* __restrict__ dsts,
                 const float* __restrict__ W1, const float* __restrict__ b1,
                 const float* __restrict__ g1, const float* __restrict__ be1,
                 const float* __restrict__ W2, const float* __restrict__ b2,
                 const float* __restrict__ g2, const float* __restrict__ be2,
                 unsigned* __restrict__ agg, int E)
{
    __shared__ float buf[64 * EBLK];
    __shared__ int dloc[EBLK];
    __shared__ int rstart[EBLK];
    __shared__ int nrun_s, dprev_s, dnext_s;

    const int tid = threadIdx.x;
    const int p = blockIdx.x * EBLK + tid;
    const bool valid = p < E;

    int dst = -1, src = 0, e = 0;
    if (valid) {
        e = (int)perm[p];
        dst = dsts[p];
        src = ei[e];
    }
    dloc[tid] = dst;   // -1 for tail-invalid threads
    if (tid == 0) {
        nrun_s = 0;
        dprev_s = (blockIdx.x == 0) ? -1 : dsts[(size_t)blockIdx.x * EBLK - 1];
        int nx = blockIdx.x * EBLK + EBLK;
        dnext_s = (nx < E) ? dsts[nx] : -1;
    }

    float h2v[128];
    if (valid) {
        // ---- stage x[src] -> cols 0..31
        const float4* xp = (const float4*)(x + (size_t)src * 32);
        #pragma unroll
        for (int q = 0; q < 8; ++q) {
            float4 v = xp[q];
            buf[BIDX(4*q+0, tid)] = v.x;
            buf[BIDX(4*q+1, tid)] = v.y;
            buf[BIDX(4*q+2, tid)] = v.z;
            buf[BIDX(4*q+3, tid)] = v.w;
        }
        // ---- geometry -> cols 32..38
        {
            float pix = pos[3*dst+0], piy = pos[3*dst+1], piz = pos[3*dst+2];
            float pjx = pos[3*src+0], pjy = pos[3*src+1], pjz = pos[3*src+2];
            float dx = pjx - pix, dy = pjy - piy, dz = pjz - piz;
            float nix = nrm[3*dst+0], niy = nrm[3*dst+1], niz = nrm[3*dst+2];
            float njx = nrm[3*src+0], njy = nrm[3*src+1], njz = nrm[3*src+2];
            buf[BIDX(32, tid)] = sqrtf(dx*dx + dy*dy + dz*dz) * 0.125f;
            float cx, cy, cz, c2, d, den, inv, sn, cs;
            cx = niy*dz - niz*dy; cy = niz*dx - nix*dz; cz = nix*dy - niy*dx;
            c2 = cx*cx + cy*cy + cz*cz;
            d  = nix*dx + niy*dy + niz*dz;
            den = c2 + d*d;
            if (den > 0.f) { inv = rsqrtf(den); sn = sqrtf(c2)*inv; cs = d*inv; }
            else           { sn = 0.f; cs = 1.f; }   // atan2(0,0) = 0
            buf[BIDX(33, tid)] = sn; buf[BIDX(34, tid)] = cs;
            cx = njy*dz - njz*dy; cy = njz*dx - njx*dz; cz = njx*dy - njy*dx;
            c2 = cx*cx + cy*cy + cz*cz;
            d  = njx*dx + njy*dy + njz*dz;
            den = c2 + d*d;
            if (den > 0.f) { inv = rsqrtf(den); sn = sqrtf(c2)*inv; cs = d*inv; }
            else           { sn = 0.f; cs = 1.f; }
            buf[BIDX(35, tid)] = sn; buf[BIDX(36, tid)] = cs;
            cx = niy*njz - niz*njy; cy = niz*njx - nix*njz; cz = nix*njy - niy*njx;
            c2 = cx*cx + cy*cy + cz*cz;
            d  = nix*njx + niy*njy + niz*njz;
            den = c2 + d*d;
            if (den > 0.f) { inv = rsqrtf(den); sn = sqrtf(c2)*inv; cs = d*inv; }
            else           { sn = 0.f; cs = 1.f; }
            buf[BIDX(37, tid)] = sn; buf[BIDX(38, tid)] = cs;
        }
        // ---- edge_attr -> cols 39..46 (gathered via perm)
        {
            const float4* ep = (const float4*)(ea + (size_t)e * 8);
            float4 a0 = ep[0], a1 = ep[1];
            buf[BIDX(39, tid)] = a0.x; buf[BIDX(40, tid)] = a0.y;
            buf[BIDX(41, tid)] = a0.z; buf[BIDX(42, tid)] = a0.w;
            buf[BIDX(43, tid)] = a1.x; buf[BIDX(44, tid)] = a1.y;
            buf[BIDX(45, tid)] = a1.z; buf[BIDX(46, tid)] = a1.w;
        }

        // ---- GEMM1: 47 -> 64
        float h1v[64];
        {
            const float4* bp = (const float4*)b1;
            #pragma unroll
            for (int j4 = 0; j4 < 16; ++j4) {
                float4 b = bp[j4];
                h1v[4*j4+0]=b.x; h1v[4*j4+1]=b.y; h1v[4*j4+2]=b.z; h1v[4*j4+3]=b.w;
            }
            for (int k = 0; k < 47; ++k) {
                float m = buf[BIDX(k, tid)];
                const float4* wr = (const float4*)(W1 + k*64);
                #pragma unroll
                for (int j4 = 0; j4 < 16; ++j4) {
                    float4 w = wr[j4];
                    h1v[4*j4+0] = fmaf(m, w.x, h1v[4*j4+0]);
                    h1v[4*j4+1] = fmaf(m, w.y, h1v[4*j4+1]);
                    h1v[4*j4+2] = fmaf(m, w.z, h1v[4*j4+2]);
                    h1v[4*j4+3] = fmaf(m, w.w, h1v[4*j4+3]);
                }
            }
        }
        // ---- ReLU + LN(64) -> LDS cols 0..63
        {
            float s = 0.f, s2 = 0.f;
            #pragma unroll
            for (int j = 0; j < 64; ++j) {
                float v = fmaxf(h1v[j], 0.f);
                h1v[j] = v; s += v; s2 += v*v;
            }
            float mu = s * (1.f/64.f);
            float var = fmaxf(s2 * (1.f/64.f) - mu*mu, 0.f);
            float rstd = rsqrtf(var + LN_EPS);
            #pragma unroll
            for (int j = 0; j < 64; ++j)
                buf[BIDX(j, tid)] = fmaf((h1v[j] - mu) * rstd, g1[j], be1[j]);
        }
        // ---- GEMM2: 64 -> 128
        {
            const float4* bp = (const float4*)b2;
            #pragma unroll
            for (int j4 = 0; j4 < 32; ++j4) {
                float4 b = bp[j4];
                h2v[4*j4+0]=b.x; h2v[4*j4+1]=b.y; h2v[4*j4+2]=b.z; h2v[4*j4+3]=b.w;
            }
            for (int k = 0; k < 64; ++k) {
                float m = buf[BIDX(k, tid)];
                const float4* wr = (const float4*)(W2 + k*128);
                #pragma unroll
                for (int j4 = 0; j4 < 32; ++j4) {
                    float4 w = wr[j4];
                    h2v[4*j4+0] = fmaf(m, w.x, h2v[4*j4+0]);
                    h2v[4*j4+1] = fmaf(m, w.y, h2v[4*j4+1]);
                    h2v[4*j4+2] = fmaf(m, w.z, h2v[4*j4+2]);
                    h2v[4*j4+3] = fmaf(m, w.w, h2v[4*j4+3]);
                }
            }
        }
        // ---- ReLU + LN(128), keep in registers
        {
            float s = 0.f, s2 = 0.f;
            #pragma unroll
            for (int j = 0; j < 128; ++j) {
                float v = fmaxf(h2v[j], 0.f);
                h2v[j] = v; s += v; s2 += v*v;
            }
            float mu = s * (1.f/128.f);
            float var = fmaxf(s2 * (1.f/128.f) - mu*mu, 0.f);
            float rstd = rsqrtf(var + LN_EPS);
            #pragma unroll
            for (int j = 0; j < 128; ++j)
                h2v[j] = fmaf((h2v[j] - mu) * rstd, g2[j], be2[j]);
        }
    }

    // ---- segmented max over dst-runs ----
    __syncthreads();   // A: dloc/dprev/dnext/nrun visible
    {
        // FIX (R2): tid 0 ALWAYS starts a run when valid; dprev_s only decides
        // contPrev below. Previously a run continuing from the previous block
        // started no run here and its edges were dropped.
        if (valid && (tid == 0 || dst != dloc[tid - 1])) {
            int r = atomicAdd(&nrun_s, 1);
            rstart[r] = tid;
        }
    }
    __syncthreads();   // B: rstart/nrun final
    const int nr = nrun_s;
    const int w = tid >> 6;     // wave id 0..2
    const int j = tid & 63;     // feature within chunk

    #pragma unroll
    for (int chunk = 0; chunk < 2; ++chunk) {
        if (valid) {
            #pragma unroll
            for (int q = 0; q < 64; ++q)
                buf[BIDX(q, tid)] = h2v[chunk*64 + q];
        }
        __syncthreads();   // C: features staged
        for (int r = w; r < nr; r += 3) {
            int s0 = rstart[r];
            int d  = dloc[s0];
            float val = buf[BIDX(j, s0)];
            int c = s0 + 1;
            while (c < EBLK && dloc[c] == d) {
                val = fmaxf(val, buf[BIDX(j, c)]);
                ++c;
            }
            bool contPrev = (s0 == 0) && (dprev_s == d);
            bool contNext = (c == EBLK) && (dnext_s == d);
            unsigned enc = ord(val);
            unsigned* ap = agg + (size_t)d * 128 + chunk * 64 + j;
            if (contPrev || contNext) atomicMax(ap, enc);
            else                      *ap = enc;
        }
        __syncthreads();   // D: reduce done before buf reuse
    }
}

// ---------------- node MLP: agg[128] @ Wg -> ReLU -> LN -> out ----------------
__global__ __launch_bounds__(256, 4)
void node_kernel(const unsigned* __restrict__ agg,
                 const float* __restrict__ Wg, const float* __restrict__ bg,
                 const float* __restrict__ gg, const float* __restrict__ beg,
                 float* __restrict__ out, int N)
{
    __shared__ float a_lds[16 * 130];
    const int nb = blockIdx.x * 16;
    const size_t total = (size_t)N * 128;
    for (int t = threadIdx.x; t < 16 * 128; t += 256) {
        size_t g = (size_t)nb * 128 + t;
        unsigned u = (g < total) ? agg[g] : 0u;
        a_lds[(t >> 7) * 130 + (t & 127)] = (u == 0u) ? 0.f : unord(u);
    }
    __syncthreads();
    const int n_local = threadIdx.x >> 4;
    const int og = threadIdx.x & 15;
    const int node = nb + n_local;
    if (node >= N) return;

    float acc[16];
    {
        const float4* bp = (const float4*)(bg + og * 16);
        #pragma unroll
        for (int r4 = 0; r4 < 4; ++r4) {
            float4 b = bp[r4];
            acc[4*r4+0]=b.x; acc[4*r4+1]=b.y; acc[4*r4+2]=b.z; acc[4*r4+3]=b.w;
        }
    }
    for (int k = 0; k < 128; ++k) {
        float a = a_lds[n_local * 130 + k];
        const float4* wr = (const float4*)(Wg + (size_t)k * 256 + og * 16);
        #pragma unroll
        for (int r4 = 0; r4 < 4; ++r4) {
            float4 wv = wr[r4];
            acc[4*r4+0] = fmaf(a, wv.x, acc[4*r4+0]);
            acc[4*r4+1] = fmaf(a, wv.y, acc[4*r4+1]);
            acc[4*r4+2] = fmaf(a, wv.z, acc[4*r4+2]);
            acc[4*r4+3] = fmaf(a, wv.w, acc[4*r4+3]);
        }
    }
    float s = 0.f, s2 = 0.f;
    #pragma unroll
    for (int r = 0; r < 16; ++r) {
        float v = fmaxf(acc[r], 0.f);
        acc[r] = v; s += v; s2 += v*v;
    }
    #pragma unroll
    for (int m = 1; m < 16; m <<= 1) {
        s  += __shfl_xor(s,  m, 16);
        s2 += __shfl_xor(s2, m, 16);
    }
    float mu = s * (1.f/256.f);
    float var = fmaxf(s2 * (1.f/256.f) - mu*mu, 0.f);
    float rstd = rsqrtf(var + LN_EPS);
    float4* op = (float4*)(out + (size_t)node * 256 + og * 16);
    #pragma unroll
    for (int r4 = 0; r4 < 4; ++r4) {
        float4 o;
        o.x = fmaf((acc[4*r4+0] - mu) * rstd, gg[og*16 + 4*r4+0], beg[og*16 + 4*r4+0]);
        o.y = fmaf((acc[4*r4+1] - mu) * rstd, gg[og*16 + 4*r4+1], beg[og*16 + 4*r4+1]);
        o.z = fmaf((acc[4*r4+2] - mu) * rstd, gg[og*16 + 4*r4+2], beg[og*16 + 4*r4+2]);
        o.w = fmaf((acc[4*r4+3] - mu) * rstd, gg[og*16 + 4*r4+3], beg[og*16 + 4*r4+3]);
        op[r4] = o;
    }
}

extern "C" void kernel_launch(void* const* d_in, const int* in_sizes, int n_in,
                              void* d_out, int out_size, void* d_ws, size_t ws_size,
                              hipStream_t stream) {
    const float* x         = (const float*)d_in[0];
    const float* pos       = (const float*)d_in[1];
    const float* nrm       = (const float*)d_in[2];
    const float* edge_attr = (const float*)d_in[3];
    const int*   ei        = (const int*)d_in[4];
    const float* W1  = (const float*)d_in[5];
    const float* b1  = (const float*)d_in[6];
    const float* g1  = (const float*)d_in[7];
    const float* be1 = (const float*)d_in[8];
    const float* W2  = (const float*)d_in[9];
    const float* b2  = (const float*)d_in[10];
    const float* g2  = (const float*)d_in[11];
    const float* be2 = (const float*)d_in[12];
    const float* Wg  = (const float*)d_in[13];
    const float* bg  = (const float*)d_in[14];
    const float* gg  = (const float*)d_in[15];
    const float* beg = (const float*)d_in[16];

    const int E = in_sizes[3] / 8;    // edge_attr is [E,8]
    const int N = in_sizes[0] / 32;   // x is [N,32]

    // workspace layout (~38.8 MB total)
    char* ws = (char*)d_ws;
    unsigned* agg  = (unsigned*)ws;                 ws += (size_t)N * 128 * 4;  // 25.6 MB
    unsigned* deg  = (unsigned*)ws;                 ws += (size_t)N * 4;
    unsigned* off  = (unsigned*)ws;                 ws += (size_t)N * 4;
    unsigned* part = (unsigned*)ws;                 ws += 256 * 4;
    unsigned* perm = (unsigned*)ws;                 ws += (size_t)E * 4;
    int*      dsts = (int*)ws;                      ws += (size_t)E * 4;

    hipMemsetAsync(agg, 0, (size_t)N * 128 * 4, stream);
    hipMemsetAsync(deg, 0, (size_t)N * 4, stream);

    const int nbN = (N + 255) / 256;   // 196 <= 256 (scan2 single-block capacity)
    hipLaunchKernelGGL(hist_kernel, dim3((E + 255) / 256), dim3(256), 0, stream, ei, deg, E);
    hipLaunchKernelGGL(scan1, dim3(nbN), dim3(256), 0, stream, deg, part, N);
    hipLaunchKernelGGL(scan2, dim3(1), dim3(256), 0, stream, part, nbN);
    hipLaunchKernelGGL(scan3, dim3(nbN), dim3(256), 0, stream, deg, part, off, N);
    hipLaunchKernelGGL(scatter_kernel, dim3((E + 255) / 256), dim3(256), 0, stream,
                       ei, off, perm, dsts, E);

    hipLaunchKernelGGL(edge_kernel, dim3((E + EBLK - 1) / EBLK), dim3(EBLK), 0, stream,
                       x, pos, nrm, edge_attr, ei, perm, dsts,
                       W1, b1, g1, be1, W2, b2, g2, be2, agg, E);

    hipLaunchKernelGGL(node_kernel, dim3((N + 15) / 16), dim3(256), 0, stream,
                       agg, Wg, bg, gg, beg, (float*)d_out, N);
}

// Round 4
// 1772.786 us; speedup vs baseline: 4.9499x; 1.1401x over previous
//
#include <hip/hip_runtime.h>
#include <hip/hip_bf16.h>
#include <math.h>

// DockPointNet fused, round 4: edge kernel restructured for latency hiding.
// - Single 33 KB LDS buffer (bf16, per-thread columns) reused for msg -> h1n
//   -> reduce staging; no barriers inside the MLP phase.
// - h2 acc in VGPRs; launch_bounds(256,3) -> ~12 waves/CU (vs 6 in R3).
// - Ballot-based run bookkeeping: reduce scan has explicit [rstart,rend],
//   unrolled independent LDS reads instead of a dependent while-chain.
// CSR prep + node kernel unchanged from R3 (correct, cheap-ish).

#define LN_EPS 1e-5f
#define PR 258   // u16 row stride for hbuf (2-way banks on both access patterns)

__device__ __forceinline__ unsigned ord(float f) {
    int i = __float_as_int(f);
    return (i >= 0) ? ((unsigned)i | 0x80000000u) : ~((unsigned)i);
}
__device__ __forceinline__ float unord(unsigned u) {
    int i = (u & 0x80000000u) ? (int)(u & 0x7fffffffu) : ~(int)u;
    return __int_as_float(i);
}
__device__ __forceinline__ unsigned short f2b(float f) {   // RNE f32->bf16
    unsigned u = __float_as_uint(f);
    return (unsigned short)((u + 0x7FFFu + ((u >> 16) & 1u)) >> 16);
}
__device__ __forceinline__ float b2f(unsigned short h) {
    return __uint_as_float((unsigned)h << 16);
}

// ---------------- CSR build (unchanged) ----------------
__global__ void hist_kernel(const int* __restrict__ ei, unsigned* __restrict__ deg, int E) {
    int e = blockIdx.x * 256 + threadIdx.x;
    if (e < E) atomicAdd(&deg[ei[E + e]], 1u);
}

__global__ void scan1(const unsigned* __restrict__ deg, unsigned* __restrict__ part, int N) {
    __shared__ unsigned s[256];
    int i = blockIdx.x * 256 + threadIdx.x;
    s[threadIdx.x] = (i < N) ? deg[i] : 0u;
    __syncthreads();
    for (int st = 128; st > 0; st >>= 1) {
        if (threadIdx.x < st) s[threadIdx.x] += s[threadIdx.x + st];
        __syncthreads();
    }
    if (threadIdx.x == 0) part[blockIdx.x] = s[0];
}

__global__ void scan2(unsigned* __restrict__ part, int nb) {
    __shared__ unsigned s[256];
    int t = threadIdx.x;
    unsigned v = (t < nb) ? part[t] : 0u;
    s[t] = v;
    __syncthreads();
    for (int st = 1; st < 256; st <<= 1) {
        unsigned add = (t >= st) ? s[t - st] : 0u;
        __syncthreads();
        s[t] += add;
        __syncthreads();
    }
    if (t < nb) part[t] = s[t] - v;   // exclusive
}

__global__ void scan3(const unsigned* __restrict__ deg, const unsigned* __restrict__ part,
                      unsigned* __restrict__ off, int N) {
    __shared__ unsigned s[256];
    int i = blockIdx.x * 256 + threadIdx.x, t = threadIdx.x;
    unsigned v = (i < N) ? deg[i] : 0u;
    s[t] = v;
    __syncthreads();
    for (int st = 1; st < 256; st <<= 1) {
        unsigned add = (t >= st) ? s[t - st] : 0u;
        __syncthreads();
        s[t] += add;
        __syncthreads();
    }
    if (i < N) off[i] = part[blockIdx.x] + s[t] - v;   // exclusive
}

__global__ void scatter_kernel(const int* __restrict__ ei, unsigned* __restrict__ cursor,
                               unsigned* __restrict__ perm, int* __restrict__ dsts, int E) {
    int e = blockIdx.x * 256 + threadIdx.x;
    if (e >= E) return;
    int d = ei[E + e];
    unsigned pos = atomicAdd(&cursor[d], 1u);
    perm[pos] = (unsigned)e;
    dsts[pos] = d;
}

// ---------------- fused edge MLP + segmented max ----------------
__global__ __launch_bounds__(256, 3)
void edge_kernel(const float* __restrict__ x,
                 const float* __restrict__ pos,
                 const float* __restrict__ nrm,
                 const float* __restrict__ ea,
                 const int* __restrict__ ei,
                 const unsigned* __restrict__ perm,
                 const int* __restrict__ dsts,
                 const float* __restrict__ W1, const float* __restrict__ b1,
                 const float* __restrict__ g1, const float* __restrict__ be1,
                 const float* __restrict__ W2, const float* __restrict__ b2,
                 const float* __restrict__ g2, const float* __restrict__ be2,
                 unsigned* __restrict__ agg, int E)
{
    __shared__ unsigned short hbuf[64 * PR];    // 33 KB: msg -> h1n -> staging
    __shared__ int dloc[256];
    __shared__ unsigned long long wmask[4];
    __shared__ short rstart[256], rend[256];
    __shared__ int dprev_s, dnext_s;

    const int tid  = threadIdx.x;
    const int base = blockIdx.x * 256;
    const int p    = base + tid;
    const bool valid = p < E;
    const int nvalid = (E - base < 256) ? (E - base) : 256;

    int dst = -1, src = 0, e = 0;
    if (valid) {
        e = (int)perm[p];
        dst = dsts[p];
        src = ei[e];
    }
    dloc[tid] = dst;
    if (tid == 0) {
        dprev_s = (blockIdx.x == 0) ? -1 : dsts[(size_t)base - 1];
        dnext_s = (base + 256 < E) ? dsts[base + 256] : -1;
    }
    __syncthreads();   // B1: dloc ready

    // ---- run bookkeeping via ballot (no atomics, no serial scans)
    bool is_start = valid && (tid == 0 || dloc[tid - 1] != dst);
    bool is_end   = valid && (tid == nvalid - 1 || dloc[tid + 1] != dst);
    unsigned long long mb = __ballot(is_start);
    if ((tid & 63) == 0) wmask[tid >> 6] = mb;
    __syncthreads();   // B2: wmask ready
    int nr = 0;
    {
        int rid = 0;
        #pragma unroll
        for (int wv = 0; wv < 4; ++wv) {
            unsigned long long m = wmask[wv];
            if (wv < (tid >> 6)) rid += __popcll(m);
            nr += __popcll(m);
        }
        rid += __popcll(wmask[tid >> 6] & ((1ull << (tid & 63)) - 1ull));
        if (is_start) rstart[rid] = (short)tid;
        if (is_end)   rend[is_start ? rid : rid - 1] = (short)tid;
    }

    float h2[128];
    if (valid) {
        // ---- stage msg (bf16) into own column: x(32) | ppf(7) | ea(8)
        {
            const float4* xp = (const float4*)(x + (size_t)src * 32);
            #pragma unroll
            for (int q = 0; q < 8; ++q) {
                float4 v = xp[q];
                hbuf[(4*q+0)*PR + tid] = f2b(v.x);
                hbuf[(4*q+1)*PR + tid] = f2b(v.y);
                hbuf[(4*q+2)*PR + tid] = f2b(v.z);
                hbuf[(4*q+3)*PR + tid] = f2b(v.w);
            }
            float pix = pos[3*dst+0], piy = pos[3*dst+1], piz = pos[3*dst+2];
            float pjx = pos[3*src+0], pjy = pos[3*src+1], pjz = pos[3*src+2];
            float dx = pjx - pix, dy = pjy - piy, dz = pjz - piz;
            float nix = nrm[3*dst+0], niy = nrm[3*dst+1], niz = nrm[3*dst+2];
            float njx = nrm[3*src+0], njy = nrm[3*src+1], njz = nrm[3*src+2];
            hbuf[32*PR + tid] = f2b(sqrtf(dx*dx + dy*dy + dz*dz) * 0.125f);
            float cx, cy, cz, c2, d, den, inv, sn, cs;
            cx = niy*dz - niz*dy; cy = niz*dx - nix*dz; cz = nix*dy - niy*dx;
            c2 = cx*cx + cy*cy + cz*cz;  d = nix*dx + niy*dy + niz*dz;
            den = c2 + d*d;
            if (den > 0.f) { inv = rsqrtf(den); sn = sqrtf(c2)*inv; cs = d*inv; }
            else           { sn = 0.f; cs = 1.f; }
            hbuf[33*PR + tid] = f2b(sn); hbuf[34*PR + tid] = f2b(cs);
            cx = njy*dz - njz*dy; cy = njz*dx - njx*dz; cz = njx*dy - njy*dx;
            c2 = cx*cx + cy*cy + cz*cz;  d = njx*dx + njy*dy + njz*dz;
            den = c2 + d*d;
            if (den > 0.f) { inv = rsqrtf(den); sn = sqrtf(c2)*inv; cs = d*inv; }
            else           { sn = 0.f; cs = 1.f; }
            hbuf[35*PR + tid] = f2b(sn); hbuf[36*PR + tid] = f2b(cs);
            cx = niy*njz - niz*njy; cy = niz*njx - nix*njz; cz = nix*njy - niy*njx;
            c2 = cx*cx + cy*cy + cz*cz;  d = nix*njx + niy*njy + niz*njz;
            den = c2 + d*d;
            if (den > 0.f) { inv = rsqrtf(den); sn = sqrtf(c2)*inv; cs = d*inv; }
            else           { sn = 0.f; cs = 1.f; }
            hbuf[37*PR + tid] = f2b(sn); hbuf[38*PR + tid] = f2b(cs);

            const float4* ep = (const float4*)(ea + (size_t)e * 8);
            float4 a0 = ep[0], a1 = ep[1];
            hbuf[39*PR + tid] = f2b(a0.x); hbuf[40*PR + tid] = f2b(a0.y);
            hbuf[41*PR + tid] = f2b(a0.z); hbuf[42*PR + tid] = f2b(a0.w);
            hbuf[43*PR + tid] = f2b(a1.x); hbuf[44*PR + tid] = f2b(a1.y);
            hbuf[45*PR + tid] = f2b(a1.z); hbuf[46*PR + tid] = f2b(a1.w);
        }

        // ---- GEMM1: 47 -> 64 (weights via uniform scalar loads)
        float h1[64];
        {
            const float4* bp = (const float4*)b1;
            #pragma unroll
            for (int j4 = 0; j4 < 16; ++j4) {
                float4 b = bp[j4];
                h1[4*j4+0]=b.x; h1[4*j4+1]=b.y; h1[4*j4+2]=b.z; h1[4*j4+3]=b.w;
            }
            for (int k = 0; k < 47; ++k) {
                float m = b2f(hbuf[k*PR + tid]);
                const float4* wr = (const float4*)(W1 + k*64);
                #pragma unroll
                for (int j4 = 0; j4 < 16; ++j4) {
                    float4 w = wr[j4];
                    h1[4*j4+0] = fmaf(m, w.x, h1[4*j4+0]);
                    h1[4*j4+1] = fmaf(m, w.y, h1[4*j4+1]);
                    h1[4*j4+2] = fmaf(m, w.z, h1[4*j4+2]);
                    h1[4*j4+3] = fmaf(m, w.w, h1[4*j4+3]);
                }
            }
        }
        // ---- ReLU + LN(64) -> own column rows 0..63 (bf16)
        {
            float s = 0.f, s2 = 0.f;
            #pragma unroll
            for (int j = 0; j < 64; ++j) {
                float v = fmaxf(h1[j], 0.f);
                h1[j] = v; s += v; s2 += v*v;
            }
            float mu = s * (1.f/64.f);
            float var = fmaxf(s2 * (1.f/64.f) - mu*mu, 0.f);
            float rstd = rsqrtf(var + LN_EPS);
            #pragma unroll
            for (int j = 0; j < 64; ++j)
                hbuf[j*PR + tid] = f2b(fmaf((h1[j] - mu) * rstd, g1[j], be1[j]));
        }
        // ---- GEMM2: 64 -> 128, acc in VGPRs
        {
            const float4* bp = (const float4*)b2;
            #pragma unroll
            for (int j4 = 0; j4 < 32; ++j4) {
                float4 b = bp[j4];
                h2[4*j4+0]=b.x; h2[4*j4+1]=b.y; h2[4*j4+2]=b.z; h2[4*j4+3]=b.w;
            }
            for (int k = 0; k < 64; ++k) {
                float m = b2f(hbuf[k*PR + tid]);
                const float4* wr = (const float4*)(W2 + k*128);
                #pragma unroll
                for (int j4 = 0; j4 < 32; ++j4) {
                    float4 w = wr[j4];
                    h2[4*j4+0] = fmaf(m, w.x, h2[4*j4+0]);
                    h2[4*j4+1] = fmaf(m, w.y, h2[4*j4+1]);
                    h2[4*j4+2] = fmaf(m, w.z, h2[4*j4+2]);
                    h2[4*j4+3] = fmaf(m, w.w, h2[4*j4+3]);
                }
            }
        }
        // ---- ReLU + LN(128) in registers
        {
            float s = 0.f, s2 = 0.f;
            #pragma unroll
            for (int j = 0; j < 128; ++j) {
                float v = fmaxf(h2[j], 0.f);
                h2[j] = v; s += v; s2 += v*v;
            }
            float mu = s * (1.f/128.f);
            float var = fmaxf(s2 * (1.f/128.f) - mu*mu, 0.f);
            float rstd = rsqrtf(var + LN_EPS);
            #pragma unroll
            for (int j = 0; j < 128; ++j)
                h2[j] = fmaf((h2[j] - mu) * rstd, g2[j], be2[j]);
        }
    }

    // ---- segmented max, 2 chunks of 64 features ----
    const int w = tid >> 6;     // wave 0..3
    const int j = tid & 63;     // feature row within chunk

    #pragma unroll
    for (int chunk = 0; chunk < 2; ++chunk) {
        if (valid) {
            #pragma unroll
            for (int q = 0; q < 64; ++q)
                hbuf[q*PR + tid] = f2b(h2[chunk*64 + q]);
        }
        __syncthreads();   // staging (and, first pass, rstart/rend) visible
        for (int r = w; r < nr; r += 4) {
            int s0 = rstart[r], en = rend[r];
            int d  = dloc[s0];
            float v0 = -1e30f, v1 = -1e30f, v2 = -1e30f, v3 = -1e30f;
            int c = s0;
            for (; c + 3 <= en; c += 4) {
                v0 = fmaxf(v0, b2f(hbuf[j*PR + c]));
                v1 = fmaxf(v1, b2f(hbuf[j*PR + c + 1]));
                v2 = fmaxf(v2, b2f(hbuf[j*PR + c + 2]));
                v3 = fmaxf(v3, b2f(hbuf[j*PR + c + 3]));
            }
            for (; c <= en; ++c) v0 = fmaxf(v0, b2f(hbuf[j*PR + c]));
            float val = fmaxf(fmaxf(v0, v1), fmaxf(v2, v3));
            bool contPrev = (s0 == 0) && (dprev_s == d);
            bool contNext = (en == nvalid - 1) && (dnext_s == d);
            unsigned enc = ord(val);
            unsigned* ap = agg + (size_t)d * 128 + chunk * 64 + j;
            if (contPrev || contNext) atomicMax(ap, enc);
            else                      *ap = enc;
        }
        __syncthreads();   // scan done before buf reuse
    }
}

// ---------------- node MLP (unchanged) ----------------
__global__ __launch_bounds__(256, 4)
void node_kernel(const unsigned* __restrict__ agg,
                 const float* __restrict__ Wg, const float* __restrict__ bg,
                 const float* __restrict__ gg, const float* __restrict__ beg,
                 float* __restrict__ out, int N)
{
    __shared__ float a_lds[16 * 130];
    const int nb = blockIdx.x * 16;
    const size_t total = (size_t)N * 128;
    for (int t = threadIdx.x; t < 16 * 128; t += 256) {
        size_t g = (size_t)nb * 128 + t;
        unsigned u = (g < total) ? agg[g] : 0u;
        a_lds[(t >> 7) * 130 + (t & 127)] = (u == 0u) ? 0.f : unord(u);
    }
    __syncthreads();
    const int n_local = threadIdx.x >> 4;
    const int og = threadIdx.x & 15;
    const int node = nb + n_local;
    if (node >= N) return;

    float acc[16];
    {
        const float4* bp = (const float4*)(bg + og * 16);
        #pragma unroll
        for (int r4 = 0; r4 < 4; ++r4) {
            float4 b = bp[r4];
            acc[4*r4+0]=b.x; acc[4*r4+1]=b.y; acc[4*r4+2]=b.z; acc[4*r4+3]=b.w;
        }
    }
    for (int k = 0; k < 128; ++k) {
        float a = a_lds[n_local * 130 + k];
        const float4* wr = (const float4*)(Wg + (size_t)k * 256 + og * 16);
        #pragma unroll
        for (int r4 = 0; r4 < 4; ++r4) {
            float4 wv = wr[r4];
            acc[4*r4+0] = fmaf(a, wv.x, acc[4*r4+0]);
            acc[4*r4+1] = fmaf(a, wv.y, acc[4*r4+1]);
            acc[4*r4+2] = fmaf(a, wv.z, acc[4*r4+2]);
            acc[4*r4+3] = fmaf(a, wv.w, acc[4*r4+3]);
        }
    }
    float s = 0.f, s2 = 0.f;
    #pragma unroll
    for (int r = 0; r < 16; ++r) {
        float v = fmaxf(acc[r], 0.f);
        acc[r] = v; s += v; s2 += v*v;
    }
    #pragma unroll
    for (int m = 1; m < 16; m <<= 1) {
        s  += __shfl_xor(s,  m, 16);
        s2 += __shfl_xor(s2, m, 16);
    }
    float mu = s * (1.f/256.f);
    float var = fmaxf(s2 * (1.f/256.f) - mu*mu, 0.f);
    float rstd = rsqrtf(var + LN_EPS);
    float4* op = (float4*)(out + (size_t)node * 256 + og * 16);
    #pragma unroll
    for (int r4 = 0; r4 < 4; ++r4) {
        float4 o;
        o.x = fmaf((acc[4*r4+0] - mu) * rstd, gg[og*16 + 4*r4+0], beg[og*16 + 4*r4+0]);
        o.y = fmaf((acc[4*r4+1] - mu) * rstd, gg[og*16 + 4*r4+1], beg[og*16 + 4*r4+1]);
        o.z = fmaf((acc[4*r4+2] - mu) * rstd, gg[og*16 + 4*r4+2], beg[og*16 + 4*r4+2]);
        o.w = fmaf((acc[4*r4+3] - mu) * rstd, gg[og*16 + 4*r4+3], beg[og*16 + 4*r4+3]);
        op[r4] = o;
    }
}

extern "C" void kernel_launch(void* const* d_in, const int* in_sizes, int n_in,
                              void* d_out, int out_size, void* d_ws, size_t ws_size,
                              hipStream_t stream) {
    const float* x         = (const float*)d_in[0];
    const float* pos       = (const float*)d_in[1];
    const float* nrm       = (const float*)d_in[2];
    const float* edge_attr = (const float*)d_in[3];
    const int*   ei        = (const int*)d_in[4];
    const float* W1  = (const float*)d_in[5];
    const float* b1  = (const float*)d_in[6];
    const float* g1  = (const float*)d_in[7];
    const float* be1 = (const float*)d_in[8];
    const float* W2  = (const float*)d_in[9];
    const float* b2  = (const float*)d_in[10];
    const float* g2  = (const float*)d_in[11];
    const float* be2 = (const float*)d_in[12];
    const float* Wg  = (const float*)d_in[13];
    const float* bg  = (const float*)d_in[14];
    const float* gg  = (const float*)d_in[15];
    const float* beg = (const float*)d_in[16];

    const int E = in_sizes[3] / 8;    // edge_attr is [E,8]
    const int N = in_sizes[0] / 32;   // x is [N,32]

    char* ws = (char*)d_ws;
    unsigned* agg  = (unsigned*)ws;                 ws += (size_t)N * 128 * 4;
    unsigned* deg  = (unsigned*)ws;                 ws += (size_t)N * 4;
    unsigned* off  = (unsigned*)ws;                 ws += (size_t)N * 4;
    unsigned* part = (unsigned*)ws;                 ws += 256 * 4;
    unsigned* perm = (unsigned*)ws;                 ws += (size_t)E * 4;
    int*      dsts = (int*)ws;                      ws += (size_t)E * 4;

    hipMemsetAsync(agg, 0, (size_t)N * 128 * 4, stream);
    hipMemsetAsync(deg, 0, (size_t)N * 4, stream);

    const int nbN = (N + 255) / 256;
    hipLaunchKernelGGL(hist_kernel, dim3((E + 255) / 256), dim3(256), 0, stream, ei, deg, E);
    hipLaunchKernelGGL(scan1, dim3(nbN), dim3(256), 0, stream, deg, part, N);
    hipLaunchKernelGGL(scan2, dim3(1), dim3(256), 0, stream, part, nbN);
    hipLaunchKernelGGL(scan3, dim3(nbN), dim3(256), 0, stream, deg, part, off, N);
    hipLaunchKernelGGL(scatter_kernel, dim3((E + 255) / 256), dim3(256), 0, stream,
                       ei, off, perm, dsts, E);

    hipLaunchKernelGGL(edge_kernel, dim3((E + 255) / 256), dim3(256), 0, stream,
                       x, pos, nrm, edge_attr, ei, perm, dsts,
                       W1, b1, g1, be1, W2, b2, g2, be2, agg, E);

    hipLaunchKernelGGL(node_kernel, dim3((N + 15) / 16), dim3(256), 0, stream,
                       agg, Wg, bg, gg, beg, (float*)d_out, N);
}

// Round 5
// 1718.514 us; speedup vs baseline: 5.1063x; 1.0316x over previous
//
#include <hip/hip_runtime.h>
#include <hip/hip_bf16.h>
#include <math.h>

// DockPointNet fused, round 5: R4 + spill fix.
// R4 bug: the reduce-staging loop over chunk{0,1} contains __syncthreads(),
// so it could NOT be unrolled -> h2[chunk*64+q] dynamic index -> h2 demoted
// to scratch (819 MB/launch each way, VGPR=84). Fix: duplicate the two chunk
// passes with static indices so h2 stays in VGPRs. launch_bounds(256,3).

#define LN_EPS 1e-5f
#define PR 258   // u16 row stride for hbuf (2-way banks on both access patterns)

__device__ __forceinline__ unsigned ord(float f) {
    int i = __float_as_int(f);
    return (i >= 0) ? ((unsigned)i | 0x80000000u) : ~((unsigned)i);
}
__device__ __forceinline__ float unord(unsigned u) {
    int i = (u & 0x80000000u) ? (int)(u & 0x7fffffffu) : ~(int)u;
    return __int_as_float(i);
}
__device__ __forceinline__ unsigned short f2b(float f) {   // RNE f32->bf16
    unsigned u = __float_as_uint(f);
    return (unsigned short)((u + 0x7FFFu + ((u >> 16) & 1u)) >> 16);
}
__device__ __forceinline__ float b2f(unsigned short h) {
    return __uint_as_float((unsigned)h << 16);
}

// ---------------- CSR build (unchanged) ----------------
__global__ void hist_kernel(const int* __restrict__ ei, unsigned* __restrict__ deg, int E) {
    int e = blockIdx.x * 256 + threadIdx.x;
    if (e < E) atomicAdd(&deg[ei[E + e]], 1u);
}

__global__ void scan1(const unsigned* __restrict__ deg, unsigned* __restrict__ part, int N) {
    __shared__ unsigned s[256];
    int i = blockIdx.x * 256 + threadIdx.x;
    s[threadIdx.x] = (i < N) ? deg[i] : 0u;
    __syncthreads();
    for (int st = 128; st > 0; st >>= 1) {
        if (threadIdx.x < st) s[threadIdx.x] += s[threadIdx.x + st];
        __syncthreads();
    }
    if (threadIdx.x == 0) part[blockIdx.x] = s[0];
}

__global__ void scan2(unsigned* __restrict__ part, int nb) {
    __shared__ unsigned s[256];
    int t = threadIdx.x;
    unsigned v = (t < nb) ? part[t] : 0u;
    s[t] = v;
    __syncthreads();
    for (int st = 1; st < 256; st <<= 1) {
        unsigned add = (t >= st) ? s[t - st] : 0u;
        __syncthreads();
        s[t] += add;
        __syncthreads();
    }
    if (t < nb) part[t] = s[t] - v;   // exclusive
}

__global__ void scan3(const unsigned* __restrict__ deg, const unsigned* __restrict__ part,
                      unsigned* __restrict__ off, int N) {
    __shared__ unsigned s[256];
    int i = blockIdx.x * 256 + threadIdx.x, t = threadIdx.x;
    unsigned v = (i < N) ? deg[i] : 0u;
    s[t] = v;
    __syncthreads();
    for (int st = 1; st < 256; st <<= 1) {
        unsigned add = (t >= st) ? s[t - st] : 0u;
        __syncthreads();
        s[t] += add;
        __syncthreads();
    }
    if (i < N) off[i] = part[blockIdx.x] + s[t] - v;   // exclusive
}

__global__ void scatter_kernel(const int* __restrict__ ei, unsigned* __restrict__ cursor,
                               unsigned* __restrict__ perm, int* __restrict__ dsts, int E) {
    int e = blockIdx.x * 256 + threadIdx.x;
    if (e >= E) return;
    int d = ei[E + e];
    unsigned pos = atomicAdd(&cursor[d], 1u);
    perm[pos] = (unsigned)e;
    dsts[pos] = d;
}

// staging + segmented-max reduce for one 64-feature chunk (static indices!)
#define STAGE_REDUCE(CB)                                                        \
    {                                                                           \
        if (valid) {                                                            \
            _Pragma("unroll")                                                   \
            for (int q = 0; q < 64; ++q)                                        \
                hbuf[q*PR + tid] = f2b(h2[(CB) + q]);                           \
        }                                                                       \
        __syncthreads();                                                        \
        for (int r = w; r < nr; r += 4) {                                       \
            int s0 = rstart[r], en = rend[r];                                   \
            int d  = dloc[s0];                                                  \
            float v0 = -1e30f, v1 = -1e30f, v2 = -1e30f, v3 = -1e30f;           \
            int c = s0;                                                         \
            for (; c + 3 <= en; c += 4) {                                       \
                v0 = fmaxf(v0, b2f(hbuf[j*PR + c]));                            \
                v1 = fmaxf(v1, b2f(hbuf[j*PR + c + 1]));                        \
                v2 = fmaxf(v2, b2f(hbuf[j*PR + c + 2]));                        \
                v3 = fmaxf(v3, b2f(hbuf[j*PR + c + 3]));                        \
            }                                                                   \
            for (; c <= en; ++c) v0 = fmaxf(v0, b2f(hbuf[j*PR + c]));           \
            float val = fmaxf(fmaxf(v0, v1), fmaxf(v2, v3));                    \
            bool contPrev = (s0 == 0) && (dprev_s == d);                        \
            bool contNext = (en == nvalid - 1) && (dnext_s == d);               \
            unsigned enc = ord(val);                                            \
            unsigned* ap = agg + (size_t)d * 128 + (CB) + j;                    \
            if (contPrev || contNext) atomicMax(ap, enc);                       \
            else                      *ap = enc;                                \
        }                                                                       \
        __syncthreads();                                                        \
    }

// ---------------- fused edge MLP + segmented max ----------------
__global__ __launch_bounds__(256, 3)
void edge_kernel(const float* __restrict__ x,
                 const float* __restrict__ pos,
                 const float* __restrict__ nrm,
                 const float* __restrict__ ea,
                 const int* __restrict__ ei,
                 const unsigned* __restrict__ perm,
                 const int* __restrict__ dsts,
                 const float* __restrict__ W1, const float* __restrict__ b1,
                 const float* __restrict__ g1, const float* __restrict__ be1,
                 const float* __restrict__ W2, const float* __restrict__ b2,
                 const float* __restrict__ g2, const float* __restrict__ be2,
                 unsigned* __restrict__ agg, int E)
{
    __shared__ unsigned short hbuf[64 * PR];    // 33 KB: msg -> h1n -> staging
    __shared__ int dloc[256];
    __shared__ unsigned long long wmask[4];
    __shared__ short rstart[256], rend[256];
    __shared__ int dprev_s, dnext_s;

    const int tid  = threadIdx.x;
    const int base = blockIdx.x * 256;
    const int p    = base + tid;
    const bool valid = p < E;
    const int nvalid = (E - base < 256) ? (E - base) : 256;

    int dst = -1, src = 0, e = 0;
    if (valid) {
        e = (int)perm[p];
        dst = dsts[p];
        src = ei[e];
    }
    dloc[tid] = dst;
    if (tid == 0) {
        dprev_s = (blockIdx.x == 0) ? -1 : dsts[(size_t)base - 1];
        dnext_s = (base + 256 < E) ? dsts[base + 256] : -1;
    }
    __syncthreads();   // B1: dloc ready

    // ---- run bookkeeping via ballot
    bool is_start = valid && (tid == 0 || dloc[tid - 1] != dst);
    bool is_end   = valid && (tid == nvalid - 1 || dloc[tid + 1] != dst);
    unsigned long long mb = __ballot(is_start);
    if ((tid & 63) == 0) wmask[tid >> 6] = mb;
    __syncthreads();   // B2: wmask ready
    int nr = 0;
    {
        int rid = 0;
        #pragma unroll
        for (int wv = 0; wv < 4; ++wv) {
            unsigned long long m = wmask[wv];
            if (wv < (tid >> 6)) rid += __popcll(m);
            nr += __popcll(m);
        }
        rid += __popcll(wmask[tid >> 6] & ((1ull << (tid & 63)) - 1ull));
        if (is_start) rstart[rid] = (short)tid;
        if (is_end)   rend[is_start ? rid : rid - 1] = (short)tid;
    }

    float h2[128];
    if (valid) {
        // ---- stage msg (bf16) into own column: x(32) | ppf(7) | ea(8)
        {
            const float4* xp = (const float4*)(x + (size_t)src * 32);
            #pragma unroll
            for (int q = 0; q < 8; ++q) {
                float4 v = xp[q];
                hbuf[(4*q+0)*PR + tid] = f2b(v.x);
                hbuf[(4*q+1)*PR + tid] = f2b(v.y);
                hbuf[(4*q+2)*PR + tid] = f2b(v.z);
                hbuf[(4*q+3)*PR + tid] = f2b(v.w);
            }
            float pix = pos[3*dst+0], piy = pos[3*dst+1], piz = pos[3*dst+2];
            float pjx = pos[3*src+0], pjy = pos[3*src+1], pjz = pos[3*src+2];
            float dx = pjx - pix, dy = pjy - piy, dz = pjz - piz;
            float nix = nrm[3*dst+0], niy = nrm[3*dst+1], niz = nrm[3*dst+2];
            float njx = nrm[3*src+0], njy = nrm[3*src+1], njz = nrm[3*src+2];
            hbuf[32*PR + tid] = f2b(sqrtf(dx*dx + dy*dy + dz*dz) * 0.125f);
            float cx, cy, cz, c2, d, den, inv, sn, cs;
            cx = niy*dz - niz*dy; cy = niz*dx - nix*dz; cz = nix*dy - niy*dx;
            c2 = cx*cx + cy*cy + cz*cz;  d = nix*dx + niy*dy + niz*dz;
            den = c2 + d*d;
            if (den > 0.f) { inv = rsqrtf(den); sn = sqrtf(c2)*inv; cs = d*inv; }
            else           { sn = 0.f; cs = 1.f; }
            hbuf[33*PR + tid] = f2b(sn); hbuf[34*PR + tid] = f2b(cs);
            cx = njy*dz - njz*dy; cy = njz*dx - njx*dz; cz = njx*dy - njy*dx;
            c2 = cx*cx + cy*cy + cz*cz;  d = njx*dx + njy*dy + njz*dz;
            den = c2 + d*d;
            if (den > 0.f) { inv = rsqrtf(den); sn = sqrtf(c2)*inv; cs = d*inv; }
            else           { sn = 0.f; cs = 1.f; }
            hbuf[35*PR + tid] = f2b(sn); hbuf[36*PR + tid] = f2b(cs);
            cx = niy*njz - niz*njy; cy = niz*njx - nix*njz; cz = nix*njy - niy*njx;
            c2 = cx*cx + cy*cy + cz*cz;  d = nix*njx + niy*njy + niz*njz;
            den = c2 + d*d;
            if (den > 0.f) { inv = rsqrtf(den); sn = sqrtf(c2)*inv; cs = d*inv; }
            else           { sn = 0.f; cs = 1.f; }
            hbuf[37*PR + tid] = f2b(sn); hbuf[38*PR + tid] = f2b(cs);

            const float4* ep = (const float4*)(ea + (size_t)e * 8);
            float4 a0 = ep[0], a1 = ep[1];
            hbuf[39*PR + tid] = f2b(a0.x); hbuf[40*PR + tid] = f2b(a0.y);
            hbuf[41*PR + tid] = f2b(a0.z); hbuf[42*PR + tid] = f2b(a0.w);
            hbuf[43*PR + tid] = f2b(a1.x); hbuf[44*PR + tid] = f2b(a1.y);
            hbuf[45*PR + tid] = f2b(a1.z); hbuf[46*PR + tid] = f2b(a1.w);
        }

        // ---- GEMM1: 47 -> 64 (wave-uniform weight rows -> scalar loads)
        float h1[64];
        {
            const float4* bp = (const float4*)b1;
            #pragma unroll
            for (int j4 = 0; j4 < 16; ++j4) {
                float4 b = bp[j4];
                h1[4*j4+0]=b.x; h1[4*j4+1]=b.y; h1[4*j4+2]=b.z; h1[4*j4+3]=b.w;
            }
            for (int k = 0; k < 47; ++k) {
                float m = b2f(hbuf[k*PR + tid]);
                const float4* wr = (const float4*)(W1 + k*64);
                #pragma unroll
                for (int j4 = 0; j4 < 16; ++j4) {
                    float4 w = wr[j4];
                    h1[4*j4+0] = fmaf(m, w.x, h1[4*j4+0]);
                    h1[4*j4+1] = fmaf(m, w.y, h1[4*j4+1]);
                    h1[4*j4+2] = fmaf(m, w.z, h1[4*j4+2]);
                    h1[4*j4+3] = fmaf(m, w.w, h1[4*j4+3]);
                }
            }
        }
        // ---- ReLU + LN(64) -> own column rows 0..63 (bf16)
        {
            float s = 0.f, s2 = 0.f;
            #pragma unroll
            for (int j = 0; j < 64; ++j) {
                float v = fmaxf(h1[j], 0.f);
                h1[j] = v; s += v; s2 += v*v;
            }
            float mu = s * (1.f/64.f);
            float var = fmaxf(s2 * (1.f/64.f) - mu*mu, 0.f);
            float rstd = rsqrtf(var + LN_EPS);
            #pragma unroll
            for (int j = 0; j < 64; ++j)
                hbuf[j*PR + tid] = f2b(fmaf((h1[j] - mu) * rstd, g1[j], be1[j]));
        }
        // ---- GEMM2: 64 -> 128, acc in VGPRs
        {
            const float4* bp = (const float4*)b2;
            #pragma unroll
            for (int j4 = 0; j4 < 32; ++j4) {
                float4 b = bp[j4];
                h2[4*j4+0]=b.x; h2[4*j4+1]=b.y; h2[4*j4+2]=b.z; h2[4*j4+3]=b.w;
            }
            for (int k = 0; k < 64; ++k) {
                float m = b2f(hbuf[k*PR + tid]);
                const float4* wr = (const float4*)(W2 + k*128);
                #pragma unroll
                for (int j4 = 0; j4 < 32; ++j4) {
                    float4 w = wr[j4];
                    h2[4*j4+0] = fmaf(m, w.x, h2[4*j4+0]);
                    h2[4*j4+1] = fmaf(m, w.y, h2[4*j4+1]);
                    h2[4*j4+2] = fmaf(m, w.z, h2[4*j4+2]);
                    h2[4*j4+3] = fmaf(m, w.w, h2[4*j4+3]);
                }
            }
        }
        // ---- ReLU + LN(128) in registers
        {
            float s = 0.f, s2 = 0.f;
            #pragma unroll
            for (int j = 0; j < 128; ++j) {
                float v = fmaxf(h2[j], 0.f);
                h2[j] = v; s += v; s2 += v*v;
            }
            float mu = s * (1.f/128.f);
            float var = fmaxf(s2 * (1.f/128.f) - mu*mu, 0.f);
            float rstd = rsqrtf(var + LN_EPS);
            #pragma unroll
            for (int j = 0; j < 128; ++j)
                h2[j] = fmaf((h2[j] - mu) * rstd, g2[j], be2[j]);
        }
    }

    // ---- segmented max, chunks duplicated with STATIC indices (spill fix) ----
    const int w = tid >> 6;     // wave 0..3
    const int j = tid & 63;     // feature row within chunk

    STAGE_REDUCE(0)
    STAGE_REDUCE(64)
}

// ---------------- node MLP (unchanged) ----------------
__global__ __launch_bounds__(256, 4)
void node_kernel(const unsigned* __restrict__ agg,
                 const float* __restrict__ Wg, const float* __restrict__ bg,
                 const float* __restrict__ gg, const float* __restrict__ beg,
                 float* __restrict__ out, int N)
{
    __shared__ float a_lds[16 * 130];
    const int nb = blockIdx.x * 16;
    const size_t total = (size_t)N * 128;
    for (int t = threadIdx.x; t < 16 * 128; t += 256) {
        size_t g = (size_t)nb * 128 + t;
        unsigned u = (g < total) ? agg[g] : 0u;
        a_lds[(t >> 7) * 130 + (t & 127)] = (u == 0u) ? 0.f : unord(u);
    }
    __syncthreads();
    const int n_local = threadIdx.x >> 4;
    const int og = threadIdx.x & 15;
    const int node = nb + n_local;
    if (node >= N) return;

    float acc[16];
    {
        const float4* bp = (const float4*)(bg + og * 16);
        #pragma unroll
        for (int r4 = 0; r4 < 4; ++r4) {
            float4 b = bp[r4];
            acc[4*r4+0]=b.x; acc[4*r4+1]=b.y; acc[4*r4+2]=b.z; acc[4*r4+3]=b.w;
        }
    }
    for (int k = 0; k < 128; ++k) {
        float a = a_lds[n_local * 130 + k];
        const float4* wr = (const float4*)(Wg + (size_t)k * 256 + og * 16);
        #pragma unroll
        for (int r4 = 0; r4 < 4; ++r4) {
            float4 wv = wr[r4];
            acc[4*r4+0] = fmaf(a, wv.x, acc[4*r4+0]);
            acc[4*r4+1] = fmaf(a, wv.y, acc[4*r4+1]);
            acc[4*r4+2] = fmaf(a, wv.z, acc[4*r4+2]);
            acc[4*r4+3] = fmaf(a, wv.w, acc[4*r4+3]);
        }
    }
    float s = 0.f, s2 = 0.f;
    #pragma unroll
    for (int r = 0; r < 16; ++r) {
        float v = fmaxf(acc[r], 0.f);
        acc[r] = v; s += v; s2 += v*v;
    }
    #pragma unroll
    for (int m = 1; m < 16; m <<= 1) {
        s  += __shfl_xor(s,  m, 16);
        s2 += __shfl_xor(s2, m, 16);
    }
    float mu = s * (1.f/256.f);
    float var = fmaxf(s2 * (1.f/256.f) - mu*mu, 0.f);
    float rstd = rsqrtf(var + LN_EPS);
    float4* op = (float4*)(out + (size_t)node * 256 + og * 16);
    #pragma unroll
    for (int r4 = 0; r4 < 4; ++r4) {
        float4 o;
        o.x = fmaf((acc[4*r4+0] - mu) * rstd, gg[og*16 + 4*r4+0], beg[og*16 + 4*r4+0]);
        o.y = fmaf((acc[4*r4+1] - mu) * rstd, gg[og*16 + 4*r4+1], beg[og*16 + 4*r4+1]);
        o.z = fmaf((acc[4*r4+2] - mu) * rstd, gg[og*16 + 4*r4+2], beg[og*16 + 4*r4+2]);
        o.w = fmaf((acc[4*r4+3] - mu) * rstd, gg[og*16 + 4*r4+3], beg[og*16 + 4*r4+3]);
        op[r4] = o;
    }
}

extern "C" void kernel_launch(void* const* d_in, const int* in_sizes, int n_in,
                              void* d_out, int out_size, void* d_ws, size_t ws_size,
                              hipStream_t stream) {
    const float* x         = (const float*)d_in[0];
    const float* pos       = (const float*)d_in[1];
    const float* nrm       = (const float*)d_in[2];
    const float* edge_attr = (const float*)d_in[3];
    const int*   ei        = (const int*)d_in[4];
    const float* W1  = (const float*)d_in[5];
    const float* b1  = (const float*)d_in[6];
    const float* g1  = (const float*)d_in[7];
    const float* be1 = (const float*)d_in[8];
    const float* W2  = (const float*)d_in[9];
    const float* b2  = (const float*)d_in[10];
    const float* g2  = (const float*)d_in[11];
    const float* be2 = (const float*)d_in[12];
    const float* Wg  = (const float*)d_in[13];
    const float* bg  = (const float*)d_in[14];
    const float* gg  = (const float*)d_in[15];
    const float* beg = (const float*)d_in[16];

    const int E = in_sizes[3] / 8;    // edge_attr is [E,8]
    const int N = in_sizes[0] / 32;   // x is [N,32]

    char* ws = (char*)d_ws;
    unsigned* agg  = (unsigned*)ws;                 ws += (size_t)N * 128 * 4;
    unsigned* deg  = (unsigned*)ws;                 ws += (size_t)N * 4;
    unsigned* off  = (unsigned*)ws;                 ws += (size_t)N * 4;
    unsigned* part = (unsigned*)ws;                 ws += 256 * 4;
    unsigned* perm = (unsigned*)ws;                 ws += (size_t)E * 4;
    int*      dsts = (int*)ws;                      ws += (size_t)E * 4;

    hipMemsetAsync(agg, 0, (size_t)N * 128 * 4, stream);
    hipMemsetAsync(deg, 0, (size_t)N * 4, stream);

    const int nbN = (N + 255) / 256;
    hipLaunchKernelGGL(hist_kernel, dim3((E + 255) / 256), dim3(256), 0, stream, ei, deg, E);
    hipLaunchKernelGGL(scan1, dim3(nbN), dim3(256), 0, stream, deg, part, N);
    hipLaunchKernelGGL(scan2, dim3(1), dim3(256), 0, stream, part, nbN);
    hipLaunchKernelGGL(scan3, dim3(nbN), dim3(256), 0, stream, deg, part, off, N);
    hipLaunchKernelGGL(scatter_kernel, dim3((E + 255) / 256), dim3(256), 0, stream,
                       ei, off, perm, dsts, E);

    hipLaunchKernelGGL(edge_kernel, dim3((E + 255) / 256), dim3(256), 0, stream,
                       x, pos, nrm, edge_attr, ei, perm, dsts,
                       W1, b1, g1, be1, W2, b2, g2, be2, agg, E);

    hipLaunchKernelGGL(node_kernel, dim3((N + 15) / 16), dim3(256), 0, stream,
                       agg, Wg, bg, gg, beg, (float*)d_out, N);
}

// Round 6
// 1230.415 us; speedup vs baseline: 7.1319x; 1.3967x over previous
//
#include <hip/hip_runtime.h>
#include <hip/hip_bf16.h>
#include <math.h>

// DockPointNet fused, round 6: 2 threads per edge (pair = same lane, adjacent
// waves -> `half` is wave-uniform, weight rows remain SGPR scalar loads).
// Each thread holds 32/64 h1 accs then 64/128 h2 accs -> ~90 VGPR peak, no
// scratch spill (R4/R5 spilled 64-128 floats/thread = ~830 MB HBM traffic).
// LN partial sums combined through LDS (pair spans waves). h2 staged for the
// segmented max in ONE pass (col = 2*el+half). 128 edges/block.

#define LN_EPS 1e-5f
#define PR 258   // u16 row stride: 256 staging cols + pad (2-way banks max)

__device__ __forceinline__ unsigned ord(float f) {
    int i = __float_as_int(f);
    return (i >= 0) ? ((unsigned)i | 0x80000000u) : ~((unsigned)i);
}
__device__ __forceinline__ float unord(unsigned u) {
    int i = (u & 0x80000000u) ? (int)(u & 0x7fffffffu) : ~(int)u;
    return __int_as_float(i);
}
__device__ __forceinline__ unsigned short f2b(float f) {   // RNE f32->bf16
    unsigned u = __float_as_uint(f);
    return (unsigned short)((u + 0x7FFFu + ((u >> 16) & 1u)) >> 16);
}
__device__ __forceinline__ float b2f(unsigned short h) {
    return __uint_as_float((unsigned)h << 16);
}

// ---------------- CSR build (unchanged) ----------------
__global__ void hist_kernel(const int* __restrict__ ei, unsigned* __restrict__ deg, int E) {
    int e = blockIdx.x * 256 + threadIdx.x;
    if (e < E) atomicAdd(&deg[ei[E + e]], 1u);
}

__global__ void scan1(const unsigned* __restrict__ deg, unsigned* __restrict__ part, int N) {
    __shared__ unsigned s[256];
    int i = blockIdx.x * 256 + threadIdx.x;
    s[threadIdx.x] = (i < N) ? deg[i] : 0u;
    __syncthreads();
    for (int st = 128; st > 0; st >>= 1) {
        if (threadIdx.x < st) s[threadIdx.x] += s[threadIdx.x + st];
        __syncthreads();
    }
    if (threadIdx.x == 0) part[blockIdx.x] = s[0];
}

__global__ void scan2(unsigned* __restrict__ part, int nb) {
    __shared__ unsigned s[256];
    int t = threadIdx.x;
    unsigned v = (t < nb) ? part[t] : 0u;
    s[t] = v;
    __syncthreads();
    for (int st = 1; st < 256; st <<= 1) {
        unsigned add = (t >= st) ? s[t - st] : 0u;
        __syncthreads();
        s[t] += add;
        __syncthreads();
    }
    if (t < nb) part[t] = s[t] - v;   // exclusive
}

__global__ void scan3(const unsigned* __restrict__ deg, const unsigned* __restrict__ part,
                      unsigned* __restrict__ off, int N) {
    __shared__ unsigned s[256];
    int i = blockIdx.x * 256 + threadIdx.x, t = threadIdx.x;
    unsigned v = (i < N) ? deg[i] : 0u;
    s[t] = v;
    __syncthreads();
    for (int st = 1; st < 256; st <<= 1) {
        unsigned add = (t >= st) ? s[t - st] : 0u;
        __syncthreads();
        s[t] += add;
        __syncthreads();
    }
    if (i < N) off[i] = part[blockIdx.x] + s[t] - v;   // exclusive
}

__global__ void scatter_kernel(const int* __restrict__ ei, unsigned* __restrict__ cursor,
                               unsigned* __restrict__ perm, int* __restrict__ dsts, int E) {
    int e = blockIdx.x * 256 + threadIdx.x;
    if (e >= E) return;
    int d = ei[E + e];
    unsigned pos = atomicAdd(&cursor[d], 1u);
    perm[pos] = (unsigned)e;
    dsts[pos] = d;
}

// ---------------- fused edge MLP + segmented max ----------------
__global__ __launch_bounds__(256, 4)
void edge_kernel(const float* __restrict__ x,
                 const float* __restrict__ pos,
                 const float* __restrict__ nrm,
                 const float* __restrict__ ea,
                 const int* __restrict__ ei,
                 const unsigned* __restrict__ perm,
                 const int* __restrict__ dsts,
                 const float* __restrict__ W1, const float* __restrict__ b1,
                 const float* __restrict__ g1, const float* __restrict__ be1,
                 const float* __restrict__ W2, const float* __restrict__ b2,
                 const float* __restrict__ g2, const float* __restrict__ be2,
                 unsigned* __restrict__ agg, int E)
{
    __shared__ unsigned short hbuf[64 * PR];   // 33 KB: msg -> h1n -> h2 staging
    __shared__ float sbuf[256], s2buf[256];    // LN partial sums [half*128+el]
    __shared__ int dloc[128];
    __shared__ short rstart[128], rend[128];
    __shared__ unsigned long long wmask[2];
    __shared__ int dprev_s, dnext_s;

    const int tid  = threadIdx.x;
    const int lane = tid & 63;
    const int wid  = __builtin_amdgcn_readfirstlane(tid >> 6);   // 0..3, SGPR
    const int half = wid & 1;                                     // SGPR
    const int el   = ((wid >> 1) << 6) | lane;                    // edge 0..127
    const int base = blockIdx.x * 128;
    const int p    = base + el;
    const bool valid = p < E;
    const int nvalid = (E - base < 128) ? (E - base) : 128;

    int dst = 0, src = 0, e = 0;
    if (valid) {
        e   = (int)perm[p];
        dst = dsts[p];
        src = ei[e];
    }
    if (half == 0) dloc[el] = valid ? dst : -1;
    if (tid == 0) {
        dprev_s = (blockIdx.x == 0) ? -1 : dsts[(size_t)base - 1];
        dnext_s = (base + 128 < E) ? dsts[base + 128] : -1;
    }

    // ---- stage msg (bf16) into column el, split by half
    if (half == 0) {
        // x[src][0..15] -> rows 0..15
        const float4* xp = (const float4*)(x + (size_t)src * 32);
        #pragma unroll
        for (int q = 0; q < 4; ++q) {
            float4 v = xp[q];
            hbuf[(4*q+0)*PR + el] = f2b(v.x);
            hbuf[(4*q+1)*PR + el] = f2b(v.y);
            hbuf[(4*q+2)*PR + el] = f2b(v.z);
            hbuf[(4*q+3)*PR + el] = f2b(v.w);
        }
        // geometry -> rows 32..38
        float pix = pos[3*dst+0], piy = pos[3*dst+1], piz = pos[3*dst+2];
        float pjx = pos[3*src+0], pjy = pos[3*src+1], pjz = pos[3*src+2];
        float dx = pjx - pix, dy = pjy - piy, dz = pjz - piz;
        float nix = nrm[3*dst+0], niy = nrm[3*dst+1], niz = nrm[3*dst+2];
        float njx = nrm[3*src+0], njy = nrm[3*src+1], njz = nrm[3*src+2];
        hbuf[32*PR + el] = f2b(sqrtf(dx*dx + dy*dy + dz*dz) * 0.125f);
        float cx, cy, cz, c2, d, den, inv, sn, cs;
        cx = niy*dz - niz*dy; cy = niz*dx - nix*dz; cz = nix*dy - niy*dx;
        c2 = cx*cx + cy*cy + cz*cz;  d = nix*dx + niy*dy + niz*dz;
        den = c2 + d*d;
        if (den > 0.f) { inv = rsqrtf(den); sn = sqrtf(c2)*inv; cs = d*inv; }
        else           { sn = 0.f; cs = 1.f; }   // atan2(0,0)=0
        hbuf[33*PR + el] = f2b(sn); hbuf[34*PR + el] = f2b(cs);
        cx = njy*dz - njz*dy; cy = njz*dx - njx*dz; cz = njx*dy - njy*dx;
        c2 = cx*cx + cy*cy + cz*cz;  d = njx*dx + njy*dy + njz*dz;
        den = c2 + d*d;
        if (den > 0.f) { inv = rsqrtf(den); sn = sqrtf(c2)*inv; cs = d*inv; }
        else           { sn = 0.f; cs = 1.f; }
        hbuf[35*PR + el] = f2b(sn); hbuf[36*PR + el] = f2b(cs);
        cx = niy*njz - niz*njy; cy = niz*njx - nix*njz; cz = nix*njy - niy*njx;
        c2 = cx*cx + cy*cy + cz*cz;  d = nix*njx + niy*njy + niz*njz;
        den = c2 + d*d;
        if (den > 0.f) { inv = rsqrtf(den); sn = sqrtf(c2)*inv; cs = d*inv; }
        else           { sn = 0.f; cs = 1.f; }
        hbuf[37*PR + el] = f2b(sn); hbuf[38*PR + el] = f2b(cs);
    } else {
        // x[src][16..31] -> rows 16..31
        const float4* xp = (const float4*)(x + (size_t)src * 32) + 4;
        #pragma unroll
        for (int q = 0; q < 4; ++q) {
            float4 v = xp[q];
            hbuf[(16+4*q+0)*PR + el] = f2b(v.x);
            hbuf[(16+4*q+1)*PR + el] = f2b(v.y);
            hbuf[(16+4*q+2)*PR + el] = f2b(v.z);
            hbuf[(16+4*q+3)*PR + el] = f2b(v.w);
        }
        // edge_attr -> rows 39..46
        const float4* ep = (const float4*)(ea + (size_t)e * 8);
        float4 a0 = ep[0], a1 = ep[1];
        hbuf[39*PR + el] = f2b(a0.x); hbuf[40*PR + el] = f2b(a0.y);
        hbuf[41*PR + el] = f2b(a0.z); hbuf[42*PR + el] = f2b(a0.w);
        hbuf[43*PR + el] = f2b(a1.x); hbuf[44*PR + el] = f2b(a1.y);
        hbuf[45*PR + el] = f2b(a1.z); hbuf[46*PR + el] = f2b(a1.w);
    }
    __syncthreads();   // B1: msg + dloc ready

    // ---- run detection over 128 edges (tids 0..127, ballot per wave)
    bool is_start = false, is_end = false;
    if (tid < 128) {
        int dt = dloc[tid];
        bool isv = tid < nvalid;
        is_start = isv && (tid == 0 || dloc[tid - 1] != dt);
        is_end   = isv && (tid == nvalid - 1 || dloc[tid + 1] != dt);
    }
    {
        unsigned long long mb = __ballot(is_start);
        if (wid < 2 && lane == 0) wmask[wid] = mb;
    }

    // ---- GEMM1: 47 -> 64, this thread computes j = j0..j0+31 (j0 wave-uniform)
    const int j0 = half * 32;
    float h1[32];
    {
        const float4* bp = (const float4*)(b1 + j0);
        #pragma unroll
        for (int j4 = 0; j4 < 8; ++j4) {
            float4 b = bp[j4];
            h1[4*j4+0]=b.x; h1[4*j4+1]=b.y; h1[4*j4+2]=b.z; h1[4*j4+3]=b.w;
        }
        for (int k = 0; k < 47; ++k) {
            float m = b2f(hbuf[k*PR + el]);
            const float4* wr = (const float4*)(W1 + k*64 + j0);
            #pragma unroll
            for (int j4 = 0; j4 < 8; ++j4) {
                float4 w = wr[j4];
                h1[4*j4+0] = fmaf(m, w.x, h1[4*j4+0]);
                h1[4*j4+1] = fmaf(m, w.y, h1[4*j4+1]);
                h1[4*j4+2] = fmaf(m, w.z, h1[4*j4+2]);
                h1[4*j4+3] = fmaf(m, w.w, h1[4*j4+3]);
            }
        }
    }
    // ---- ReLU + LN(64): partials via LDS (pair spans waves)
    {
        float s = 0.f, s2 = 0.f;
        #pragma unroll
        for (int j = 0; j < 32; ++j) {
            float v = fmaxf(h1[j], 0.f);
            h1[j] = v; s += v; s2 += v*v;
        }
        sbuf[half*128 + el] = s;  s2buf[half*128 + el] = s2;
    }
    __syncthreads();   // B2: partials + wmask visible

    // run bookkeeping (needs wmask): all threads get nr; tids<128 write bounds
    int nr;
    {
        unsigned long long m0 = wmask[0], m1 = wmask[1];
        nr = __popcll(m0) + __popcll(m1);
        if (tid < 128) {
            int widr = tid >> 6;
            int rid = (widr ? __popcll(m0) : 0)
                    + __popcll((widr ? m1 : m0) & ((1ull << lane) - 1ull));
            if (is_start) rstart[rid] = (short)tid;
            if (is_end)   rend[is_start ? rid : rid - 1] = (short)tid;
        }
    }
    {
        float s  = sbuf[el] + sbuf[128 + el];
        float s2 = s2buf[el] + s2buf[128 + el];
        float mu = s * (1.f/64.f);
        float var = fmaxf(s2 * (1.f/64.f) - mu*mu, 0.f);
        float rstd = rsqrtf(var + LN_EPS);
        #pragma unroll
        for (int j = 0; j < 32; ++j)
            hbuf[(j0 + j)*PR + el] = f2b(fmaf((h1[j] - mu) * rstd, g1[j0 + j], be1[j0 + j]));
    }
    __syncthreads();   // B3: h1n (all 64 rows) ready

    // ---- GEMM2: 64 -> 128, this thread computes f = f0..f0+63 (f0 wave-uniform)
    const int f0 = half * 64;
    float h2[64];
    {
        const float4* bp = (const float4*)(b2 + f0);
        #pragma unroll
        for (int j4 = 0; j4 < 16; ++j4) {
            float4 b = bp[j4];
            h2[4*j4+0]=b.x; h2[4*j4+1]=b.y; h2[4*j4+2]=b.z; h2[4*j4+3]=b.w;
        }
        for (int k = 0; k < 64; ++k) {
            float m = b2f(hbuf[k*PR + el]);
            const float4* wr = (const float4*)(W2 + k*128 + f0);
            #pragma unroll
            for (int j4 = 0; j4 < 16; ++j4) {
                float4 w = wr[j4];
                h2[4*j4+0] = fmaf(m, w.x, h2[4*j4+0]);
                h2[4*j4+1] = fmaf(m, w.y, h2[4*j4+1]);
                h2[4*j4+2] = fmaf(m, w.z, h2[4*j4+2]);
                h2[4*j4+3] = fmaf(m, w.w, h2[4*j4+3]);
            }
        }
    }
    // ---- ReLU + LN(128): partials via LDS
    {
        float s = 0.f, s2 = 0.f;
        #pragma unroll
        for (int j = 0; j < 64; ++j) {
            float v = fmaxf(h2[j], 0.f);
            h2[j] = v; s += v; s2 += v*v;
        }
        sbuf[half*128 + el] = s;  s2buf[half*128 + el] = s2;
    }
    __syncthreads();   // B4: partials visible (GEMM2 hbuf reads done too)
    {
        float s  = sbuf[el] + sbuf[128 + el];
        float s2 = s2buf[el] + s2buf[128 + el];
        float mu = s * (1.f/128.f);
        float var = fmaxf(s2 * (1.f/128.f) - mu*mu, 0.f);
        float rstd = rsqrtf(var + LN_EPS);
        // stage normalized h2 for the reduce: row q, col 2*el+half
        const int stcol = 2*el + half;
        #pragma unroll
        for (int q = 0; q < 64; ++q)
            hbuf[q*PR + stcol] = f2b(fmaf((h2[q] - mu) * rstd, g2[f0 + q], be2[f0 + q]));
    }
    __syncthreads();   // B5: staging + rstart/rend ready

    // ---- segmented max: feature f = tid&127, run stride 2 by group
    {
        const int grp = tid >> 7;
        const int f   = tid & 127;
        const int fr  = f & 63;
        const int fc  = f >> 6;
        for (int r = grp; r < nr; r += 2) {
            int s0 = rstart[r], en = rend[r];
            int d  = dloc[s0];
            float v0 = -1e30f, v1 = -1e30f, v2 = -1e30f, v3 = -1e30f;
            int c = s0;
            for (; c + 3 <= en; c += 4) {
                v0 = fmaxf(v0, b2f(hbuf[fr*PR + 2*c + fc]));
                v1 = fmaxf(v1, b2f(hbuf[fr*PR + 2*(c+1) + fc]));
                v2 = fmaxf(v2, b2f(hbuf[fr*PR + 2*(c+2) + fc]));
                v3 = fmaxf(v3, b2f(hbuf[fr*PR + 2*(c+3) + fc]));
            }
            for (; c <= en; ++c) v0 = fmaxf(v0, b2f(hbuf[fr*PR + 2*c + fc]));
            float val = fmaxf(fmaxf(v0, v1), fmaxf(v2, v3));
            bool contPrev = (s0 == 0) && (dprev_s == d);
            bool contNext = (en == nvalid - 1) && (dnext_s == d);
            unsigned enc = ord(val);
            unsigned* ap = agg + (size_t)d * 128 + f;
            if (contPrev || contNext) atomicMax(ap, enc);
            else                      *ap = enc;
        }
    }
}

// ---------------- node MLP (unchanged) ----------------
__global__ __launch_bounds__(256, 4)
void node_kernel(const unsigned* __restrict__ agg,
                 const float* __restrict__ Wg, const float* __restrict__ bg,
                 const float* __restrict__ gg, const float* __restrict__ beg,
                 float* __restrict__ out, int N)
{
    __shared__ float a_lds[16 * 130];
    const int nb = blockIdx.x * 16;
    const size_t total = (size_t)N * 128;
    for (int t = threadIdx.x; t < 16 * 128; t += 256) {
        size_t g = (size_t)nb * 128 + t;
        unsigned u = (g < total) ? agg[g] : 0u;
        a_lds[(t >> 7) * 130 + (t & 127)] = (u == 0u) ? 0.f : unord(u);
    }
    __syncthreads();
    const int n_local = threadIdx.x >> 4;
    const int og = threadIdx.x & 15;
    const int node = nb + n_local;
    if (node >= N) return;

    float acc[16];
    {
        const float4* bp = (const float4*)(bg + og * 16);
        #pragma unroll
        for (int r4 = 0; r4 < 4; ++r4) {
            float4 b = bp[r4];
            acc[4*r4+0]=b.x; acc[4*r4+1]=b.y; acc[4*r4+2]=b.z; acc[4*r4+3]=b.w;
        }
    }
    for (int k = 0; k < 128; ++k) {
        float a = a_lds[n_local * 130 + k];
        const float4* wr = (const float4*)(Wg + (size_t)k * 256 + og * 16);
        #pragma unroll
        for (int r4 = 0; r4 < 4; ++r4) {
            float4 wv = wr[r4];
            acc[4*r4+0] = fmaf(a, wv.x, acc[4*r4+0]);
            acc[4*r4+1] = fmaf(a, wv.y, acc[4*r4+1]);
            acc[4*r4+2] = fmaf(a, wv.z, acc[4*r4+2]);
            acc[4*r4+3] = fmaf(a, wv.w, acc[4*r4+3]);
        }
    }
    float s = 0.f, s2 = 0.f;
    #pragma unroll
    for (int r = 0; r < 16; ++r) {
        float v = fmaxf(acc[r], 0.f);
        acc[r] = v; s += v; s2 += v*v;
    }
    #pragma unroll
    for (int m = 1; m < 16; m <<= 1) {
        s  += __shfl_xor(s,  m, 16);
        s2 += __shfl_xor(s2, m, 16);
    }
    float mu = s * (1.f/256.f);
    float var = fmaxf(s2 * (1.f/256.f) - mu*mu, 0.f);
    float rstd = rsqrtf(var + LN_EPS);
    float4* op = (float4*)(out + (size_t)node * 256 + og * 16);
    #pragma unroll
    for (int r4 = 0; r4 < 4; ++r4) {
        float4 o;
        o.x = fmaf((acc[4*r4+0] - mu) * rstd, gg[og*16 + 4*r4+0], beg[og*16 + 4*r4+0]);
        o.y = fmaf((acc[4*r4+1] - mu) * rstd, gg[og*16 + 4*r4+1], beg[og*16 + 4*r4+1]);
        o.z = fmaf((acc[4*r4+2] - mu) * rstd, gg[og*16 + 4*r4+2], beg[og*16 + 4*r4+2]);
        o.w = fmaf((acc[4*r4+3] - mu) * rstd, gg[og*16 + 4*r4+3], beg[og*16 + 4*r4+3]);
        op[r4] = o;
    }
}

extern "C" void kernel_launch(void* const* d_in, const int* in_sizes, int n_in,
                              void* d_out, int out_size, void* d_ws, size_t ws_size,
                              hipStream_t stream) {
    const float* x         = (const float*)d_in[0];
    const float* pos       = (const float*)d_in[1];
    const float* nrm       = (const float*)d_in[2];
    const float* edge_attr = (const float*)d_in[3];
    const int*   ei        = (const int*)d_in[4];
    const float* W1  = (const float*)d_in[5];
    const float* b1  = (const float*)d_in[6];
    const float* g1  = (const float*)d_in[7];
    const float* be1 = (const float*)d_in[8];
    const float* W2  = (const float*)d_in[9];
    const float* b2  = (const float*)d_in[10];
    const float* g2  = (const float*)d_in[11];
    const float* be2 = (const float*)d_in[12];
    const float* Wg  = (const float*)d_in[13];
    const float* bg  = (const float*)d_in[14];
    const float* gg  = (const float*)d_in[15];
    const float* beg = (const float*)d_in[16];

    const int E = in_sizes[3] / 8;    // edge_attr is [E,8]
    const int N = in_sizes[0] / 32;   // x is [N,32]

    char* ws = (char*)d_ws;
    unsigned* agg  = (unsigned*)ws;                 ws += (size_t)N * 128 * 4;
    unsigned* deg  = (unsigned*)ws;                 ws += (size_t)N * 4;
    unsigned* off  = (unsigned*)ws;                 ws += (size_t)N * 4;
    unsigned* part = (unsigned*)ws;                 ws += 256 * 4;
    unsigned* perm = (unsigned*)ws;                 ws += (size_t)E * 4;
    int*      dsts = (int*)ws;                      ws += (size_t)E * 4;

    hipMemsetAsync(agg, 0, (size_t)N * 128 * 4, stream);
    hipMemsetAsync(deg, 0, (size_t)N * 4, stream);

    const int nbN = (N + 255) / 256;
    hipLaunchKernelGGL(hist_kernel, dim3((E + 255) / 256), dim3(256), 0, stream, ei, deg, E);
    hipLaunchKernelGGL(scan1, dim3(nbN), dim3(256), 0, stream, deg, part, N);
    hipLaunchKernelGGL(scan2, dim3(1), dim3(256), 0, stream, part, nbN);
    hipLaunchKernelGGL(scan3, dim3(nbN), dim3(256), 0, stream, deg, part, off, N);
    hipLaunchKernelGGL(scatter_kernel, dim3((E + 255) / 256), dim3(256), 0, stream,
                       ei, off, perm, dsts, E);

    hipLaunchKernelGGL(edge_kernel, dim3((E + 127) / 128), dim3(256), 0, stream,
                       x, pos, nrm, edge_attr, ei, perm, dsts,
                       W1, b1, g1, be1, W2, b2, g2, be2, agg, E);

    hipLaunchKernelGGL(node_kernel, dim3((N + 15) / 16), dim3(256), 0, stream,
                       agg, Wg, bg, gg, beg, (float*)d_out, N);
}

// Round 7
// 959.128 us; speedup vs baseline: 9.1491x; 1.2828x over previous
//
#include <hip/hip_runtime.h>
#include <hip/hip_bf16.h>
#include <math.h>

// DockPointNet fused, round 7: MFMA edge MLP.
// 128 edges/block, 4 waves; wave w owns edges w*32..w*32+31 (2 M-tiles of 16)
// EXCLUSIVELY -> GEMM1 -> LN1 (quad shfl_xor) -> h1n to own LDS rows ->
// GEMM2 -> LN2 -> stage, all barrier-free per wave. Weights prepacked to bf16
// B-fragment layout (coalesced 16B frag loads). mfma_f32_16x16x32_bf16:
//   A: m=lane&15, k=(lane>>4)*8+j ; B: n=lane&15, k=(lane>>4)*8+j
//   C: row=(lane>>4)*4+reg, col=lane&15
// Run detection + segmented max + CSR prep + node kernel: unchanged from R6.

#define LN_EPS 1e-5f
#define EPB 128
#define SM 72     // hbuf row stride in shorts (2-way banks, 8B-aligned frags)
#define SP 130    // st row stride in shorts

typedef __attribute__((ext_vector_type(8))) short bf16x8;
typedef __attribute__((ext_vector_type(4))) float floatx4;
typedef __attribute__((ext_vector_type(4))) short s4v;

__device__ __forceinline__ unsigned ord(float f) {
    int i = __float_as_int(f);
    return (i >= 0) ? ((unsigned)i | 0x80000000u) : ~((unsigned)i);
}
__device__ __forceinline__ float unord(unsigned u) {
    int i = (u & 0x80000000u) ? (int)(u & 0x7fffffffu) : ~(int)u;
    return __int_as_float(i);
}
__device__ __forceinline__ unsigned short f2b(float f) {   // RNE f32->bf16
    unsigned u = __float_as_uint(f);
    return (unsigned short)((u + 0x7FFFu + ((u >> 16) & 1u)) >> 16);
}
__device__ __forceinline__ float b2f(unsigned short h) {
    return __uint_as_float((unsigned)h << 16);
}

// ---------------- CSR build (unchanged) ----------------
__global__ void hist_kernel(const int* __restrict__ ei, unsigned* __restrict__ deg, int E) {
    int e = blockIdx.x * 256 + threadIdx.x;
    if (e < E) atomicAdd(&deg[ei[E + e]], 1u);
}

__global__ void scan1(const unsigned* __restrict__ deg, unsigned* __restrict__ part, int N) {
    __shared__ unsigned s[256];
    int i = blockIdx.x * 256 + threadIdx.x;
    s[threadIdx.x] = (i < N) ? deg[i] : 0u;
    __syncthreads();
    for (int st = 128; st > 0; st >>= 1) {
        if (threadIdx.x < st) s[threadIdx.x] += s[threadIdx.x + st];
        __syncthreads();
    }
    if (threadIdx.x == 0) part[blockIdx.x] = s[0];
}

__global__ void scan2(unsigned* __restrict__ part, int nb) {
    __shared__ unsigned s[256];
    int t = threadIdx.x;
    unsigned v = (t < nb) ? part[t] : 0u;
    s[t] = v;
    __syncthreads();
    for (int st = 1; st < 256; st <<= 1) {
        unsigned add = (t >= st) ? s[t - st] : 0u;
        __syncthreads();
        s[t] += add;
        __syncthreads();
    }
    if (t < nb) part[t] = s[t] - v;   // exclusive
}

__global__ void scan3(const unsigned* __restrict__ deg, const unsigned* __restrict__ part,
                      unsigned* __restrict__ off, int N) {
    __shared__ unsigned s[256];
    int i = blockIdx.x * 256 + threadIdx.x, t = threadIdx.x;
    unsigned v = (i < N) ? deg[i] : 0u;
    s[t] = v;
    __syncthreads();
    for (int st = 1; st < 256; st <<= 1) {
        unsigned add = (t >= st) ? s[t - st] : 0u;
        __syncthreads();
        s[t] += add;
        __syncthreads();
    }
    if (i < N) off[i] = part[blockIdx.x] + s[t] - v;   // exclusive
}

__global__ void scatter_kernel(const int* __restrict__ ei, unsigned* __restrict__ cursor,
                               unsigned* __restrict__ perm, int* __restrict__ dsts, int E) {
    int e = blockIdx.x * 256 + threadIdx.x;
    if (e >= E) return;
    int d = ei[E + e];
    unsigned pos = atomicAdd(&cursor[d], 1u);
    perm[pos] = (unsigned)e;
    dsts[pos] = d;
}

// ---------------- weight prepack: fp32 row-major -> bf16 B-fragments ----------
// W1p: frag fi = s*4+nt (s=K-step, nt=N-tile): lane l, j: W1[s*32+(l>>4)*8+j][nt*16+(l&15)]
// W2p: fi = s*8+nt, same pattern, row stride 128. k>=47 of W1 zero-padded.
__global__ void wprep_kernel(const float* __restrict__ W1, const float* __restrict__ W2,
                             unsigned short* __restrict__ W1p, unsigned short* __restrict__ W2p)
{
    int t = threadIdx.x;
    for (int fl = t; fl < 8 * 64; fl += 256) {
        int fi = fl >> 6, l = fl & 63;
        int s = fi >> 2, nt = fi & 3;
        int n = nt * 16 + (l & 15);
        int kb = s * 32 + ((l >> 4) << 3);
        #pragma unroll
        for (int j = 0; j < 8; ++j) {
            int k = kb + j;
            W1p[fl * 8 + j] = f2b((k < 47) ? W1[k * 64 + n] : 0.f);
        }
    }
    for (int fl = t; fl < 16 * 64; fl += 256) {
        int fi = fl >> 6, l = fl & 63;
        int s = fi >> 3, nt = fi & 7;
        int n = nt * 16 + (l & 15);
        int kb = s * 32 + ((l >> 4) << 3);
        #pragma unroll
        for (int j = 0; j < 8; ++j)
            W2p[fl * 8 + j] = f2b(W2[(kb + j) * 128 + n]);
    }
}

// ---------------- fused edge MLP (MFMA) + segmented max ----------------
__global__ __launch_bounds__(256, 2)
void edge_kernel(const float* __restrict__ x,
                 const float* __restrict__ pos,
                 const float* __restrict__ nrm,
                 const float* __restrict__ ea,
                 const int* __restrict__ ei,
                 const unsigned* __restrict__ perm,
                 const int* __restrict__ dsts,
                 const unsigned short* __restrict__ W1p, const float* __restrict__ b1,
                 const float* __restrict__ g1, const float* __restrict__ be1,
                 const unsigned short* __restrict__ W2p, const float* __restrict__ b2,
                 const float* __restrict__ g2, const float* __restrict__ be2,
                 unsigned* __restrict__ agg, int E)
{
    __shared__ unsigned short hbuf[EPB * SM];   // msg (k=0..63, padded) -> h1n
    __shared__ unsigned short st[128 * SP];     // h2n staging: [feature][edge]
    __shared__ int dloc[EPB];
    __shared__ short rstart[EPB], rend[EPB];
    __shared__ unsigned long long wmask[2];
    __shared__ int dprev_s, dnext_s;

    const int tid  = threadIdx.x;
    const int lane = tid & 63;
    const int half = tid >> 7;      // staging role
    const int el   = tid & 127;     // staging edge
    const int base = blockIdx.x * EPB;
    const int p    = base + el;
    const bool valid = p < E;
    const int nvalid = (E - base < EPB) ? (E - base) : EPB;

    int dst = 0, src = 0, e = 0;
    if (valid) {
        e   = (int)perm[p];
        dst = dsts[p];
        src = ei[e];
    }
    if (half == 0) dloc[el] = valid ? dst : -1;
    if (tid == 0) {
        dprev_s = (blockIdx.x == 0) ? -1 : dsts[(size_t)base - 1];
        dnext_s = (base + EPB < E) ? dsts[base + EPB] : -1;
    }

    // ---- stage msg row el (bf16): x 0..31 | ppf 32..38 | ea 39..46 | 0 47..63
    if (valid) {
        unsigned short* row = &hbuf[el * SM];
        if (half == 0) {
            const float4* xp = (const float4*)(x + (size_t)src * 32);
            #pragma unroll
            for (int q = 0; q < 4; ++q) {
                float4 v = xp[q];
                s4v h = { (short)f2b(v.x), (short)f2b(v.y), (short)f2b(v.z), (short)f2b(v.w) };
                *(s4v*)&row[4 * q] = h;
            }
            float pix = pos[3*dst+0], piy = pos[3*dst+1], piz = pos[3*dst+2];
            float pjx = pos[3*src+0], pjy = pos[3*src+1], pjz = pos[3*src+2];
            float dx = pjx - pix, dy = pjy - piy, dz = pjz - piz;
            float nix = nrm[3*dst+0], niy = nrm[3*dst+1], niz = nrm[3*dst+2];
            float njx = nrm[3*src+0], njy = nrm[3*src+1], njz = nrm[3*src+2];
            row[32] = f2b(sqrtf(dx*dx + dy*dy + dz*dz) * 0.125f);
            float cx, cy, cz, c2, d, den, inv, sn, cs;
            cx = niy*dz - niz*dy; cy = niz*dx - nix*dz; cz = nix*dy - niy*dx;
            c2 = cx*cx + cy*cy + cz*cz;  d = nix*dx + niy*dy + niz*dz;
            den = c2 + d*d;
            if (den > 0.f) { inv = rsqrtf(den); sn = sqrtf(c2)*inv; cs = d*inv; }
            else           { sn = 0.f; cs = 1.f; }   // atan2(0,0)=0
            row[33] = f2b(sn); row[34] = f2b(cs);
            cx = njy*dz - njz*dy; cy = njz*dx - njx*dz; cz = njx*dy - njy*dx;
            c2 = cx*cx + cy*cy + cz*cz;  d = njx*dx + njy*dy + njz*dz;
            den = c2 + d*d;
            if (den > 0.f) { inv = rsqrtf(den); sn = sqrtf(c2)*inv; cs = d*inv; }
            else           { sn = 0.f; cs = 1.f; }
            row[35] = f2b(sn); row[36] = f2b(cs);
            cx = niy*njz - niz*njy; cy = niz*njx - nix*njz; cz = nix*njy - niy*njx;
            c2 = cx*cx + cy*cy + cz*cz;  d = nix*njx + niy*njy + niz*njz;
            den = c2 + d*d;
            if (den > 0.f) { inv = rsqrtf(den); sn = sqrtf(c2)*inv; cs = d*inv; }
            else           { sn = 0.f; cs = 1.f; }
            row[37] = f2b(sn); row[38] = f2b(cs);
        } else {
            const float4* xp = (const float4*)(x + (size_t)src * 32) + 4;
            #pragma unroll
            for (int q = 0; q < 4; ++q) {
                float4 v = xp[q];
                s4v h = { (short)f2b(v.x), (short)f2b(v.y), (short)f2b(v.z), (short)f2b(v.w) };
                *(s4v*)&row[16 + 4 * q] = h;
            }
            const float4* ep = (const float4*)(ea + (size_t)e * 8);
            float4 a0 = ep[0], a1 = ep[1];
            row[39] = f2b(a0.x); row[40] = f2b(a0.y);
            row[41] = f2b(a0.z); row[42] = f2b(a0.w);
            row[43] = f2b(a1.x); row[44] = f2b(a1.y);
            row[45] = f2b(a1.z); row[46] = f2b(a1.w);
            row[47] = 0;
            s4v z = {0, 0, 0, 0};
            *(s4v*)&row[48] = z; *(s4v*)&row[52] = z;
            *(s4v*)&row[56] = z; *(s4v*)&row[60] = z;
        }
    }
    __syncthreads();   // B1: msg + dloc ready

    // ---- run detection (ballot over 128 edges, tids 0..127 = waves 0,1)
    bool is_start = false, is_end = false;
    if (tid < 128) {
        int dt = dloc[tid];
        bool isv = tid < nvalid;
        is_start = isv && (tid == 0 || dloc[tid - 1] != dt);
        is_end   = isv && (tid == nvalid - 1 || dloc[tid + 1] != dt);
    }
    {
        unsigned long long mb = __ballot(is_start);
        if ((tid >> 6) < 2 && lane == 0) wmask[tid >> 6] = mb;
    }
    __syncthreads();   // B2: wmask visible
    int nr;
    {
        unsigned long long m0 = wmask[0], m1 = wmask[1];
        nr = __popcll(m0) + __popcll(m1);
        if (tid < 128) {
            int widr = tid >> 6;
            int rid = (widr ? __popcll(m0) : 0)
                    + __popcll((widr ? m1 : m0) & ((1ull << lane) - 1ull));
            if (is_start) rstart[rid] = (short)tid;
            if (is_end)   rend[is_start ? rid : rid - 1] = (short)tid;
        }
    }

    // ---- MFMA MLP: wave-private, no barriers until staging done
    const int wid  = __builtin_amdgcn_readfirstlane(tid >> 6);   // 0..3
    const int quad = lane >> 4, col = lane & 15;
    const int mb0  = wid * 32;

    // GEMM1: 47(->64) -> 64
    {
        bf16x8 w1f[8];
        const bf16x8* W1v = (const bf16x8*)W1p;
        #pragma unroll
        for (int i = 0; i < 8; ++i) w1f[i] = W1v[i * 64 + lane];
        float b1v[4], g1v[4], e1v[4];
        #pragma unroll
        for (int nt = 0; nt < 4; ++nt) {
            b1v[nt] = b1[nt*16 + col]; g1v[nt] = g1[nt*16 + col]; e1v[nt] = be1[nt*16 + col];
        }
        #pragma unroll
        for (int t = 0; t < 2; ++t) {
            const int mb = mb0 + t * 16;
            floatx4 acc[4] = {{0,0,0,0},{0,0,0,0},{0,0,0,0},{0,0,0,0}};
            #pragma unroll
            for (int s = 0; s < 2; ++s) {
                const unsigned short* ap = &hbuf[(mb + col) * SM + s*32 + quad*8];
                union { s4v h[2]; bf16x8 v; } u;
                u.h[0] = *(const s4v*)ap; u.h[1] = *(const s4v*)(ap + 4);
                #pragma unroll
                for (int nt = 0; nt < 4; ++nt)
                    acc[nt] = __builtin_amdgcn_mfma_f32_16x16x32_bf16(u.v, w1f[s*4+nt], acc[nt], 0, 0, 0);
            }
            float ps[4] = {0,0,0,0}, p2[4] = {0,0,0,0};
            #pragma unroll
            for (int nt = 0; nt < 4; ++nt)
                #pragma unroll
                for (int r = 0; r < 4; ++r) {
                    float v = fmaxf(acc[nt][r] + b1v[nt], 0.f);
                    acc[nt][r] = v; ps[r] += v; p2[r] += v * v;
                }
            #pragma unroll
            for (int r = 0; r < 4; ++r) {
                #pragma unroll
                for (int m = 1; m < 16; m <<= 1) {
                    ps[r] += __shfl_xor(ps[r], m);
                    p2[r] += __shfl_xor(p2[r], m);
                }
            }
            float mu[4], rs[4];
            #pragma unroll
            for (int r = 0; r < 4; ++r) {
                mu[r] = ps[r] * (1.f/64.f);
                float var = fmaxf(p2[r] * (1.f/64.f) - mu[r]*mu[r], 0.f);
                rs[r] = rsqrtf(var + LN_EPS);
            }
            #pragma unroll
            for (int nt = 0; nt < 4; ++nt)
                #pragma unroll
                for (int r = 0; r < 4; ++r) {
                    float hn = (acc[nt][r] - mu[r]) * rs[r] * g1v[nt] + e1v[nt];
                    hbuf[(mb + quad*4 + r) * SM + nt*16 + col] = f2b(hn);
                }
        }
    }
    // GEMM2: 64 -> 128 (reads own h1n rows; same-wave LDS RAW, compiler waits)
    {
        bf16x8 w2f[16];
        const bf16x8* W2v = (const bf16x8*)W2p;
        #pragma unroll
        for (int i = 0; i < 16; ++i) w2f[i] = W2v[i * 64 + lane];
        float b2v[8], g2v[8], e2v[8];
        #pragma unroll
        for (int nt = 0; nt < 8; ++nt) {
            b2v[nt] = b2[nt*16 + col]; g2v[nt] = g2[nt*16 + col]; e2v[nt] = be2[nt*16 + col];
        }
        #pragma unroll
        for (int t = 0; t < 2; ++t) {
            const int mb = mb0 + t * 16;
            floatx4 acc[8] = {{0,0,0,0},{0,0,0,0},{0,0,0,0},{0,0,0,0},
                              {0,0,0,0},{0,0,0,0},{0,0,0,0},{0,0,0,0}};
            #pragma unroll
            for (int s = 0; s < 2; ++s) {
                const unsigned short* ap = &hbuf[(mb + col) * SM + s*32 + quad*8];
                union { s4v h[2]; bf16x8 v; } u;
                u.h[0] = *(const s4v*)ap; u.h[1] = *(const s4v*)(ap + 4);
                #pragma unroll
                for (int nt = 0; nt < 8; ++nt)
                    acc[nt] = __builtin_amdgcn_mfma_f32_16x16x32_bf16(u.v, w2f[s*8+nt], acc[nt], 0, 0, 0);
            }
            float ps[4] = {0,0,0,0}, p2[4] = {0,0,0,0};
            #pragma unroll
            for (int nt = 0; nt < 8; ++nt)
                #pragma unroll
                for (int r = 0; r < 4; ++r) {
                    float v = fmaxf(acc[nt][r] + b2v[nt], 0.f);
                    acc[nt][r] = v; ps[r] += v; p2[r] += v * v;
                }
            #pragma unroll
            for (int r = 0; r < 4; ++r) {
                #pragma unroll
                for (int m = 1; m < 16; m <<= 1) {
                    ps[r] += __shfl_xor(ps[r], m);
                    p2[r] += __shfl_xor(p2[r], m);
                }
            }
            float mu[4], rs[4];
            #pragma unroll
            for (int r = 0; r < 4; ++r) {
                mu[r] = ps[r] * (1.f/128.f);
                float var = fmaxf(p2[r] * (1.f/128.f) - mu[r]*mu[r], 0.f);
                rs[r] = rsqrtf(var + LN_EPS);
            }
            #pragma unroll
            for (int nt = 0; nt < 8; ++nt)
                #pragma unroll
                for (int r = 0; r < 4; ++r) {
                    float hn = (acc[nt][r] - mu[r]) * rs[r] * g2v[nt] + e2v[nt];
                    st[(nt*16 + col) * SP + (mb + quad*4 + r)] = f2b(hn);
                }
        }
    }
    __syncthreads();   // B3: h2n staging + rstart/rend ready

    // ---- segmented max: feature f = tid&127, runs strided by 2
    {
        const int grp = tid >> 7;
        const int f   = tid & 127;
        const unsigned short* fr = &st[f * SP];
        for (int r = grp; r < nr; r += 2) {
            int s0 = rstart[r], en = rend[r];
            int d  = dloc[s0];
            float v0 = -1e30f, v1 = -1e30f, v2 = -1e30f, v3 = -1e30f;
            int c = s0;
            for (; c + 3 <= en; c += 4) {
                v0 = fmaxf(v0, b2f(fr[c]));
                v1 = fmaxf(v1, b2f(fr[c + 1]));
                v2 = fmaxf(v2, b2f(fr[c + 2]));
                v3 = fmaxf(v3, b2f(fr[c + 3]));
            }
            for (; c <= en; ++c) v0 = fmaxf(v0, b2f(fr[c]));
            float val = fmaxf(fmaxf(v0, v1), fmaxf(v2, v3));
            bool contPrev = (s0 == 0) && (dprev_s == d);
            bool contNext = (en == nvalid - 1) && (dnext_s == d);
            unsigned enc = ord(val);
            unsigned* ap = agg + (size_t)d * 128 + f;
            if (contPrev || contNext) atomicMax(ap, enc);
            else                      *ap = enc;
        }
    }
}

// ---------------- node MLP (unchanged) ----------------
__global__ __launch_bounds__(256, 4)
void node_kernel(const unsigned* __restrict__ agg,
                 const float* __restrict__ Wg, const float* __restrict__ bg,
                 const float* __restrict__ gg, const float* __restrict__ beg,
                 float* __restrict__ out, int N)
{
    __shared__ float a_lds[16 * 130];
    const int nb = blockIdx.x * 16;
    const size_t total = (size_t)N * 128;
    for (int t = threadIdx.x; t < 16 * 128; t += 256) {
        size_t g = (size_t)nb * 128 + t;
        unsigned u = (g < total) ? agg[g] : 0u;
        a_lds[(t >> 7) * 130 + (t & 127)] = (u == 0u) ? 0.f : unord(u);
    }
    __syncthreads();
    const int n_local = threadIdx.x >> 4;
    const int og = threadIdx.x & 15;
    const int node = nb + n_local;
    if (node >= N) return;

    float acc[16];
    {
        const float4* bp = (const float4*)(bg + og * 16);
        #pragma unroll
        for (int r4 = 0; r4 < 4; ++r4) {
            float4 b = bp[r4];
            acc[4*r4+0]=b.x; acc[4*r4+1]=b.y; acc[4*r4+2]=b.z; acc[4*r4+3]=b.w;
        }
    }
    for (int k = 0; k < 128; ++k) {
        float a = a_lds[n_local * 130 + k];
        const float4* wr = (const float4*)(Wg + (size_t)k * 256 + og * 16);
        #pragma unroll
        for (int r4 = 0; r4 < 4; ++r4) {
            float4 wv = wr[r4];
            acc[4*r4+0] = fmaf(a, wv.x, acc[4*r4+0]);
            acc[4*r4+1] = fmaf(a, wv.y, acc[4*r4+1]);
            acc[4*r4+2] = fmaf(a, wv.z, acc[4*r4+2]);
            acc[4*r4+3] = fmaf(a, wv.w, acc[4*r4+3]);
        }
    }
    float s = 0.f, s2 = 0.f;
    #pragma unroll
    for (int r = 0; r < 16; ++r) {
        float v = fmaxf(acc[r], 0.f);
        acc[r] = v; s += v; s2 += v*v;
    }
    #pragma unroll
    for (int m = 1; m < 16; m <<= 1) {
        s  += __shfl_xor(s,  m, 16);
        s2 += __shfl_xor(s2, m, 16);
    }
    float mu = s * (1.f/256.f);
    float var = fmaxf(s2 * (1.f/256.f) - mu*mu, 0.f);
    float rstd = rsqrtf(var + LN_EPS);
    float4* op = (float4*)(out + (size_t)node * 256 + og * 16);
    #pragma unroll
    for (int r4 = 0; r4 < 4; ++r4) {
        float4 o;
        o.x = fmaf((acc[4*r4+0] - mu) * rstd, gg[og*16 + 4*r4+0], beg[og*16 + 4*r4+0]);
        o.y = fmaf((acc[4*r4+1] - mu) * rstd, gg[og*16 + 4*r4+1], beg[og*16 + 4*r4+1]);
        o.z = fmaf((acc[4*r4+2] - mu) * rstd, gg[og*16 + 4*r4+2], beg[og*16 + 4*r4+2]);
        o.w = fmaf((acc[4*r4+3] - mu) * rstd, gg[og*16 + 4*r4+3], beg[og*16 + 4*r4+3]);
        op[r4] = o;
    }
}

extern "C" void kernel_launch(void* const* d_in, const int* in_sizes, int n_in,
                              void* d_out, int out_size, void* d_ws, size_t ws_size,
                              hipStream_t stream) {
    const float* x         = (const float*)d_in[0];
    const float* pos       = (const float*)d_in[1];
    const float* nrm       = (const float*)d_in[2];
    const float* edge_attr = (const float*)d_in[3];
    const int*   ei        = (const int*)d_in[4];
    const float* W1  = (const float*)d_in[5];
    const float* b1  = (const float*)d_in[6];
    const float* g1  = (const float*)d_in[7];
    const float* be1 = (const float*)d_in[8];
    const float* W2  = (const float*)d_in[9];
    const float* b2  = (const float*)d_in[10];
    const float* g2  = (const float*)d_in[11];
    const float* be2 = (const float*)d_in[12];
    const float* Wg  = (const float*)d_in[13];
    const float* bg  = (const float*)d_in[14];
    const float* gg  = (const float*)d_in[15];
    const float* beg = (const float*)d_in[16];

    const int E = in_sizes[3] / 8;    // edge_attr is [E,8]
    const int N = in_sizes[0] / 32;   // x is [N,32]

    char* ws = (char*)d_ws;
    unsigned* agg  = (unsigned*)ws;                   ws += (size_t)N * 128 * 4;
    unsigned* deg  = (unsigned*)ws;                   ws += (size_t)N * 4;
    unsigned* off  = (unsigned*)ws;                   ws += (size_t)N * 4;
    unsigned* part = (unsigned*)ws;                   ws += 256 * 4;
    unsigned* perm = (unsigned*)ws;                   ws += (size_t)E * 4;
    int*      dsts = (int*)ws;                        ws += (size_t)E * 4;
    unsigned short* W1p = (unsigned short*)ws;        ws += 8 * 64 * 8 * 2;
    unsigned short* W2p = (unsigned short*)ws;        ws += 16 * 64 * 8 * 2;

    hipMemsetAsync(agg, 0, (size_t)N * 128 * 4, stream);
    hipMemsetAsync(deg, 0, (size_t)N * 4, stream);

    hipLaunchKernelGGL(wprep_kernel, dim3(1), dim3(256), 0, stream, W1, W2, W1p, W2p);

    const int nbN = (N + 255) / 256;
    hipLaunchKernelGGL(hist_kernel, dim3((E + 255) / 256), dim3(256), 0, stream, ei, deg, E);
    hipLaunchKernelGGL(scan1, dim3(nbN), dim3(256), 0, stream, deg, part, N);
    hipLaunchKernelGGL(scan2, dim3(1), dim3(256), 0, stream, part, nbN);
    hipLaunchKernelGGL(scan3, dim3(nbN), dim3(256), 0, stream, deg, part, off, N);
    hipLaunchKernelGGL(scatter_kernel, dim3((E + 255) / 256), dim3(256), 0, stream,
                       ei, off, perm, dsts, E);

    hipLaunchKernelGGL(edge_kernel, dim3((E + EPB - 1) / EPB), dim3(256), 0, stream,
                       x, pos, nrm, edge_attr, ei, perm, dsts,
                       W1p, b1, g1, be1, W2p, b2, g2, be2, agg, E);

    hipLaunchKernelGGL(node_kernel, dim3((N + 15) / 16), dim3(256), 0, stream,
                       agg, Wg, bg, gg, beg, (float*)d_out, N);
}

// Round 8
// 652.770 us; speedup vs baseline: 13.4430x; 1.4693x over previous
//
#include <hip/hip_runtime.h>
#include <hip/hip_bf16.h>
#include <math.h>

// DockPointNet fused, round 8: R7 + MFMA node MLP.
// R7's node_kernel was latency-bound (396 us, VALUBusy 7%, VGPR=32: 512
// serial L2 loads/thread). Now: 64 nodes/block, agg tile -> bf16 LDS,
// Wg prepacked to bf16 B-frags, 16 nt-tiles x 4 MFMAs per wave, LN(256)
// via 16-lane shfl_xor on C-layout rows, direct dword stores.
// Edge kernel / CSR prep unchanged from R7.

#define LN_EPS 1e-5f
#define EPB 128
#define SM 72     // hbuf row stride in shorts
#define SP 130    // st row stride in shorts
#define AS 132    // node a_bf row stride in shorts

typedef __attribute__((ext_vector_type(8))) short bf16x8;
typedef __attribute__((ext_vector_type(4))) float floatx4;
typedef __attribute__((ext_vector_type(4))) short s4v;

__device__ __forceinline__ unsigned ord(float f) {
    int i = __float_as_int(f);
    return (i >= 0) ? ((unsigned)i | 0x80000000u) : ~((unsigned)i);
}
__device__ __forceinline__ float unord(unsigned u) {
    int i = (u & 0x80000000u) ? (int)(u & 0x7fffffffu) : ~(int)u;
    return __int_as_float(i);
}
__device__ __forceinline__ unsigned short f2b(float f) {   // RNE f32->bf16
    unsigned u = __float_as_uint(f);
    return (unsigned short)((u + 0x7FFFu + ((u >> 16) & 1u)) >> 16);
}
__device__ __forceinline__ float b2f(unsigned short h) {
    return __uint_as_float((unsigned)h << 16);
}

// ---------------- CSR build (unchanged) ----------------
__global__ void hist_kernel(const int* __restrict__ ei, unsigned* __restrict__ deg, int E) {
    int e = blockIdx.x * 256 + threadIdx.x;
    if (e < E) atomicAdd(&deg[ei[E + e]], 1u);
}

__global__ void scan1(const unsigned* __restrict__ deg, unsigned* __restrict__ part, int N) {
    __shared__ unsigned s[256];
    int i = blockIdx.x * 256 + threadIdx.x;
    s[threadIdx.x] = (i < N) ? deg[i] : 0u;
    __syncthreads();
    for (int st = 128; st > 0; st >>= 1) {
        if (threadIdx.x < st) s[threadIdx.x] += s[threadIdx.x + st];
        __syncthreads();
    }
    if (threadIdx.x == 0) part[blockIdx.x] = s[0];
}

__global__ void scan2(unsigned* __restrict__ part, int nb) {
    __shared__ unsigned s[256];
    int t = threadIdx.x;
    unsigned v = (t < nb) ? part[t] : 0u;
    s[t] = v;
    __syncthreads();
    for (int st = 1; st < 256; st <<= 1) {
        unsigned add = (t >= st) ? s[t - st] : 0u;
        __syncthreads();
        s[t] += add;
        __syncthreads();
    }
    if (t < nb) part[t] = s[t] - v;   // exclusive
}

__global__ void scan3(const unsigned* __restrict__ deg, const unsigned* __restrict__ part,
                      unsigned* __restrict__ off, int N) {
    __shared__ unsigned s[256];
    int i = blockIdx.x * 256 + threadIdx.x, t = threadIdx.x;
    unsigned v = (i < N) ? deg[i] : 0u;
    s[t] = v;
    __syncthreads();
    for (int st = 1; st < 256; st <<= 1) {
        unsigned add = (t >= st) ? s[t - st] : 0u;
        __syncthreads();
        s[t] += add;
        __syncthreads();
    }
    if (i < N) off[i] = part[blockIdx.x] + s[t] - v;   // exclusive
}

__global__ void scatter_kernel(const int* __restrict__ ei, unsigned* __restrict__ cursor,
                               unsigned* __restrict__ perm, int* __restrict__ dsts, int E) {
    int e = blockIdx.x * 256 + threadIdx.x;
    if (e >= E) return;
    int d = ei[E + e];
    unsigned pos = atomicAdd(&cursor[d], 1u);
    perm[pos] = (unsigned)e;
    dsts[pos] = d;
}

// ---------------- weight prepack: fp32 row-major -> bf16 B-fragments ----------
__global__ void wprep_kernel(const float* __restrict__ W1, const float* __restrict__ W2,
                             const float* __restrict__ Wg,
                             unsigned short* __restrict__ W1p, unsigned short* __restrict__ W2p,
                             unsigned short* __restrict__ Wgp)
{
    int t = threadIdx.x;
    for (int fl = t; fl < 8 * 64; fl += 256) {
        int fi = fl >> 6, l = fl & 63;
        int s = fi >> 2, nt = fi & 3;
        int n = nt * 16 + (l & 15);
        int kb = s * 32 + ((l >> 4) << 3);
        #pragma unroll
        for (int j = 0; j < 8; ++j) {
            int k = kb + j;
            W1p[fl * 8 + j] = f2b((k < 47) ? W1[k * 64 + n] : 0.f);
        }
    }
    for (int fl = t; fl < 16 * 64; fl += 256) {
        int fi = fl >> 6, l = fl & 63;
        int s = fi >> 3, nt = fi & 7;
        int n = nt * 16 + (l & 15);
        int kb = s * 32 + ((l >> 4) << 3);
        #pragma unroll
        for (int j = 0; j < 8; ++j)
            W2p[fl * 8 + j] = f2b(W2[(kb + j) * 128 + n]);
    }
    // Wg: K=128 (s=0..3), N=256 (nt=0..15); fi = s*16+nt
    for (int fl = t; fl < 64 * 64; fl += 256) {
        int fi = fl >> 6, l = fl & 63;
        int s = fi >> 4, nt = fi & 15;
        int n = nt * 16 + (l & 15);
        int kb = s * 32 + ((l >> 4) << 3);
        #pragma unroll
        for (int j = 0; j < 8; ++j)
            Wgp[fl * 8 + j] = f2b(Wg[(size_t)(kb + j) * 256 + n]);
    }
}

// ---------------- fused edge MLP (MFMA) + segmented max (unchanged R7) -------
__global__ __launch_bounds__(256, 2)
void edge_kernel(const float* __restrict__ x,
                 const float* __restrict__ pos,
                 const float* __restrict__ nrm,
                 const float* __restrict__ ea,
                 const int* __restrict__ ei,
                 const unsigned* __restrict__ perm,
                 const int* __restrict__ dsts,
                 const unsigned short* __restrict__ W1p, const float* __restrict__ b1,
                 const float* __restrict__ g1, const float* __restrict__ be1,
                 const unsigned short* __restrict__ W2p, const float* __restrict__ b2,
                 const float* __restrict__ g2, const float* __restrict__ be2,
                 unsigned* __restrict__ agg, int E)
{
    __shared__ unsigned short hbuf[EPB * SM];
    __shared__ unsigned short st[128 * SP];
    __shared__ int dloc[EPB];
    __shared__ short rstart[EPB], rend[EPB];
    __shared__ unsigned long long wmask[2];
    __shared__ int dprev_s, dnext_s;

    const int tid  = threadIdx.x;
    const int lane = tid & 63;
    const int half = tid >> 7;
    const int el   = tid & 127;
    const int base = blockIdx.x * EPB;
    const int p    = base + el;
    const bool valid = p < E;
    const int nvalid = (E - base < EPB) ? (E - base) : EPB;

    int dst = 0, src = 0, e = 0;
    if (valid) {
        e   = (int)perm[p];
        dst = dsts[p];
        src = ei[e];
    }
    if (half == 0) dloc[el] = valid ? dst : -1;
    if (tid == 0) {
        dprev_s = (blockIdx.x == 0) ? -1 : dsts[(size_t)base - 1];
        dnext_s = (base + EPB < E) ? dsts[base + EPB] : -1;
    }

    if (valid) {
        unsigned short* row = &hbuf[el * SM];
        if (half == 0) {
            const float4* xp = (const float4*)(x + (size_t)src * 32);
            #pragma unroll
            for (int q = 0; q < 4; ++q) {
                float4 v = xp[q];
                s4v h = { (short)f2b(v.x), (short)f2b(v.y), (short)f2b(v.z), (short)f2b(v.w) };
                *(s4v*)&row[4 * q] = h;
            }
            float pix = pos[3*dst+0], piy = pos[3*dst+1], piz = pos[3*dst+2];
            float pjx = pos[3*src+0], pjy = pos[3*src+1], pjz = pos[3*src+2];
            float dx = pjx - pix, dy = pjy - piy, dz = pjz - piz;
            float nix = nrm[3*dst+0], niy = nrm[3*dst+1], niz = nrm[3*dst+2];
            float njx = nrm[3*src+0], njy = nrm[3*src+1], njz = nrm[3*src+2];
            row[32] = f2b(sqrtf(dx*dx + dy*dy + dz*dz) * 0.125f);
            float cx, cy, cz, c2, d, den, inv, sn, cs;
            cx = niy*dz - niz*dy; cy = niz*dx - nix*dz; cz = nix*dy - niy*dx;
            c2 = cx*cx + cy*cy + cz*cz;  d = nix*dx + niy*dy + niz*dz;
            den = c2 + d*d;
            if (den > 0.f) { inv = rsqrtf(den); sn = sqrtf(c2)*inv; cs = d*inv; }
            else           { sn = 0.f; cs = 1.f; }   // atan2(0,0)=0
            row[33] = f2b(sn); row[34] = f2b(cs);
            cx = njy*dz - njz*dy; cy = njz*dx - njx*dz; cz = njx*dy - njy*dx;
            c2 = cx*cx + cy*cy + cz*cz;  d = njx*dx + njy*dy + njz*dz;
            den = c2 + d*d;
            if (den > 0.f) { inv = rsqrtf(den); sn = sqrtf(c2)*inv; cs = d*inv; }
            else           { sn = 0.f; cs = 1.f; }
            row[35] = f2b(sn); row[36] = f2b(cs);
            cx = niy*njz - niz*njy; cy = niz*njx - nix*njz; cz = nix*njy - niy*njx;
            c2 = cx*cx + cy*cy + cz*cz;  d = nix*njx + niy*njy + niz*njz;
            den = c2 + d*d;
            if (den > 0.f) { inv = rsqrtf(den); sn = sqrtf(c2)*inv; cs = d*inv; }
            else           { sn = 0.f; cs = 1.f; }
            row[37] = f2b(sn); row[38] = f2b(cs);
        } else {
            const float4* xp = (const float4*)(x + (size_t)src * 32) + 4;
            #pragma unroll
            for (int q = 0; q < 4; ++q) {
                float4 v = xp[q];
                s4v h = { (short)f2b(v.x), (short)f2b(v.y), (short)f2b(v.z), (short)f2b(v.w) };
                *(s4v*)&row[16 + 4 * q] = h;
            }
            const float4* ep = (const float4*)(ea + (size_t)e * 8);
            float4 a0 = ep[0], a1 = ep[1];
            row[39] = f2b(a0.x); row[40] = f2b(a0.y);
            row[41] = f2b(a0.z); row[42] = f2b(a0.w);
            row[43] = f2b(a1.x); row[44] = f2b(a1.y);
            row[45] = f2b(a1.z); row[46] = f2b(a1.w);
            row[47] = 0;
            s4v z = {0, 0, 0, 0};
            *(s4v*)&row[48] = z; *(s4v*)&row[52] = z;
            *(s4v*)&row[56] = z; *(s4v*)&row[60] = z;
        }
    }
    __syncthreads();   // B1: msg + dloc ready

    bool is_start = false, is_end = false;
    if (tid < 128) {
        int dt = dloc[tid];
        bool isv = tid < nvalid;
        is_start = isv && (tid == 0 || dloc[tid - 1] != dt);
        is_end   = isv && (tid == nvalid - 1 || dloc[tid + 1] != dt);
    }
    {
        unsigned long long mb = __ballot(is_start);
        if ((tid >> 6) < 2 && lane == 0) wmask[tid >> 6] = mb;
    }
    __syncthreads();   // B2: wmask visible
    int nr;
    {
        unsigned long long m0 = wmask[0], m1 = wmask[1];
        nr = __popcll(m0) + __popcll(m1);
        if (tid < 128) {
            int widr = tid >> 6;
            int rid = (widr ? __popcll(m0) : 0)
                    + __popcll((widr ? m1 : m0) & ((1ull << lane) - 1ull));
            if (is_start) rstart[rid] = (short)tid;
            if (is_end)   rend[is_start ? rid : rid - 1] = (short)tid;
        }
    }

    const int wid  = __builtin_amdgcn_readfirstlane(tid >> 6);
    const int quad = lane >> 4, col = lane & 15;
    const int mb0  = wid * 32;

    // GEMM1: 47(->64) -> 64
    {
        bf16x8 w1f[8];
        const bf16x8* W1v = (const bf16x8*)W1p;
        #pragma unroll
        for (int i = 0; i < 8; ++i) w1f[i] = W1v[i * 64 + lane];
        float b1v[4], g1v[4], e1v[4];
        #pragma unroll
        for (int nt = 0; nt < 4; ++nt) {
            b1v[nt] = b1[nt*16 + col]; g1v[nt] = g1[nt*16 + col]; e1v[nt] = be1[nt*16 + col];
        }
        #pragma unroll
        for (int t = 0; t < 2; ++t) {
            const int mb = mb0 + t * 16;
            floatx4 acc[4] = {{0,0,0,0},{0,0,0,0},{0,0,0,0},{0,0,0,0}};
            #pragma unroll
            for (int s = 0; s < 2; ++s) {
                const unsigned short* ap = &hbuf[(mb + col) * SM + s*32 + quad*8];
                union { s4v h[2]; bf16x8 v; } u;
                u.h[0] = *(const s4v*)ap; u.h[1] = *(const s4v*)(ap + 4);
                #pragma unroll
                for (int nt = 0; nt < 4; ++nt)
                    acc[nt] = __builtin_amdgcn_mfma_f32_16x16x32_bf16(u.v, w1f[s*4+nt], acc[nt], 0, 0, 0);
            }
            float ps[4] = {0,0,0,0}, p2[4] = {0,0,0,0};
            #pragma unroll
            for (int nt = 0; nt < 4; ++nt)
                #pragma unroll
                for (int r = 0; r < 4; ++r) {
                    float v = fmaxf(acc[nt][r] + b1v[nt], 0.f);
                    acc[nt][r] = v; ps[r] += v; p2[r] += v * v;
                }
            #pragma unroll
            for (int r = 0; r < 4; ++r) {
                #pragma unroll
                for (int m = 1; m < 16; m <<= 1) {
                    ps[r] += __shfl_xor(ps[r], m);
                    p2[r] += __shfl_xor(p2[r], m);
                }
            }
            float mu[4], rs[4];
            #pragma unroll
            for (int r = 0; r < 4; ++r) {
                mu[r] = ps[r] * (1.f/64.f);
                float var = fmaxf(p2[r] * (1.f/64.f) - mu[r]*mu[r], 0.f);
                rs[r] = rsqrtf(var + LN_EPS);
            }
            #pragma unroll
            for (int nt = 0; nt < 4; ++nt)
                #pragma unroll
                for (int r = 0; r < 4; ++r) {
                    float hn = (acc[nt][r] - mu[r]) * rs[r] * g1v[nt] + e1v[nt];
                    hbuf[(mb + quad*4 + r) * SM + nt*16 + col] = f2b(hn);
                }
        }
    }
    // GEMM2: 64 -> 128
    {
        bf16x8 w2f[16];
        const bf16x8* W2v = (const bf16x8*)W2p;
        #pragma unroll
        for (int i = 0; i < 16; ++i) w2f[i] = W2v[i * 64 + lane];
        float b2v[8], g2v[8], e2v[8];
        #pragma unroll
        for (int nt = 0; nt < 8; ++nt) {
            b2v[nt] = b2[nt*16 + col]; g2v[nt] = g2[nt*16 + col]; e2v[nt] = be2[nt*16 + col];
        }
        #pragma unroll
        for (int t = 0; t < 2; ++t) {
            const int mb = mb0 + t * 16;
            floatx4 acc[8] = {{0,0,0,0},{0,0,0,0},{0,0,0,0},{0,0,0,0},
                              {0,0,0,0},{0,0,0,0},{0,0,0,0},{0,0,0,0}};
            #pragma unroll
            for (int s = 0; s < 2; ++s) {
                const unsigned short* ap = &hbuf[(mb + col) * SM + s*32 + quad*8];
                union { s4v h[2]; bf16x8 v; } u;
                u.h[0] = *(const s4v*)ap; u.h[1] = *(const s4v*)(ap + 4);
                #pragma unroll
                for (int nt = 0; nt < 8; ++nt)
                    acc[nt] = __builtin_amdgcn_mfma_f32_16x16x32_bf16(u.v, w2f[s*8+nt], acc[nt], 0, 0, 0);
            }
            float ps[4] = {0,0,0,0}, p2[4] = {0,0,0,0};
            #pragma unroll
            for (int nt = 0; nt < 8; ++nt)
                #pragma unroll
                for (int r = 0; r < 4; ++r) {
                    float v = fmaxf(acc[nt][r] + b2v[nt], 0.f);
                    acc[nt][r] = v; ps[r] += v; p2[r] += v * v;
                }
            #pragma unroll
            for (int r = 0; r < 4; ++r) {
                #pragma unroll
                for (int m = 1; m < 16; m <<= 1) {
                    ps[r] += __shfl_xor(ps[r], m);
                    p2[r] += __shfl_xor(p2[r], m);
                }
            }
            float mu[4], rs[4];
            #pragma unroll
            for (int r = 0; r < 4; ++r) {
                mu[r] = ps[r] * (1.f/128.f);
                float var = fmaxf(p2[r] * (1.f/128.f) - mu[r]*mu[r], 0.f);
                rs[r] = rsqrtf(var + LN_EPS);
            }
            #pragma unroll
            for (int nt = 0; nt < 8; ++nt)
                #pragma unroll
                for (int r = 0; r < 4; ++r) {
                    float hn = (acc[nt][r] - mu[r]) * rs[r] * g2v[nt] + e2v[nt];
                    st[(nt*16 + col) * SP + (mb + quad*4 + r)] = f2b(hn);
                }
        }
    }
    __syncthreads();   // B3: staging + rstart/rend ready

    {
        const int grp = tid >> 7;
        const int f   = tid & 127;
        const unsigned short* fr = &st[f * SP];
        for (int r = grp; r < nr; r += 2) {
            int s0 = rstart[r], en = rend[r];
            int d  = dloc[s0];
            float v0 = -1e30f, v1 = -1e30f, v2 = -1e30f, v3 = -1e30f;
            int c = s0;
            for (; c + 3 <= en; c += 4) {
                v0 = fmaxf(v0, b2f(fr[c]));
                v1 = fmaxf(v1, b2f(fr[c + 1]));
                v2 = fmaxf(v2, b2f(fr[c + 2]));
                v3 = fmaxf(v3, b2f(fr[c + 3]));
            }
            for (; c <= en; ++c) v0 = fmaxf(v0, b2f(fr[c]));
            float val = fmaxf(fmaxf(v0, v1), fmaxf(v2, v3));
            bool contPrev = (s0 == 0) && (dprev_s == d);
            bool contNext = (en == nvalid - 1) && (dnext_s == d);
            unsigned enc = ord(val);
            unsigned* ap = agg + (size_t)d * 128 + f;
            if (contPrev || contNext) atomicMax(ap, enc);
            else                      *ap = enc;
        }
    }
}

// ---------------- node MLP (MFMA): agg[128] @ Wg[128,256] -> ReLU -> LN ------
__global__ __launch_bounds__(256, 2)
void node_kernel(const unsigned* __restrict__ agg,
                 const unsigned short* __restrict__ Wgp, const float* __restrict__ bg,
                 const float* __restrict__ gg, const float* __restrict__ beg,
                 float* __restrict__ out, int N)
{
    __shared__ unsigned short a_bf[64 * AS];   // 16.9 KB
    const int tid  = threadIdx.x;
    const int base = blockIdx.x * 64;
    const size_t total = (size_t)N * 128;

    // load agg tile (64 nodes x 128 fp32) -> bf16 LDS, coalesced
    #pragma unroll
    for (int i = 0; i < 32; ++i) {
        int idx = tid + i * 256;          // 0..8191
        int nl = idx >> 7, k = idx & 127;
        size_t g = (size_t)base * 128 + idx;
        unsigned u = (g < total) ? agg[g] : 0u;
        a_bf[nl * AS + k] = (u == 0u) ? (unsigned short)0 : f2b(unord(u));
    }
    __syncthreads();

    const int lane = tid & 63;
    const int wid  = __builtin_amdgcn_readfirstlane(tid >> 6);   // 0..3
    const int quad = lane >> 4, col = lane & 15;
    const int m0   = wid * 16;

    // A fragments: node rows m0+col, K steps s=0..3
    bf16x8 af[4];
    #pragma unroll
    for (int s = 0; s < 4; ++s) {
        const unsigned short* ap = &a_bf[(m0 + col) * AS + s*32 + quad*8];
        union { s4v h[2]; bf16x8 v; } u;
        u.h[0] = *(const s4v*)ap; u.h[1] = *(const s4v*)(ap + 4);
        af[s] = u.v;
    }

    float accv[16][4];
    float ps[4] = {0,0,0,0}, p2[4] = {0,0,0,0};
    const bf16x8* Wv = (const bf16x8*)Wgp;
    #pragma unroll
    for (int nt = 0; nt < 16; ++nt) {
        floatx4 acc = {0, 0, 0, 0};
        #pragma unroll
        for (int s = 0; s < 4; ++s)
            acc = __builtin_amdgcn_mfma_f32_16x16x32_bf16(af[s], Wv[(s*16 + nt)*64 + lane], acc, 0, 0, 0);
        float b = bg[nt*16 + col];
        #pragma unroll
        for (int r = 0; r < 4; ++r) {
            float v = fmaxf(acc[r] + b, 0.f);
            accv[nt][r] = v; ps[r] += v; p2[r] += v * v;
        }
    }
    #pragma unroll
    for (int r = 0; r < 4; ++r) {
        #pragma unroll
        for (int m = 1; m < 16; m <<= 1) {
            ps[r] += __shfl_xor(ps[r], m);
            p2[r] += __shfl_xor(p2[r], m);
        }
    }
    float mu[4], rs[4];
    #pragma unroll
    for (int r = 0; r < 4; ++r) {
        mu[r] = ps[r] * (1.f/256.f);
        float var = fmaxf(p2[r] * (1.f/256.f) - mu[r]*mu[r], 0.f);
        rs[r] = rsqrtf(var + LN_EPS);
    }
    #pragma unroll
    for (int nt = 0; nt < 16; ++nt) {
        float g = gg[nt*16 + col], be = beg[nt*16 + col];
        #pragma unroll
        for (int r = 0; r < 4; ++r) {
            int node = base + m0 + quad*4 + r;
            if (node < N)
                out[(size_t)node * 256 + nt*16 + col] = (accv[nt][r] - mu[r]) * rs[r] * g + be;
        }
    }
}

extern "C" void kernel_launch(void* const* d_in, const int* in_sizes, int n_in,
                              void* d_out, int out_size, void* d_ws, size_t ws_size,
                              hipStream_t stream) {
    const float* x         = (const float*)d_in[0];
    const float* pos       = (const float*)d_in[1];
    const float* nrm       = (const float*)d_in[2];
    const float* edge_attr = (const float*)d_in[3];
    const int*   ei        = (const int*)d_in[4];
    const float* W1  = (const float*)d_in[5];
    const float* b1  = (const float*)d_in[6];
    const float* g1  = (const float*)d_in[7];
    const float* be1 = (const float*)d_in[8];
    const float* W2  = (const float*)d_in[9];
    const float* b2  = (const float*)d_in[10];
    const float* g2  = (const float*)d_in[11];
    const float* be2 = (const float*)d_in[12];
    const float* Wg  = (const float*)d_in[13];
    const float* bg  = (const float*)d_in[14];
    const float* gg  = (const float*)d_in[15];
    const float* beg = (const float*)d_in[16];

    const int E = in_sizes[3] / 8;    // edge_attr is [E,8]
    const int N = in_sizes[0] / 32;   // x is [N,32]

    char* ws = (char*)d_ws;
    unsigned* agg  = (unsigned*)ws;                   ws += (size_t)N * 128 * 4;
    unsigned* deg  = (unsigned*)ws;                   ws += (size_t)N * 4;
    unsigned* off  = (unsigned*)ws;                   ws += (size_t)N * 4;
    unsigned* part = (unsigned*)ws;                   ws += 256 * 4;
    unsigned* perm = (unsigned*)ws;                   ws += (size_t)E * 4;
    int*      dsts = (int*)ws;                        ws += (size_t)E * 4;
    unsigned short* W1p = (unsigned short*)ws;        ws += 8 * 64 * 8 * 2;
    unsigned short* W2p = (unsigned short*)ws;        ws += 16 * 64 * 8 * 2;
    unsigned short* Wgp = (unsigned short*)ws;        ws += 64 * 64 * 8 * 2;

    hipMemsetAsync(agg, 0, (size_t)N * 128 * 4, stream);
    hipMemsetAsync(deg, 0, (size_t)N * 4, stream);

    hipLaunchKernelGGL(wprep_kernel, dim3(1), dim3(256), 0, stream, W1, W2, Wg, W1p, W2p, Wgp);

    const int nbN = (N + 255) / 256;
    hipLaunchKernelGGL(hist_kernel, dim3((E + 255) / 256), dim3(256), 0, stream, ei, deg, E);
    hipLaunchKernelGGL(scan1, dim3(nbN), dim3(256), 0, stream, deg, part, N);
    hipLaunchKernelGGL(scan2, dim3(1), dim3(256), 0, stream, part, nbN);
    hipLaunchKernelGGL(scan3, dim3(nbN), dim3(256), 0, stream, deg, part, off, N);
    hipLaunchKernelGGL(scatter_kernel, dim3((E + 255) / 256), dim3(256), 0, stream,
                       ei, off, perm, dsts, E);

    hipLaunchKernelGGL(edge_kernel, dim3((E + EPB - 1) / EPB), dim3(256), 0, stream,
                       x, pos, nrm, edge_attr, ei, perm, dsts,
                       W1p, b1, g1, be1, W2p, b2, g2, be2, agg, E);

    hipLaunchKernelGGL(node_kernel, dim3((N + 63) / 64), dim3(256), 0, stream,
                       agg, Wgp, bg, gg, beg, (float*)d_out, N);
}

// Round 9
// 607.705 us; speedup vs baseline: 14.4399x; 1.0742x over previous
//
#include <hip/hip_runtime.h>
#include <hip/hip_bf16.h>
#include <math.h>

// DockPointNet fused, round 9: R8 + VALU-diet on edge kernel + leaner prep.
// - packed bf16 conversion (v_cvt_pk_bf16_f32) for staging/epilogues;
//   st staging stored as uint pairs, reducer unpacks with shl/and (1 op/val).
// - segmented max reads uint pairs (2 edges/LDS load).
// - dsts[] array dropped (scatter stores only perm; edge gathers ei[E+e]).
// - hist/scatter 4 edges/thread; wprep 16 blocks (was 1, serialized).

#define LN_EPS 1e-5f
#define EPB 128
#define SM 72     // hbuf row stride in shorts
#define SP 130    // st row stride in shorts
#define AS 132    // node a_bf row stride in shorts

typedef __attribute__((ext_vector_type(8))) short bf16x8;
typedef __attribute__((ext_vector_type(4))) float floatx4;
typedef __attribute__((ext_vector_type(4))) short s4v;

__device__ __forceinline__ unsigned ord(float f) {
    int i = __float_as_int(f);
    return (i >= 0) ? ((unsigned)i | 0x80000000u) : ~((unsigned)i);
}
__device__ __forceinline__ float unord(unsigned u) {
    int i = (u & 0x80000000u) ? (int)(u & 0x7fffffffu) : ~(int)u;
    return __int_as_float(i);
}
__device__ __forceinline__ unsigned short f2b(float f) {   // RNE f32->bf16
    unsigned u = __float_as_uint(f);
    return (unsigned short)((u + 0x7FFFu + ((u >> 16) & 1u)) >> 16);
}
__device__ __forceinline__ float b2f(unsigned short h) {
    return __uint_as_float((unsigned)h << 16);
}
__device__ __forceinline__ unsigned f2b2(float lo, float hi) {  // packed pair
    union { __hip_bfloat162 h2; unsigned u; } c;
    c.h2 = __float22bfloat162_rn(make_float2(lo, hi));
    return c.u;
}
__device__ __forceinline__ float b2f_lo(unsigned w) { return __uint_as_float(w << 16); }
__device__ __forceinline__ float b2f_hi(unsigned w) { return __uint_as_float(w & 0xFFFF0000u); }

// ---------------- CSR build ----------------
__global__ void hist_kernel(const int* __restrict__ ei, unsigned* __restrict__ deg, int E) {
    int b4 = (blockIdx.x * 256 + threadIdx.x) * 4;
    if (b4 + 3 < E) {
        int4 d4 = *(const int4*)(ei + E + b4);
        atomicAdd(&deg[d4.x], 1u);
        atomicAdd(&deg[d4.y], 1u);
        atomicAdd(&deg[d4.z], 1u);
        atomicAdd(&deg[d4.w], 1u);
    } else {
        for (int i = 0; i < 4; ++i)
            if (b4 + i < E) atomicAdd(&deg[ei[E + b4 + i]], 1u);
    }
}

__global__ void scan1(const unsigned* __restrict__ deg, unsigned* __restrict__ part, int N) {
    __shared__ unsigned s[256];
    int i = blockIdx.x * 256 + threadIdx.x;
    s[threadIdx.x] = (i < N) ? deg[i] : 0u;
    __syncthreads();
    for (int st = 128; st > 0; st >>= 1) {
        if (threadIdx.x < st) s[threadIdx.x] += s[threadIdx.x + st];
        __syncthreads();
    }
    if (threadIdx.x == 0) part[blockIdx.x] = s[0];
}

__global__ void scan2(unsigned* __restrict__ part, int nb) {
    __shared__ unsigned s[256];
    int t = threadIdx.x;
    unsigned v = (t < nb) ? part[t] : 0u;
    s[t] = v;
    __syncthreads();
    for (int st = 1; st < 256; st <<= 1) {
        unsigned add = (t >= st) ? s[t - st] : 0u;
        __syncthreads();
        s[t] += add;
        __syncthreads();
    }
    if (t < nb) part[t] = s[t] - v;   // exclusive
}

__global__ void scan3(const unsigned* __restrict__ deg, const unsigned* __restrict__ part,
                      unsigned* __restrict__ off, int N) {
    __shared__ unsigned s[256];
    int i = blockIdx.x * 256 + threadIdx.x, t = threadIdx.x;
    unsigned v = (i < N) ? deg[i] : 0u;
    s[t] = v;
    __syncthreads();
    for (int st = 1; st < 256; st <<= 1) {
        unsigned add = (t >= st) ? s[t - st] : 0u;
        __syncthreads();
        s[t] += add;
        __syncthreads();
    }
    if (i < N) off[i] = part[blockIdx.x] + s[t] - v;   // exclusive
}

__global__ void scatter_kernel(const int* __restrict__ ei, unsigned* __restrict__ cursor,
                               unsigned* __restrict__ perm, int E) {
    int b4 = (blockIdx.x * 256 + threadIdx.x) * 4;
    if (b4 + 3 < E) {
        int4 d4 = *(const int4*)(ei + E + b4);
        perm[atomicAdd(&cursor[d4.x], 1u)] = (unsigned)(b4 + 0);
        perm[atomicAdd(&cursor[d4.y], 1u)] = (unsigned)(b4 + 1);
        perm[atomicAdd(&cursor[d4.z], 1u)] = (unsigned)(b4 + 2);
        perm[atomicAdd(&cursor[d4.w], 1u)] = (unsigned)(b4 + 3);
    } else {
        for (int i = 0; i < 4; ++i)
            if (b4 + i < E) {
                int d = ei[E + b4 + i];
                perm[atomicAdd(&cursor[d], 1u)] = (unsigned)(b4 + i);
            }
    }
}

// ---------------- weight prepack (16 blocks) ----------------
__global__ void wprep_kernel(const float* __restrict__ W1, const float* __restrict__ W2,
                             const float* __restrict__ Wg,
                             unsigned short* __restrict__ W1p, unsigned short* __restrict__ W2p,
                             unsigned short* __restrict__ Wgp)
{
    int gt = blockIdx.x * 256 + threadIdx.x;
    int gs = gridDim.x * 256;
    for (int fl = gt; fl < 8 * 64; fl += gs) {
        int fi = fl >> 6, l = fl & 63;
        int s = fi >> 2, nt = fi & 3;
        int n = nt * 16 + (l & 15);
        int kb = s * 32 + ((l >> 4) << 3);
        #pragma unroll
        for (int j = 0; j < 8; ++j) {
            int k = kb + j;
            W1p[fl * 8 + j] = f2b((k < 47) ? W1[k * 64 + n] : 0.f);
        }
    }
    for (int fl = gt; fl < 16 * 64; fl += gs) {
        int fi = fl >> 6, l = fl & 63;
        int s = fi >> 3, nt = fi & 7;
        int n = nt * 16 + (l & 15);
        int kb = s * 32 + ((l >> 4) << 3);
        #pragma unroll
        for (int j = 0; j < 8; ++j)
            W2p[fl * 8 + j] = f2b(W2[(kb + j) * 128 + n]);
    }
    for (int fl = gt; fl < 64 * 64; fl += gs) {
        int fi = fl >> 6, l = fl & 63;
        int s = fi >> 4, nt = fi & 15;
        int n = nt * 16 + (l & 15);
        int kb = s * 32 + ((l >> 4) << 3);
        #pragma unroll
        for (int j = 0; j < 8; ++j)
            Wgp[fl * 8 + j] = f2b(Wg[(size_t)(kb + j) * 256 + n]);
    }
}

// ---------------- fused edge MLP (MFMA) + segmented max ----------------
__global__ __launch_bounds__(256, 2)
void edge_kernel(const float* __restrict__ x,
                 const float* __restrict__ pos,
                 const float* __restrict__ nrm,
                 const float* __restrict__ ea,
                 const int* __restrict__ ei,
                 const unsigned* __restrict__ perm,
                 const unsigned short* __restrict__ W1p, const float* __restrict__ b1,
                 const float* __restrict__ g1, const float* __restrict__ be1,
                 const unsigned short* __restrict__ W2p, const float* __restrict__ b2,
                 const float* __restrict__ g2, const float* __restrict__ be2,
                 unsigned* __restrict__ agg, int E)
{
    __shared__ unsigned short hbuf[EPB * SM];
    __shared__ unsigned short st[128 * SP];
    __shared__ int dloc[EPB];
    __shared__ short rstart[EPB], rend[EPB];
    __shared__ unsigned long long wmask[2];
    __shared__ int dprev_s, dnext_s;

    const int tid  = threadIdx.x;
    const int lane = tid & 63;
    const int half = tid >> 7;
    const int el   = tid & 127;
    const int base = blockIdx.x * EPB;
    const int p    = base + el;
    const bool valid = p < E;
    const int nvalid = (E - base < EPB) ? (E - base) : EPB;

    int dst = 0, src = 0, e = 0;
    if (valid) {
        e   = (int)perm[p];
        src = ei[e];
        dst = ei[E + e];
    }
    if (half == 0) dloc[el] = valid ? dst : -1;
    if (tid == 0)
        dprev_s = (blockIdx.x == 0) ? -1 : ei[E + (int)perm[(size_t)base - 1]];
    if (tid == 1)
        dnext_s = (base + EPB < E) ? ei[E + (int)perm[base + EPB]] : -1;

    if (valid) {
        unsigned short* row = &hbuf[el * SM];
        if (half == 0) {
            const float4* xp = (const float4*)(x + (size_t)src * 32);
            #pragma unroll
            for (int q = 0; q < 4; ++q) {
                float4 v = xp[q];
                *(uint2*)&row[4 * q] = make_uint2(f2b2(v.x, v.y), f2b2(v.z, v.w));
            }
            float pix = pos[3*dst+0], piy = pos[3*dst+1], piz = pos[3*dst+2];
            float pjx = pos[3*src+0], pjy = pos[3*src+1], pjz = pos[3*src+2];
            float dx = pjx - pix, dy = pjy - piy, dz = pjz - piz;
            float nix = nrm[3*dst+0], niy = nrm[3*dst+1], niz = nrm[3*dst+2];
            float njx = nrm[3*src+0], njy = nrm[3*src+1], njz = nrm[3*src+2];
            row[32] = f2b(sqrtf(dx*dx + dy*dy + dz*dz) * 0.125f);
            float cx, cy, cz, c2, d, den, inv, sn, cs;
            cx = niy*dz - niz*dy; cy = niz*dx - nix*dz; cz = nix*dy - niy*dx;
            c2 = cx*cx + cy*cy + cz*cz;  d = nix*dx + niy*dy + niz*dz;
            den = c2 + d*d;
            if (den > 0.f) { inv = rsqrtf(den); sn = sqrtf(c2)*inv; cs = d*inv; }
            else           { sn = 0.f; cs = 1.f; }   // atan2(0,0)=0
            row[33] = f2b(sn); row[34] = f2b(cs);
            cx = njy*dz - njz*dy; cy = njz*dx - njx*dz; cz = njx*dy - njy*dx;
            c2 = cx*cx + cy*cy + cz*cz;  d = njx*dx + njy*dy + njz*dz;
            den = c2 + d*d;
            if (den > 0.f) { inv = rsqrtf(den); sn = sqrtf(c2)*inv; cs = d*inv; }
            else           { sn = 0.f; cs = 1.f; }
            row[35] = f2b(sn); row[36] = f2b(cs);
            cx = niy*njz - niz*njy; cy = niz*njx - nix*njz; cz = nix*njy - niy*njx;
            c2 = cx*cx + cy*cy + cz*cz;  d = nix*njx + niy*njy + niz*njz;
            den = c2 + d*d;
            if (den > 0.f) { inv = rsqrtf(den); sn = sqrtf(c2)*inv; cs = d*inv; }
            else           { sn = 0.f; cs = 1.f; }
            row[37] = f2b(sn); row[38] = f2b(cs);
        } else {
            const float4* xp = (const float4*)(x + (size_t)src * 32) + 4;
            #pragma unroll
            for (int q = 0; q < 4; ++q) {
                float4 v = xp[q];
                *(uint2*)&row[16 + 4 * q] = make_uint2(f2b2(v.x, v.y), f2b2(v.z, v.w));
            }
            const float4* ep = (const float4*)(ea + (size_t)e * 8);
            float4 a0 = ep[0], a1 = ep[1];
            row[39] = f2b(a0.x);
            *(uint2*)&row[40] = make_uint2(f2b2(a0.y, a0.z), f2b2(a0.w, a1.x));
            *(uint2*)&row[44] = make_uint2(f2b2(a1.y, a1.z), f2b2(a1.w, 0.f));
            uint2 z = make_uint2(0u, 0u);
            *(uint2*)&row[48] = z; *(uint2*)&row[52] = z;
            *(uint2*)&row[56] = z; *(uint2*)&row[60] = z;
        }
    }
    __syncthreads();   // B1: msg + dloc ready

    bool is_start = false, is_end = false;
    if (tid < 128) {
        int dt = dloc[tid];
        bool isv = tid < nvalid;
        is_start = isv && (tid == 0 || dloc[tid - 1] != dt);
        is_end   = isv && (tid == nvalid - 1 || dloc[tid + 1] != dt);
    }
    {
        unsigned long long mb = __ballot(is_start);
        if ((tid >> 6) < 2 && lane == 0) wmask[tid >> 6] = mb;
    }
    __syncthreads();   // B2: wmask visible
    int nr;
    {
        unsigned long long m0 = wmask[0], m1 = wmask[1];
        nr = __popcll(m0) + __popcll(m1);
        if (tid < 128) {
            int widr = tid >> 6;
            int rid = (widr ? __popcll(m0) : 0)
                    + __popcll((widr ? m1 : m0) & ((1ull << lane) - 1ull));
            if (is_start) rstart[rid] = (short)tid;
            if (is_end)   rend[is_start ? rid : rid - 1] = (short)tid;
        }
    }

    const int wid  = __builtin_amdgcn_readfirstlane(tid >> 6);
    const int quad = lane >> 4, col = lane & 15;
    const int mb0  = wid * 32;

    // GEMM1: 47(->64) -> 64
    {
        bf16x8 w1f[8];
        const bf16x8* W1v = (const bf16x8*)W1p;
        #pragma unroll
        for (int i = 0; i < 8; ++i) w1f[i] = W1v[i * 64 + lane];
        float b1v[4], g1v[4], e1v[4];
        #pragma unroll
        for (int nt = 0; nt < 4; ++nt) {
            b1v[nt] = b1[nt*16 + col]; g1v[nt] = g1[nt*16 + col]; e1v[nt] = be1[nt*16 + col];
        }
        #pragma unroll
        for (int t = 0; t < 2; ++t) {
            const int mb = mb0 + t * 16;
            floatx4 acc[4] = {{0,0,0,0},{0,0,0,0},{0,0,0,0},{0,0,0,0}};
            #pragma unroll
            for (int s = 0; s < 2; ++s) {
                const unsigned short* ap = &hbuf[(mb + col) * SM + s*32 + quad*8];
                union { s4v h[2]; bf16x8 v; } u;
                u.h[0] = *(const s4v*)ap; u.h[1] = *(const s4v*)(ap + 4);
                #pragma unroll
                for (int nt = 0; nt < 4; ++nt)
                    acc[nt] = __builtin_amdgcn_mfma_f32_16x16x32_bf16(u.v, w1f[s*4+nt], acc[nt], 0, 0, 0);
            }
            float ps[4] = {0,0,0,0}, p2[4] = {0,0,0,0};
            #pragma unroll
            for (int nt = 0; nt < 4; ++nt)
                #pragma unroll
                for (int r = 0; r < 4; ++r) {
                    float v = fmaxf(acc[nt][r] + b1v[nt], 0.f);
                    acc[nt][r] = v; ps[r] += v; p2[r] += v * v;
                }
            #pragma unroll
            for (int r = 0; r < 4; ++r) {
                #pragma unroll
                for (int m = 1; m < 16; m <<= 1) {
                    ps[r] += __shfl_xor(ps[r], m);
                    p2[r] += __shfl_xor(p2[r], m);
                }
            }
            float mu[4], rs[4];
            #pragma unroll
            for (int r = 0; r < 4; ++r) {
                mu[r] = ps[r] * (1.f/64.f);
                float var = fmaxf(p2[r] * (1.f/64.f) - mu[r]*mu[r], 0.f);
                rs[r] = rsqrtf(var + LN_EPS);
            }
            #pragma unroll
            for (int nt = 0; nt < 4; ++nt) {
                #pragma unroll
                for (int r = 0; r < 4; r += 2) {
                    float h0 = (acc[nt][r]   - mu[r])   * rs[r]   * g1v[nt] + e1v[nt];
                    float h1 = (acc[nt][r+1] - mu[r+1]) * rs[r+1] * g1v[nt] + e1v[nt];
                    unsigned pk = f2b2(h0, h1);
                    hbuf[(mb + quad*4 + r)   * SM + nt*16 + col] = (unsigned short)pk;
                    hbuf[(mb + quad*4 + r+1) * SM + nt*16 + col] = (unsigned short)(pk >> 16);
                }
            }
        }
    }
    // GEMM2: 64 -> 128
    {
        bf16x8 w2f[16];
        const bf16x8* W2v = (const bf16x8*)W2p;
        #pragma unroll
        for (int i = 0; i < 16; ++i) w2f[i] = W2v[i * 64 + lane];
        float b2v[8], g2v[8], e2v[8];
        #pragma unroll
        for (int nt = 0; nt < 8; ++nt) {
            b2v[nt] = b2[nt*16 + col]; g2v[nt] = g2[nt*16 + col]; e2v[nt] = be2[nt*16 + col];
        }
        #pragma unroll
        for (int t = 0; t < 2; ++t) {
            const int mb = mb0 + t * 16;
            floatx4 acc[8] = {{0,0,0,0},{0,0,0,0},{0,0,0,0},{0,0,0,0},
                              {0,0,0,0},{0,0,0,0},{0,0,0,0},{0,0,0,0}};
            #pragma unroll
            for (int s = 0; s < 2; ++s) {
                const unsigned short* ap = &hbuf[(mb + col) * SM + s*32 + quad*8];
                union { s4v h[2]; bf16x8 v; } u;
                u.h[0] = *(const s4v*)ap; u.h[1] = *(const s4v*)(ap + 4);
                #pragma unroll
                for (int nt = 0; nt < 8; ++nt)
                    acc[nt] = __builtin_amdgcn_mfma_f32_16x16x32_bf16(u.v, w2f[s*8+nt], acc[nt], 0, 0, 0);
            }
            float ps[4] = {0,0,0,0}, p2[4] = {0,0,0,0};
            #pragma unroll
            for (int nt = 0; nt < 8; ++nt)
                #pragma unroll
                for (int r = 0; r < 4; ++r) {
                    float v = fmaxf(acc[nt][r] + b2v[nt], 0.f);
                    acc[nt][r] = v; ps[r] += v; p2[r] += v * v;
                }
            #pragma unroll
            for (int r = 0; r < 4; ++r) {
                #pragma unroll
                for (int m = 1; m < 16; m <<= 1) {
                    ps[r] += __shfl_xor(ps[r], m);
                    p2[r] += __shfl_xor(p2[r], m);
                }
            }
            float mu[4], rs[4];
            #pragma unroll
            for (int r = 0; r < 4; ++r) {
                mu[r] = ps[r] * (1.f/128.f);
                float var = fmaxf(p2[r] * (1.f/128.f) - mu[r]*mu[r], 0.f);
                rs[r] = rsqrtf(var + LN_EPS);
            }
            #pragma unroll
            for (int nt = 0; nt < 8; ++nt) {
                float h0 = (acc[nt][0] - mu[0]) * rs[0] * g2v[nt] + e2v[nt];
                float h1 = (acc[nt][1] - mu[1]) * rs[1] * g2v[nt] + e2v[nt];
                float h2 = (acc[nt][2] - mu[2]) * rs[2] * g2v[nt] + e2v[nt];
                float h3 = (acc[nt][3] - mu[3]) * rs[3] * g2v[nt] + e2v[nt];
                // rows are adjacent shorts in st -> two uint stores (aligned: even idx)
                unsigned* d32 = (unsigned*)&st[(nt*16 + col) * SP + mb + quad*4];
                d32[0] = f2b2(h0, h1);
                d32[1] = f2b2(h2, h3);
            }
        }
    }
    __syncthreads();   // B3: staging + rstart/rend ready

    // ---- segmented max: feature f = tid&127, runs strided by 2; paired reads
    {
        const int grp = tid >> 7;
        const int f   = tid & 127;
        const unsigned short* fr = &st[f * SP];
        const unsigned* fp = (const unsigned*)fr;    // f*SP even -> 4B aligned
        for (int r = grp; r < nr; r += 2) {
            int s0 = rstart[r], en = rend[r];
            int d  = dloc[s0];
            float v0 = -1e30f, v1 = -1e30f;
            int c = s0;
            if (c & 1) { v0 = fmaxf(v0, b2f(fr[c])); ++c; }
            for (; c + 3 <= en; c += 4) {
                unsigned wa = fp[c >> 1], wb = fp[(c >> 1) + 1];
                v0 = fmaxf(v0, fmaxf(b2f_lo(wa), b2f_hi(wa)));
                v1 = fmaxf(v1, fmaxf(b2f_lo(wb), b2f_hi(wb)));
            }
            if (c + 1 <= en) {
                unsigned wa = fp[c >> 1];
                v0 = fmaxf(v0, fmaxf(b2f_lo(wa), b2f_hi(wa)));
                c += 2;
            }
            if (c <= en) v0 = fmaxf(v0, b2f(fr[c]));
            float val = fmaxf(v0, v1);
            bool contPrev = (s0 == 0) && (dprev_s == d);
            bool contNext = (en == nvalid - 1) && (dnext_s == d);
            unsigned enc = ord(val);
            unsigned* ap = agg + (size_t)d * 128 + f;
            if (contPrev || contNext) atomicMax(ap, enc);
            else                      *ap = enc;
        }
    }
}

// ---------------- node MLP (MFMA, unchanged R8) ----------------
__global__ __launch_bounds__(256, 2)
void node_kernel(const unsigned* __restrict__ agg,
                 const unsigned short* __restrict__ Wgp, const float* __restrict__ bg,
                 const float* __restrict__ gg, const float* __restrict__ beg,
                 float* __restrict__ out, int N)
{
    __shared__ unsigned short a_bf[64 * AS];
    const int tid  = threadIdx.x;
    const int base = blockIdx.x * 64;
    const size_t total = (size_t)N * 128;

    #pragma unroll
    for (int i = 0; i < 32; ++i) {
        int idx = tid + i * 256;
        int nl = idx >> 7, k = idx & 127;
        size_t g = (size_t)base * 128 + idx;
        unsigned u = (g < total) ? agg[g] : 0u;
        a_bf[nl * AS + k] = (u == 0u) ? (unsigned short)0 : f2b(unord(u));
    }
    __syncthreads();

    const int lane = tid & 63;
    const int wid  = __builtin_amdgcn_readfirstlane(tid >> 6);
    const int quad = lane >> 4, col = lane & 15;
    const int m0   = wid * 16;

    bf16x8 af[4];
    #pragma unroll
    for (int s = 0; s < 4; ++s) {
        const unsigned short* ap = &a_bf[(m0 + col) * AS + s*32 + quad*8];
        union { s4v h[2]; bf16x8 v; } u;
        u.h[0] = *(const s4v*)ap; u.h[1] = *(const s4v*)(ap + 4);
        af[s] = u.v;
    }

    float accv[16][4];
    float ps[4] = {0,0,0,0}, p2[4] = {0,0,0,0};
    const bf16x8* Wv = (const bf16x8*)Wgp;
    #pragma unroll
    for (int nt = 0; nt < 16; ++nt) {
        floatx4 acc = {0, 0, 0, 0};
        #pragma unroll
        for (int s = 0; s < 4; ++s)
            acc = __builtin_amdgcn_mfma_f32_16x16x32_bf16(af[s], Wv[(s*16 + nt)*64 + lane], acc, 0, 0, 0);
        float b = bg[nt*16 + col];
        #pragma unroll
        for (int r = 0; r < 4; ++r) {
            float v = fmaxf(acc[r] + b, 0.f);
            accv[nt][r] = v; ps[r] += v; p2[r] += v * v;
        }
    }
    #pragma unroll
    for (int r = 0; r < 4; ++r) {
        #pragma unroll
        for (int m = 1; m < 16; m <<= 1) {
            ps[r] += __shfl_xor(ps[r], m);
            p2[r] += __shfl_xor(p2[r], m);
        }
    }
    float mu[4], rs[4];
    #pragma unroll
    for (int r = 0; r < 4; ++r) {
        mu[r] = ps[r] * (1.f/256.f);
        float var = fmaxf(p2[r] * (1.f/256.f) - mu[r]*mu[r], 0.f);
        rs[r] = rsqrtf(var + LN_EPS);
    }
    #pragma unroll
    for (int nt = 0; nt < 16; ++nt) {
        float g = gg[nt*16 + col], be = beg[nt*16 + col];
        #pragma unroll
        for (int r = 0; r < 4; ++r) {
            int node = base + m0 + quad*4 + r;
            if (node < N)
                out[(size_t)node * 256 + nt*16 + col] = (accv[nt][r] - mu[r]) * rs[r] * g + be;
        }
    }
}

extern "C" void kernel_launch(void* const* d_in, const int* in_sizes, int n_in,
                              void* d_out, int out_size, void* d_ws, size_t ws_size,
                              hipStream_t stream) {
    const float* x         = (const float*)d_in[0];
    const float* pos       = (const float*)d_in[1];
    const float* nrm       = (const float*)d_in[2];
    const float* edge_attr = (const float*)d_in[3];
    const int*   ei        = (const int*)d_in[4];
    const float* W1  = (const float*)d_in[5];
    const float* b1  = (const float*)d_in[6];
    const float* g1  = (const float*)d_in[7];
    const float* be1 = (const float*)d_in[8];
    const float* W2  = (const float*)d_in[9];
    const float* b2  = (const float*)d_in[10];
    const float* g2  = (const float*)d_in[11];
    const float* be2 = (const float*)d_in[12];
    const float* Wg  = (const float*)d_in[13];
    const float* bg  = (const float*)d_in[14];
    const float* gg  = (const float*)d_in[15];
    const float* beg = (const float*)d_in[16];

    const int E = in_sizes[3] / 8;    // edge_attr is [E,8]
    const int N = in_sizes[0] / 32;   // x is [N,32]

    char* ws = (char*)d_ws;
    unsigned* agg  = (unsigned*)ws;                   ws += (size_t)N * 128 * 4;
    unsigned* deg  = (unsigned*)ws;                   ws += (size_t)N * 4;
    unsigned* off  = (unsigned*)ws;                   ws += (size_t)N * 4;
    unsigned* part = (unsigned*)ws;                   ws += 256 * 4;
    unsigned* perm = (unsigned*)ws;                   ws += (size_t)E * 4;
    unsigned short* W1p = (unsigned short*)ws;        ws += 8 * 64 * 8 * 2;
    unsigned short* W2p = (unsigned short*)ws;        ws += 16 * 64 * 8 * 2;
    unsigned short* Wgp = (unsigned short*)ws;        ws += 64 * 64 * 8 * 2;

    hipMemsetAsync(agg, 0, (size_t)N * 128 * 4, stream);
    hipMemsetAsync(deg, 0, (size_t)N * 4, stream);

    hipLaunchKernelGGL(wprep_kernel, dim3(16), dim3(256), 0, stream, W1, W2, Wg, W1p, W2p, Wgp);

    const int nbN = (N + 255) / 256;
    const int nbE4 = (E + 1023) / 1024;
    hipLaunchKernelGGL(hist_kernel, dim3(nbE4), dim3(256), 0, stream, ei, deg, E);
    hipLaunchKernelGGL(scan1, dim3(nbN), dim3(256), 0, stream, deg, part, N);
    hipLaunchKernelGGL(scan2, dim3(1), dim3(256), 0, stream, part, nbN);
    hipLaunchKernelGGL(scan3, dim3(nbN), dim3(256), 0, stream, deg, part, off, N);
    hipLaunchKernelGGL(scatter_kernel, dim3(nbE4), dim3(256), 0, stream, ei, off, perm, E);

    hipLaunchKernelGGL(edge_kernel, dim3((E + EPB - 1) / EPB), dim3(256), 0, stream,
                       x, pos, nrm, edge_attr, ei, perm,
                       W1p, b1, g1, be1, W2p, b2, g2, be2, agg, E);

    hipLaunchKernelGGL(node_kernel, dim3((N + 63) / 64), dim3(256), 0, stream,
                       agg, Wgp, bg, gg, beg, (float*)d_out, N);
}

// Round 10
// 575.945 us; speedup vs baseline: 15.2362x; 1.0551x over previous
//
#include <hip/hip_runtime.h>
#include <hip/hip_bf16.h>
#include <math.h>

// DockPointNet fused, round 10: R9 + occupancy + coalesced dst.
// - edge_kernel launch_bounds(256,3): LDS 52 KB x3 = 156 <= 160 KB/CU,
//   VGPR 80 far under the 3-wave/EU cap -> 3 blocks/CU (was 2).
// - scatter writes uint2 (edge, dst) -> edge kernel reads dst via coalesced
//   8B load instead of the random ei[E+e] gather (R9 cost ~100 MB FETCH).
// - node_kernel launch_bounds(256,4) (latency-bound on Wgp loads).

#define LN_EPS 1e-5f
#define EPB 128
#define SM 72     // hbuf row stride in shorts
#define SP 130    // st row stride in shorts
#define AS 132    // node a_bf row stride in shorts

typedef __attribute__((ext_vector_type(8))) short bf16x8;
typedef __attribute__((ext_vector_type(4))) float floatx4;
typedef __attribute__((ext_vector_type(4))) short s4v;

__device__ __forceinline__ unsigned ord(float f) {
    int i = __float_as_int(f);
    return (i >= 0) ? ((unsigned)i | 0x80000000u) : ~((unsigned)i);
}
__device__ __forceinline__ float unord(unsigned u) {
    int i = (u & 0x80000000u) ? (int)(u & 0x7fffffffu) : ~(int)u;
    return __int_as_float(i);
}
__device__ __forceinline__ unsigned short f2b(float f) {   // RNE f32->bf16
    unsigned u = __float_as_uint(f);
    return (unsigned short)((u + 0x7FFFu + ((u >> 16) & 1u)) >> 16);
}
__device__ __forceinline__ float b2f(unsigned short h) {
    return __uint_as_float((unsigned)h << 16);
}
__device__ __forceinline__ unsigned f2b2(float lo, float hi) {  // packed pair
    union { __hip_bfloat162 h2; unsigned u; } c;
    c.h2 = __float22bfloat162_rn(make_float2(lo, hi));
    return c.u;
}
__device__ __forceinline__ float b2f_lo(unsigned w) { return __uint_as_float(w << 16); }
__device__ __forceinline__ float b2f_hi(unsigned w) { return __uint_as_float(w & 0xFFFF0000u); }

// ---------------- CSR build ----------------
__global__ void hist_kernel(const int* __restrict__ ei, unsigned* __restrict__ deg, int E) {
    int b4 = (blockIdx.x * 256 + threadIdx.x) * 4;
    if (b4 + 3 < E) {
        int4 d4 = *(const int4*)(ei + E + b4);
        atomicAdd(&deg[d4.x], 1u);
        atomicAdd(&deg[d4.y], 1u);
        atomicAdd(&deg[d4.z], 1u);
        atomicAdd(&deg[d4.w], 1u);
    } else {
        for (int i = 0; i < 4; ++i)
            if (b4 + i < E) atomicAdd(&deg[ei[E + b4 + i]], 1u);
    }
}

__global__ void scan1(const unsigned* __restrict__ deg, unsigned* __restrict__ part, int N) {
    __shared__ unsigned s[256];
    int i = blockIdx.x * 256 + threadIdx.x;
    s[threadIdx.x] = (i < N) ? deg[i] : 0u;
    __syncthreads();
    for (int st = 128; st > 0; st >>= 1) {
        if (threadIdx.x < st) s[threadIdx.x] += s[threadIdx.x + st];
        __syncthreads();
    }
    if (threadIdx.x == 0) part[blockIdx.x] = s[0];
}

__global__ void scan2(unsigned* __restrict__ part, int nb) {
    __shared__ unsigned s[256];
    int t = threadIdx.x;
    unsigned v = (t < nb) ? part[t] : 0u;
    s[t] = v;
    __syncthreads();
    for (int st = 1; st < 256; st <<= 1) {
        unsigned add = (t >= st) ? s[t - st] : 0u;
        __syncthreads();
        s[t] += add;
        __syncthreads();
    }
    if (t < nb) part[t] = s[t] - v;   // exclusive
}

__global__ void scan3(const unsigned* __restrict__ deg, const unsigned* __restrict__ part,
                      unsigned* __restrict__ off, int N) {
    __shared__ unsigned s[256];
    int i = blockIdx.x * 256 + threadIdx.x, t = threadIdx.x;
    unsigned v = (i < N) ? deg[i] : 0u;
    s[t] = v;
    __syncthreads();
    for (int st = 1; st < 256; st <<= 1) {
        unsigned add = (t >= st) ? s[t - st] : 0u;
        __syncthreads();
        s[t] += add;
        __syncthreads();
    }
    if (i < N) off[i] = part[blockIdx.x] + s[t] - v;   // exclusive
}

__global__ void scatter_kernel(const int* __restrict__ ei, unsigned* __restrict__ cursor,
                               uint2* __restrict__ pd, int E) {
    int b4 = (blockIdx.x * 256 + threadIdx.x) * 4;
    if (b4 + 3 < E) {
        int4 d4 = *(const int4*)(ei + E + b4);
        pd[atomicAdd(&cursor[d4.x], 1u)] = make_uint2((unsigned)(b4 + 0), (unsigned)d4.x);
        pd[atomicAdd(&cursor[d4.y], 1u)] = make_uint2((unsigned)(b4 + 1), (unsigned)d4.y);
        pd[atomicAdd(&cursor[d4.z], 1u)] = make_uint2((unsigned)(b4 + 2), (unsigned)d4.z);
        pd[atomicAdd(&cursor[d4.w], 1u)] = make_uint2((unsigned)(b4 + 3), (unsigned)d4.w);
    } else {
        for (int i = 0; i < 4; ++i)
            if (b4 + i < E) {
                int d = ei[E + b4 + i];
                pd[atomicAdd(&cursor[d], 1u)] = make_uint2((unsigned)(b4 + i), (unsigned)d);
            }
    }
}

// ---------------- weight prepack (16 blocks) ----------------
__global__ void wprep_kernel(const float* __restrict__ W1, const float* __restrict__ W2,
                             const float* __restrict__ Wg,
                             unsigned short* __restrict__ W1p, unsigned short* __restrict__ W2p,
                             unsigned short* __restrict__ Wgp)
{
    int gt = blockIdx.x * 256 + threadIdx.x;
    int gs = gridDim.x * 256;
    for (int fl = gt; fl < 8 * 64; fl += gs) {
        int fi = fl >> 6, l = fl & 63;
        int s = fi >> 2, nt = fi & 3;
        int n = nt * 16 + (l & 15);
        int kb = s * 32 + ((l >> 4) << 3);
        #pragma unroll
        for (int j = 0; j < 8; ++j) {
            int k = kb + j;
            W1p[fl * 8 + j] = f2b((k < 47) ? W1[k * 64 + n] : 0.f);
        }
    }
    for (int fl = gt; fl < 16 * 64; fl += gs) {
        int fi = fl >> 6, l = fl & 63;
        int s = fi >> 3, nt = fi & 7;
        int n = nt * 16 + (l & 15);
        int kb = s * 32 + ((l >> 4) << 3);
        #pragma unroll
        for (int j = 0; j < 8; ++j)
            W2p[fl * 8 + j] = f2b(W2[(kb + j) * 128 + n]);
    }
    for (int fl = gt; fl < 64 * 64; fl += gs) {
        int fi = fl >> 6, l = fl & 63;
        int s = fi >> 4, nt = fi & 15;
        int n = nt * 16 + (l & 15);
        int kb = s * 32 + ((l >> 4) << 3);
        #pragma unroll
        for (int j = 0; j < 8; ++j)
            Wgp[fl * 8 + j] = f2b(Wg[(size_t)(kb + j) * 256 + n]);
    }
}

// ---------------- fused edge MLP (MFMA) + segmented max ----------------
__global__ __launch_bounds__(256, 3)
void edge_kernel(const float* __restrict__ x,
                 const float* __restrict__ pos,
                 const float* __restrict__ nrm,
                 const float* __restrict__ ea,
                 const int* __restrict__ ei,
                 const uint2* __restrict__ pd,
                 const unsigned short* __restrict__ W1p, const float* __restrict__ b1,
                 const float* __restrict__ g1, const float* __restrict__ be1,
                 const unsigned short* __restrict__ W2p, const float* __restrict__ b2,
                 const float* __restrict__ g2, const float* __restrict__ be2,
                 unsigned* __restrict__ agg, int E)
{
    __shared__ unsigned short hbuf[EPB * SM];
    __shared__ unsigned short st[128 * SP];
    __shared__ int dloc[EPB];
    __shared__ short rstart[EPB], rend[EPB];
    __shared__ unsigned long long wmask[2];
    __shared__ int dprev_s, dnext_s;

    const int tid  = threadIdx.x;
    const int lane = tid & 63;
    const int half = tid >> 7;
    const int el   = tid & 127;
    const int base = blockIdx.x * EPB;
    const int p    = base + el;
    const bool valid = p < E;
    const int nvalid = (E - base < EPB) ? (E - base) : EPB;

    int dst = 0, src = 0, e = 0;
    if (valid) {
        uint2 pv = pd[p];
        e   = (int)pv.x;
        dst = (int)pv.y;
        src = ei[e];
    }
    if (half == 0) dloc[el] = valid ? dst : -1;
    if (tid == 0)
        dprev_s = (blockIdx.x == 0) ? -1 : (int)pd[(size_t)base - 1].y;
    if (tid == 1)
        dnext_s = (base + EPB < E) ? (int)pd[base + EPB].y : -1;

    if (valid) {
        unsigned short* row = &hbuf[el * SM];
        if (half == 0) {
            const float4* xp = (const float4*)(x + (size_t)src * 32);
            #pragma unroll
            for (int q = 0; q < 4; ++q) {
                float4 v = xp[q];
                *(uint2*)&row[4 * q] = make_uint2(f2b2(v.x, v.y), f2b2(v.z, v.w));
            }
            float pix = pos[3*dst+0], piy = pos[3*dst+1], piz = pos[3*dst+2];
            float pjx = pos[3*src+0], pjy = pos[3*src+1], pjz = pos[3*src+2];
            float dx = pjx - pix, dy = pjy - piy, dz = pjz - piz;
            float nix = nrm[3*dst+0], niy = nrm[3*dst+1], niz = nrm[3*dst+2];
            float njx = nrm[3*src+0], njy = nrm[3*src+1], njz = nrm[3*src+2];
            row[32] = f2b(sqrtf(dx*dx + dy*dy + dz*dz) * 0.125f);
            float cx, cy, cz, c2, d, den, inv, sn, cs;
            cx = niy*dz - niz*dy; cy = niz*dx - nix*dz; cz = nix*dy - niy*dx;
            c2 = cx*cx + cy*cy + cz*cz;  d = nix*dx + niy*dy + niz*dz;
            den = c2 + d*d;
            if (den > 0.f) { inv = rsqrtf(den); sn = sqrtf(c2)*inv; cs = d*inv; }
            else           { sn = 0.f; cs = 1.f; }   // atan2(0,0)=0
            row[33] = f2b(sn); row[34] = f2b(cs);
            cx = njy*dz - njz*dy; cy = njz*dx - njx*dz; cz = njx*dy - njy*dx;
            c2 = cx*cx + cy*cy + cz*cz;  d = njx*dx + njy*dy + njz*dz;
            den = c2 + d*d;
            if (den > 0.f) { inv = rsqrtf(den); sn = sqrtf(c2)*inv; cs = d*inv; }
            else           { sn = 0.f; cs = 1.f; }
            row[35] = f2b(sn); row[36] = f2b(cs);
            cx = niy*njz - niz*njy; cy = niz*njx - nix*njz; cz = nix*njy - niy*njx;
            c2 = cx*cx + cy*cy + cz*cz;  d = nix*njx + niy*njy + niz*njz;
            den = c2 + d*d;
            if (den > 0.f) { inv = rsqrtf(den); sn = sqrtf(c2)*inv; cs = d*inv; }
            else           { sn = 0.f; cs = 1.f; }
            row[37] = f2b(sn); row[38] = f2b(cs);
        } else {
            const float4* xp = (const float4*)(x + (size_t)src * 32) + 4;
            #pragma unroll
            for (int q = 0; q < 4; ++q) {
                float4 v = xp[q];
                *(uint2*)&row[16 + 4 * q] = make_uint2(f2b2(v.x, v.y), f2b2(v.z, v.w));
            }
            const float4* ep = (const float4*)(ea + (size_t)e * 8);
            float4 a0 = ep[0], a1 = ep[1];
            row[39] = f2b(a0.x);
            *(uint2*)&row[40] = make_uint2(f2b2(a0.y, a0.z), f2b2(a0.w, a1.x));
            *(uint2*)&row[44] = make_uint2(f2b2(a1.y, a1.z), f2b2(a1.w, 0.f));
            uint2 z = make_uint2(0u, 0u);
            *(uint2*)&row[48] = z; *(uint2*)&row[52] = z;
            *(uint2*)&row[56] = z; *(uint2*)&row[60] = z;
        }
    }
    __syncthreads();   // B1: msg + dloc ready

    bool is_start = false, is_end = false;
    if (tid < 128) {
        int dt = dloc[tid];
        bool isv = tid < nvalid;
        is_start = isv && (tid == 0 || dloc[tid - 1] != dt);
        is_end   = isv && (tid == nvalid - 1 || dloc[tid + 1] != dt);
    }
    {
        unsigned long long mb = __ballot(is_start);
        if ((tid >> 6) < 2 && lane == 0) wmask[tid >> 6] = mb;
    }
    __syncthreads();   // B2: wmask visible
    int nr;
    {
        unsigned long long m0 = wmask[0], m1 = wmask[1];
        nr = __popcll(m0) + __popcll(m1);
        if (tid < 128) {
            int widr = tid >> 6;
            int rid = (widr ? __popcll(m0) : 0)
                    + __popcll((widr ? m1 : m0) & ((1ull << lane) - 1ull));
            if (is_start) rstart[rid] = (short)tid;
            if (is_end)   rend[is_start ? rid : rid - 1] = (short)tid;
        }
    }

    const int wid  = __builtin_amdgcn_readfirstlane(tid >> 6);
    const int quad = lane >> 4, col = lane & 15;
    const int mb0  = wid * 32;

    // GEMM1: 47(->64) -> 64
    {
        bf16x8 w1f[8];
        const bf16x8* W1v = (const bf16x8*)W1p;
        #pragma unroll
        for (int i = 0; i < 8; ++i) w1f[i] = W1v[i * 64 + lane];
        float b1v[4], g1v[4], e1v[4];
        #pragma unroll
        for (int nt = 0; nt < 4; ++nt) {
            b1v[nt] = b1[nt*16 + col]; g1v[nt] = g1[nt*16 + col]; e1v[nt] = be1[nt*16 + col];
        }
        #pragma unroll
        for (int t = 0; t < 2; ++t) {
            const int mb = mb0 + t * 16;
            floatx4 acc[4] = {{0,0,0,0},{0,0,0,0},{0,0,0,0},{0,0,0,0}};
            #pragma unroll
            for (int s = 0; s < 2; ++s) {
                const unsigned short* ap = &hbuf[(mb + col) * SM + s*32 + quad*8];
                union { s4v h[2]; bf16x8 v; } u;
                u.h[0] = *(const s4v*)ap; u.h[1] = *(const s4v*)(ap + 4);
                #pragma unroll
                for (int nt = 0; nt < 4; ++nt)
                    acc[nt] = __builtin_amdgcn_mfma_f32_16x16x32_bf16(u.v, w1f[s*4+nt], acc[nt], 0, 0, 0);
            }
            float ps[4] = {0,0,0,0}, p2[4] = {0,0,0,0};
            #pragma unroll
            for (int nt = 0; nt < 4; ++nt)
                #pragma unroll
                for (int r = 0; r < 4; ++r) {
                    float v = fmaxf(acc[nt][r] + b1v[nt], 0.f);
                    acc[nt][r] = v; ps[r] += v; p2[r] += v * v;
                }
            #pragma unroll
            for (int r = 0; r < 4; ++r) {
                #pragma unroll
                for (int m = 1; m < 16; m <<= 1) {
                    ps[r] += __shfl_xor(ps[r], m);
                    p2[r] += __shfl_xor(p2[r], m);
                }
            }
            float mu[4], rs[4];
            #pragma unroll
            for (int r = 0; r < 4; ++r) {
                mu[r] = ps[r] * (1.f/64.f);
                float var = fmaxf(p2[r] * (1.f/64.f) - mu[r]*mu[r], 0.f);
                rs[r] = rsqrtf(var + LN_EPS);
            }
            #pragma unroll
            for (int nt = 0; nt < 4; ++nt) {
                #pragma unroll
                for (int r = 0; r < 4; r += 2) {
                    float h0 = (acc[nt][r]   - mu[r])   * rs[r]   * g1v[nt] + e1v[nt];
                    float h1 = (acc[nt][r+1] - mu[r+1]) * rs[r+1] * g1v[nt] + e1v[nt];
                    unsigned pk = f2b2(h0, h1);
                    hbuf[(mb + quad*4 + r)   * SM + nt*16 + col] = (unsigned short)pk;
                    hbuf[(mb + quad*4 + r+1) * SM + nt*16 + col] = (unsigned short)(pk >> 16);
                }
            }
        }
    }
    // GEMM2: 64 -> 128
    {
        bf16x8 w2f[16];
        const bf16x8* W2v = (const bf16x8*)W2p;
        #pragma unroll
        for (int i = 0; i < 16; ++i) w2f[i] = W2v[i * 64 + lane];
        float b2v[8], g2v[8], e2v[8];
        #pragma unroll
        for (int nt = 0; nt < 8; ++nt) {
            b2v[nt] = b2[nt*16 + col]; g2v[nt] = g2[nt*16 + col]; e2v[nt] = be2[nt*16 + col];
        }
        #pragma unroll
        for (int t = 0; t < 2; ++t) {
            const int mb = mb0 + t * 16;
            floatx4 acc[8] = {{0,0,0,0},{0,0,0,0},{0,0,0,0},{0,0,0,0},
                              {0,0,0,0},{0,0,0,0},{0,0,0,0},{0,0,0,0}};
            #pragma unroll
            for (int s = 0; s < 2; ++s) {
                const unsigned short* ap = &hbuf[(mb + col) * SM + s*32 + quad*8];
                union { s4v h[2]; bf16x8 v; } u;
                u.h[0] = *(const s4v*)ap; u.h[1] = *(const s4v*)(ap + 4);
                #pragma unroll
                for (int nt = 0; nt < 8; ++nt)
                    acc[nt] = __builtin_amdgcn_mfma_f32_16x16x32_bf16(u.v, w2f[s*8+nt], acc[nt], 0, 0, 0);
            }
            float ps[4] = {0,0,0,0}, p2[4] = {0,0,0,0};
            #pragma unroll
            for (int nt = 0; nt < 8; ++nt)
                #pragma unroll
                for (int r = 0; r < 4; ++r) {
                    float v = fmaxf(acc[nt][r] + b2v[nt], 0.f);
                    acc[nt][r] = v; ps[r] += v; p2[r] += v * v;
                }
            #pragma unroll
            for (int r = 0; r < 4; ++r) {
                #pragma unroll
                for (int m = 1; m < 16; m <<= 1) {
                    ps[r] += __shfl_xor(ps[r], m);
                    p2[r] += __shfl_xor(p2[r], m);
                }
            }
            float mu[4], rs[4];
            #pragma unroll
            for (int r = 0; r < 4; ++r) {
                mu[r] = ps[r] * (1.f/128.f);
                float var = fmaxf(p2[r] * (1.f/128.f) - mu[r]*mu[r], 0.f);
                rs[r] = rsqrtf(var + LN_EPS);
            }
            #pragma unroll
            for (int nt = 0; nt < 8; ++nt) {
                float h0 = (acc[nt][0] - mu[0]) * rs[0] * g2v[nt] + e2v[nt];
                float h1 = (acc[nt][1] - mu[1]) * rs[1] * g2v[nt] + e2v[nt];
                float h2 = (acc[nt][2] - mu[2]) * rs[2] * g2v[nt] + e2v[nt];
                float h3 = (acc[nt][3] - mu[3]) * rs[3] * g2v[nt] + e2v[nt];
                unsigned* d32 = (unsigned*)&st[(nt*16 + col) * SP + mb + quad*4];
                d32[0] = f2b2(h0, h1);
                d32[1] = f2b2(h2, h3);
            }
        }
    }
    __syncthreads();   // B3: staging + rstart/rend ready

    // ---- segmented max: feature f = tid&127, runs strided by 2; paired reads
    {
        const int grp = tid >> 7;
        const int f   = tid & 127;
        const unsigned short* fr = &st[f * SP];
        const unsigned* fp = (const unsigned*)fr;    // f*SP even -> 4B aligned
        for (int r = grp; r < nr; r += 2) {
            int s0 = rstart[r], en = rend[r];
            int d  = dloc[s0];
            float v0 = -1e30f, v1 = -1e30f;
            int c = s0;
            if (c & 1) { v0 = fmaxf(v0, b2f(fr[c])); ++c; }
            for (; c + 3 <= en; c += 4) {
                unsigned wa = fp[c >> 1], wb = fp[(c >> 1) + 1];
                v0 = fmaxf(v0, fmaxf(b2f_lo(wa), b2f_hi(wa)));
                v1 = fmaxf(v1, fmaxf(b2f_lo(wb), b2f_hi(wb)));
            }
            if (c + 1 <= en) {
                unsigned wa = fp[c >> 1];
                v0 = fmaxf(v0, fmaxf(b2f_lo(wa), b2f_hi(wa)));
                c += 2;
            }
            if (c <= en) v0 = fmaxf(v0, b2f(fr[c]));
            float val = fmaxf(v0, v1);
            bool contPrev = (s0 == 0) && (dprev_s == d);
            bool contNext = (en == nvalid - 1) && (dnext_s == d);
            unsigned enc = ord(val);
            unsigned* ap = agg + (size_t)d * 128 + f;
            if (contPrev || contNext) atomicMax(ap, enc);
            else                      *ap = enc;
        }
    }
}

// ---------------- node MLP (MFMA) ----------------
__global__ __launch_bounds__(256, 4)
void node_kernel(const unsigned* __restrict__ agg,
                 const unsigned short* __restrict__ Wgp, const float* __restrict__ bg,
                 const float* __restrict__ gg, const float* __restrict__ beg,
                 float* __restrict__ out, int N)
{
    __shared__ unsigned short a_bf[64 * AS];
    const int tid  = threadIdx.x;
    const int base = blockIdx.x * 64;
    const size_t total = (size_t)N * 128;

    #pragma unroll
    for (int i = 0; i < 32; ++i) {
        int idx = tid + i * 256;
        int nl = idx >> 7, k = idx & 127;
        size_t g = (size_t)base * 128 + idx;
        unsigned u = (g < total) ? agg[g] : 0u;
        a_bf[nl * AS + k] = (u == 0u) ? (unsigned short)0 : f2b(unord(u));
    }
    __syncthreads();

    const int lane = tid & 63;
    const int wid  = __builtin_amdgcn_readfirstlane(tid >> 6);
    const int quad = lane >> 4, col = lane & 15;
    const int m0   = wid * 16;

    bf16x8 af[4];
    #pragma unroll
    for (int s = 0; s < 4; ++s) {
        const unsigned short* ap = &a_bf[(m0 + col) * AS + s*32 + quad*8];
        union { s4v h[2]; bf16x8 v; } u;
        u.h[0] = *(const s4v*)ap; u.h[1] = *(const s4v*)(ap + 4);
        af[s] = u.v;
    }

    float accv[16][4];
    float ps[4] = {0,0,0,0}, p2[4] = {0,0,0,0};
    const bf16x8* Wv = (const bf16x8*)Wgp;
    #pragma unroll
    for (int nt = 0; nt < 16; ++nt) {
        floatx4 acc = {0, 0, 0, 0};
        #pragma unroll
        for (int s = 0; s < 4; ++s)
            acc = __builtin_amdgcn_mfma_f32_16x16x32_bf16(af[s], Wv[(s*16 + nt)*64 + lane], acc, 0, 0, 0);
        float b = bg[nt*16 + col];
        #pragma unroll
        for (int r = 0; r < 4; ++r) {
            float v = fmaxf(acc[r] + b, 0.f);
            accv[nt][r] = v; ps[r] += v; p2[r] += v * v;
        }
    }
    #pragma unroll
    for (int r = 0; r < 4; ++r) {
        #pragma unroll
        for (int m = 1; m < 16; m <<= 1) {
            ps[r] += __shfl_xor(ps[r], m);
            p2[r] += __shfl_xor(p2[r], m);
        }
    }
    float mu[4], rs[4];
    #pragma unroll
    for (int r = 0; r < 4; ++r) {
        mu[r] = ps[r] * (1.f/256.f);
        float var = fmaxf(p2[r] * (1.f/256.f) - mu[r]*mu[r], 0.f);
        rs[r] = rsqrtf(var + LN_EPS);
    }
    #pragma unroll
    for (int nt = 0; nt < 16; ++nt) {
        float g = gg[nt*16 + col], be = beg[nt*16 + col];
        #pragma unroll
        for (int r = 0; r < 4; ++r) {
            int node = base + m0 + quad*4 + r;
            if (node < N)
                out[(size_t)node * 256 + nt*16 + col] = (accv[nt][r] - mu[r]) * rs[r] * g + be;
        }
    }
}

extern "C" void kernel_launch(void* const* d_in, const int* in_sizes, int n_in,
                              void* d_out, int out_size, void* d_ws, size_t ws_size,
                              hipStream_t stream) {
    const float* x         = (const float*)d_in[0];
    const float* pos       = (const float*)d_in[1];
    const float* nrm       = (const float*)d_in[2];
    const float* edge_attr = (const float*)d_in[3];
    const int*   ei        = (const int*)d_in[4];
    const float* W1  = (const float*)d_in[5];
    const float* b1  = (const float*)d_in[6];
    const float* g1  = (const float*)d_in[7];
    const float* be1 = (const float*)d_in[8];
    const float* W2  = (const float*)d_in[9];
    const float* b2  = (const float*)d_in[10];
    const float* g2  = (const float*)d_in[11];
    const float* be2 = (const float*)d_in[12];
    const float* Wg  = (const float*)d_in[13];
    const float* bg  = (const float*)d_in[14];
    const float* gg  = (const float*)d_in[15];
    const float* beg = (const float*)d_in[16];

    const int E = in_sizes[3] / 8;    // edge_attr is [E,8]
    const int N = in_sizes[0] / 32;   // x is [N,32]

    char* ws = (char*)d_ws;
    unsigned* agg  = (unsigned*)ws;                   ws += (size_t)N * 128 * 4;
    unsigned* deg  = (unsigned*)ws;                   ws += (size_t)N * 4;
    unsigned* off  = (unsigned*)ws;                   ws += (size_t)N * 4;
    unsigned* part = (unsigned*)ws;                   ws += 256 * 4;
    uint2*    pd   = (uint2*)ws;                      ws += (size_t)E * 8;
    unsigned short* W1p = (unsigned short*)ws;        ws += 8 * 64 * 8 * 2;
    unsigned short* W2p = (unsigned short*)ws;        ws += 16 * 64 * 8 * 2;
    unsigned short* Wgp = (unsigned short*)ws;        ws += 64 * 64 * 8 * 2;

    hipMemsetAsync(agg, 0, (size_t)N * 128 * 4, stream);
    hipMemsetAsync(deg, 0, (size_t)N * 4, stream);

    hipLaunchKernelGGL(wprep_kernel, dim3(16), dim3(256), 0, stream, W1, W2, Wg, W1p, W2p, Wgp);

    const int nbN = (N + 255) / 256;
    const int nbE4 = (E + 1023) / 1024;
    hipLaunchKernelGGL(hist_kernel, dim3(nbE4), dim3(256), 0, stream, ei, deg, E);
    hipLaunchKernelGGL(scan1, dim3(nbN), dim3(256), 0, stream, deg, part, N);
    hipLaunchKernelGGL(scan2, dim3(1), dim3(256), 0, stream, part, nbN);
    hipLaunchKernelGGL(scan3, dim3(nbN), dim3(256), 0, stream, deg, part, off, N);
    hipLaunchKernelGGL(scatter_kernel, dim3(nbE4), dim3(256), 0, stream, ei, off, pd, E);

    hipLaunchKernelGGL(edge_kernel, dim3((E + EPB - 1) / EPB), dim3(256), 0, stream,
                       x, pos, nrm, edge_attr, ei, pd,
                       W1p, b1, g1, be1, W2p, b2, g2, be2, agg, E);

    hipLaunchKernelGGL(node_kernel, dim3((N + 63) / 64), dim3(256), 0, stream,
                       agg, Wgp, bg, gg, beg, (float*)d_out, N);
}